// Round 1
// 284.985 us; speedup vs baseline: 1.0501x; 1.0501x over previous
//
#include <hip/hip_runtime.h>

// MHA forward.  B=4 T=2048 DM=1024 H=16 DK=DV=64.  f32 in / f32 out.
// R11: (1) proj -> m97 structure: global_load_lds dwordx4 staging into
//      unpadded LDS with m201 both-sides XOR swizzle (conflict-free
//      ds_read_b128, no register round-trip).  (2) attn occupancy 2x:
//      64-row q-tiles, grid (16,16,4) = 4 blocks/CU, paired {qt,31-qt}
//      (33 s-tiles/block exact balance); K/V staged via global_load_lds
//      with the same swizzle; log2-domain softmax (Q pre-scaled by
//      0.125*log2e, raw v_exp_f32); defer-max rescale skip (T13).

#define B_  4
#define T_  2048
#define DM_ 1024
#define H_  16
#define D_  64
#define DMO 1024   // out row stride = H_*D_

typedef unsigned short u16;
typedef unsigned int   u32;
typedef u16   u16x8 __attribute__((ext_vector_type(8)));
typedef short s16x8 __attribute__((ext_vector_type(8)));
typedef float f32x4 __attribute__((ext_vector_type(4)));
typedef u32   u32x4 __attribute__((ext_vector_type(4)));

#if __has_builtin(__builtin_amdgcn_exp2f)
#define EXP2(x) __builtin_amdgcn_exp2f(x)
#else
#define EXP2(x) __expf((x) * 0.69314718f)
#endif

__device__ __forceinline__ u16 f2bf_hu(float f) {   // round-half-up (ties rare)
    u32 u = __builtin_bit_cast(u32, f) + 0x8000u;
    return (u16)(u >> 16);
}
// pack two f32 -> dword of two bf16 (lo,hi), 3 VALU ops
__device__ __forceinline__ u32 pk2(float lo, float hi) {
    u32 ul = __builtin_bit_cast(u32, lo) + 0x8000u;
    u32 uh = __builtin_bit_cast(u32, hi) + 0x8000u;
    return __builtin_amdgcn_perm(uh, ul, 0x07060302);  // [uh.hi16 : ul.hi16]
}
__device__ __forceinline__ u16x8 cvt8(const float* s) {
    f32x4 a = *(const f32x4*)s;
    f32x4 b = *(const f32x4*)(s + 4);
    u32x4 r { pk2(a[0], a[1]), pk2(a[2], a[3]), pk2(b[0], b[1]), pk2(b[2], b[3]) };
    return __builtin_bit_cast(u16x8, r);
}
__device__ __forceinline__ f32x4 mfma16(u16x8 a, u16x8 b, f32x4 c) {
    return __builtin_amdgcn_mfma_f32_16x16x32_bf16(
        __builtin_bit_cast(s16x8, a), __builtin_bit_cast(s16x8, b), c, 0, 0, 0);
}
// async global->LDS, 16B per lane.  LDS dest must be wave-uniform base + lane*16.
__device__ __forceinline__ void gld_lds16(const u16* g, u16* l) {
    __builtin_amdgcn_global_load_lds(
        (const __attribute__((address_space(1))) u32*)g,
        (__attribute__((address_space(3))) u32*)l, 16, 0, 0);
}

// ---------------------------------------------------------------------------
// cvt_x: x f32 [8192][1024] -> xb bf16 (same layout).  1024 blocks x 256.
// ---------------------------------------------------------------------------
__global__ __launch_bounds__(256) void cvt_x(const float* __restrict__ x,
                                             u16* __restrict__ xb) {
    size_t i0 = ((size_t)blockIdx.x * 256 + threadIdx.x) * 32;
    #pragma unroll
    for (int c = 0; c < 4; c++)
        *(u16x8*)(xb + i0 + c * 8) = cvt8(x + i0 + c * 8);
}

// ---------------------------------------------------------------------------
// cvt_w: W[mat][h][d=1024][dk=64] f32 -> Wt[(mat*16+h)*64+dk][d=1024] bf16.
// grid (16 d-blocks, 16 h, 3 mat), 256 threads; LDS transpose.
// ---------------------------------------------------------------------------
__global__ __launch_bounds__(256) void cvt_w(
    const float* __restrict__ Wq, const float* __restrict__ Wk,
    const float* __restrict__ Wv, u16* __restrict__ Wt) {
    __shared__ u16 L[64][74];
    const int dblk = blockIdx.x, h = blockIdx.y, mat = blockIdx.z;
    const float* W = (mat == 0) ? Wq : (mat == 1) ? Wk : Wv;
    const int tid = threadIdx.x;
    {   // load 64(d) x 64(dk), coalesced, convert
        const int dl = tid >> 2, c = (tid & 3) * 16;
        const float* src = W + ((size_t)h * DM_ + dblk * 64 + dl) * D_ + c;
        #pragma unroll
        for (int g = 0; g < 2; g++)
            *(u16x8*)&L[dl][c + g * 8] = cvt8(src + g * 8);
    }
    __syncthreads();
    {   // write rows of Wt: row = dk, 16 d's per thread
        const int dkr = tid >> 2, g = tid & 3;
        u16 tmp[16];
        #pragma unroll
        for (int j = 0; j < 16; j++) tmp[j] = L[g * 16 + j][dkr];
        u16* dst = Wt + ((size_t)(mat * 16 + h) * 64 + dkr) * DM_ + dblk * 64 + g * 16;
        *(u16x8*)dst = *(u16x8*)tmp;
        *(u16x8*)(dst + 8) = *(u16x8*)(tmp + 8);
    }
}

// ---------------------------------------------------------------------------
// Projection GEMM: C[8192][3072] = xb @ Wt^T (Wt rows are C-columns).
// grid (64 m-tiles, 24 n-tiles), 256 thr = 4 waves 2x2, 128x128 tile, BK=64.
// m97 structure: global_load_lds dwordx4 staging, unpadded LDS + XOR swizzle
// (pre-swizzled source granule, read addr ^ (l16&7)<<4) -> conflict-free.
// Q (pre-scaled by 0.125*log2e for exp2-domain softmax), K -> [B,H,T,64];
// V -> transposed [B,H,64,T].
// ---------------------------------------------------------------------------
__global__ __launch_bounds__(256) void proj_kernel(
    const u16* __restrict__ xb, const u16* __restrict__ Wt,
    u16* __restrict__ Qc, u16* __restrict__ Kc, u16* __restrict__ Vtc)
{
    __shared__ __attribute__((aligned(16))) u16 As[128][64];   // [m][k] (swizzled)
    __shared__ __attribute__((aligned(16))) u16 Bs[128][64];   // [n][k] (swizzled)

    const int m0 = blockIdx.x * 128;
    const int n0 = blockIdx.y * 128;          // n = mat*1024 + h*64 + dk
    const int mat = n0 >> 10;
    const int tid  = threadIdx.x;
    const int wave = tid >> 6, lane = tid & 63;
    const int quad = lane >> 4, l16 = lane & 15;
    const int wm   = wave >> 1, wn = wave & 1;

    // staging geometry: chunk = it*4+wave (8 rows each); lane covers
    // row = chunk*8 + (lane>>3), physical 16B-granule = lane&7.
    // source granule pre-swizzled so read side XORs with (row&7)<<4.
    const int r8 = lane >> 3, g8 = lane & 7;
    const int gs = (g8 ^ r8) * 8;             // source col (u16 units)
    const int ax = (l16 & 7) << 4;            // read-side byte XOR
    u16* Asp = &As[0][0];
    u16* Bsp = &Bs[0][0];
    const char* Asb = (const char*)Asp;
    const char* Bsb = (const char*)Bsp;

    f32x4 acc[4][4];
    #pragma unroll
    for (int i = 0; i < 4; i++)
        #pragma unroll
        for (int j = 0; j < 4; j++) acc[i][j] = f32x4{0.f, 0.f, 0.f, 0.f};

    for (int kb = 0; kb < 16; kb++) {
        const int kbase = kb * 64;
        __syncthreads();
        #pragma unroll
        for (int it = 0; it < 4; it++) {
            const int row = it * 32 + wave * 8 + r8;
            const int ldo = (it * 4 + wave) * 512 + lane * 8;   // u16 units
            gld_lds16(xb + (size_t)(m0 + row) * DM_ + kbase + gs, Asp + ldo);
            gld_lds16(Wt + (size_t)(n0 + row) * DM_ + kbase + gs, Bsp + ldo);
        }
        __syncthreads();
        #pragma unroll
        for (int ks = 0; ks < 2; ks++) {
            u16x8 af[4], bf[4];
            #pragma unroll
            for (int i = 0; i < 4; i++)
                af[i] = *(const u16x8*)(Asb +
                    ((((wm * 64 + i * 16 + l16) * 64 + ks * 32 + quad * 8) * 2) ^ ax));
            #pragma unroll
            for (int j = 0; j < 4; j++)
                bf[j] = *(const u16x8*)(Bsb +
                    ((((wn * 64 + j * 16 + l16) * 64 + ks * 32 + quad * 8) * 2) ^ ax));
            #pragma unroll
            for (int i = 0; i < 4; i++)
                #pragma unroll
                for (int j = 0; j < 4; j++)
                    acc[i][j] = mfma16(af[i], bf[j], acc[i][j]);
        }
    }

    // epilogue: C/D row = quad*4+r, col = l16 (m89)
    #pragma unroll
    for (int i = 0; i < 4; i++) {
        #pragma unroll
        for (int j = 0; j < 4; j++) {
            #pragma unroll
            for (int r = 0; r < 4; r++) {
                const int m  = m0 + wm * 64 + i * 16 + quad * 4 + r;
                const int bb = m >> 11, t = m & (T_ - 1);
                const int nloc = wn * 64 + j * 16 + l16;
                const int h  = ((n0 & 1023) >> 6) + (nloc >> 6);
                const int dk = nloc & 63;
                float v = acc[i][j][r];
                if (mat == 0) {        // Q pre-scaled by dk^-0.5 * log2(e)
                    Qc[((size_t)(bb * H_ + h) * T_ + t) * D_ + dk] =
                        f2bf_hu(v * 0.18033688f);
                } else if (mat == 1) {
                    Kc[((size_t)(bb * H_ + h) * T_ + t) * D_ + dk] = f2bf_hu(v);
                } else {
                    Vtc[((size_t)(bb * H_ + h) * D_ + dk) * T_ + t] = f2bf_hu(v);
                }
            }
        }
    }
}

// ---------------------------------------------------------------------------
// Flash attention, paired 64-row q-tiles: grid (16 pairs, 16 heads, 4 batch)
// x 256.  Block handles q-tiles {bx, 31-bx} (64 rows each) -> exactly 33
// s-tiles per block, 1024 blocks = 4/CU (2x the R10 occupancy).  Wave owns
// 16 q-rows (one m-frag).  K/V staged by global_load_lds + XOR swizzle;
// softmax in exp2 domain; defer-max rescale skip.
// ---------------------------------------------------------------------------
__global__ __launch_bounds__(256, 4) void attn_kernel(
    const u16* __restrict__ Qc, const u16* __restrict__ Kc,
    const u16* __restrict__ Vtc, float* __restrict__ out)
{
    __shared__ __attribute__((aligned(16))) u16 Ks[64][64];   // swizzled [s][k]
    __shared__ __attribute__((aligned(16))) u16 Vs[64][64];   // swizzled [v][s]
    __shared__ __attribute__((aligned(16))) u16 Ps[4][16][72];// per-wave P tile

    const int h = blockIdx.y, b = blockIdx.z;
    const int tid = threadIdx.x, wave = tid >> 6, lane = tid & 63;
    const int quad = lane >> 4, l16 = lane & 15;
    const int r8 = lane >> 3, g8 = lane & 7;
    const int gs = (g8 ^ r8) * 8;             // pre-swizzled source col (u16)
    const int ax = (l16 & 7) << 4;            // read-side byte XOR

    const u16* Qbh = Qc + (size_t)(b * H_ + h) * T_ * D_;
    const u16* Kbh = Kc + (size_t)(b * H_ + h) * T_ * D_;
    const u16* Vbh = Vtc + (size_t)(b * H_ + h) * D_ * T_;
    u16* Ksp = &Ks[0][0];
    u16* Vsp = &Vs[0][0];
    const char* Ksb = (const char*)Ksp;
    const char* Vsb = (const char*)Vsp;

    for (int ph = 0; ph < 2; ph++) {
        const int qt = ph ? (31 - blockIdx.x) : blockIdx.x;
        const int q0 = qt * 64;

        // Q fragments (already scaled by log2e/8 at projection)
        u16x8 qf[2];
        #pragma unroll
        for (int ks = 0; ks < 2; ks++)
            qf[ks] = *(const u16x8*)(Qbh +
                (size_t)(q0 + wave * 16 + l16) * D_ + ks * 32 + quad * 8);

        f32x4 o[4];
        float mi[4], li[4];
        #pragma unroll
        for (int i = 0; i < 4; i++) {
            o[i] = f32x4{0.f, 0.f, 0.f, 0.f};
            mi[i] = -1e30f; li[i] = 0.f;
        }

        const int nst = qt + 1;
        for (int st = 0; st < nst; st++) {
            const int s0 = st * 64;
            __syncthreads();
            #pragma unroll
            for (int p = 0; p < 2; p++) {
                const int row = p * 32 + wave * 8 + r8;
                const int ldo = (p * 4 + wave) * 512 + lane * 8;   // u16 units
                gld_lds16(Kbh + (size_t)(s0 + row) * D_ + gs, Ksp + ldo);
                gld_lds16(Vbh + (size_t)row * T_ + s0 + gs,  Vsp + ldo);
            }
            __syncthreads();

            // S = Q K^T   (log2 domain)
            f32x4 s[4];
            #pragma unroll
            for (int i = 0; i < 4; i++) s[i] = f32x4{0.f, 0.f, 0.f, 0.f};
            #pragma unroll
            for (int ks = 0; ks < 2; ks++) {
                #pragma unroll
                for (int nt = 0; nt < 4; nt++) {
                    u16x8 bfr = *(const u16x8*)(Ksb +
                        ((((nt * 16 + l16) * 64 + ks * 32 + quad * 8) * 2) ^ ax));
                    s[nt] = mfma16(qf[ks], bfr, s[nt]);
                }
            }

            // causal mask — diagonal s-tile only (64-row q-tile = 1 s-tile)
            if (st == nst - 1) {
                #pragma unroll
                for (int nt = 0; nt < 4; nt++) {
                    const int sc = s0 + nt * 16 + l16;
                    #pragma unroll
                    for (int r = 0; r < 4; r++) {
                        const int qr = q0 + wave * 16 + quad * 4 + r;
                        if (sc > qr) s[nt][r] = -1e30f;
                    }
                }
            }

            // online softmax (row = quad*4+r; cols across quad's 16 lanes)
            #pragma unroll
            for (int r = 0; r < 4; r++) {
                float mx = fmaxf(fmaxf(s[0][r], s[1][r]),
                                 fmaxf(s[2][r], s[3][r]));
                #pragma unroll
                for (int off = 1; off < 16; off <<= 1)
                    mx = fmaxf(mx, __shfl_xor(mx, off));
                if (__any(mx > mi[r])) {       // defer-max: skip rescale pass
                    const float mn = fmaxf(mi[r], mx);
                    const float alpha = EXP2(mi[r] - mn);
                    li[r] *= alpha;
                    mi[r] = mn;
                    #pragma unroll
                    for (int nt = 0; nt < 4; nt++) o[nt][r] *= alpha;
                }
                float sum = 0.f;
                #pragma unroll
                for (int nt = 0; nt < 4; nt++) {
                    const float p = EXP2(s[nt][r] - mi[r]);
                    s[nt][r] = p;
                    sum += p;
                }
                #pragma unroll
                for (int off = 1; off < 16; off <<= 1)
                    sum += __shfl_xor(sum, off);
                li[r] += sum;
            }

            // P: C-layout -> wave-private LDS (no barrier: intra-wave DS order)
            #pragma unroll
            for (int nt = 0; nt < 4; nt++)
                #pragma unroll
                for (int r = 0; r < 4; r++)
                    Ps[wave][quad * 4 + r][nt * 16 + l16] = f2bf_hu(s[nt][r]);

            // O += P V
            #pragma unroll
            for (int ks = 0; ks < 2; ks++) {
                u16x8 a = *(const u16x8*)&Ps[wave][l16][ks * 32 + quad * 8];
                #pragma unroll
                for (int nt = 0; nt < 4; nt++) {
                    u16x8 bv = *(const u16x8*)(Vsb +
                        ((((nt * 16 + l16) * 64 + ks * 32 + quad * 8) * 2) ^ ax));
                    o[nt] = mfma16(a, bv, o[nt]);
                }
            }
        }

        // f32 output
        #pragma unroll
        for (int r = 0; r < 4; r++) {
            const float inv = 1.0f / li[r];
            const int qr = q0 + wave * 16 + quad * 4 + r;
            #pragma unroll
            for (int nt = 0; nt < 4; nt++)
                out[(size_t)(b * T_ + qr) * DMO + h * D_ + nt * 16 + l16] =
                    o[nt][r] * inv;
        }
    }
}

// ---------------------------------------------------------------------------
extern "C" void kernel_launch(void* const* d_in, const int* in_sizes, int n_in,
                              void* d_out, int out_size, void* d_ws, size_t ws_size,
                              hipStream_t stream) {
    int xi = 0, wi[3] = {1, 2, 3};
    {
        int k = 0, found = 0;
        for (int i = 0; i < n_in && i < 8; i++) {
            if (in_sizes[i] == B_ * T_ * DM_) { xi = i; found = 1; }
            else if (in_sizes[i] == H_ * DM_ * D_ && k < 3) wi[k++] = i;
        }
        if (!found || k != 3) { xi = 0; wi[0] = 1; wi[1] = 2; wi[2] = 3; }
    }
    const float* x  = (const float*)d_in[xi];
    const float* Wq = (const float*)d_in[wi[0]];
    const float* Wk = (const float*)d_in[wi[1]];
    const float* Wv = (const float*)d_in[wi[2]];
    float* out = (float*)d_out;

    // bf16 staging scratch lives in d_out (dead before attn writes it):
    //   xb = 8.4M u16 (16.8 MB), Wt = 3.1M u16 (6.3 MB) -> 23.1 of 33.5 MB.
    u16* xb = (u16*)d_out;
    u16* Wt = xb + (size_t)B_ * T_ * DM_;
    // ws: Q + K + Vt bf16 = 50.3 MB (R8-verified to fit).
    const size_t per = (size_t)B_ * H_ * T_ * D_;
    u16* Qc  = (u16*)d_ws;
    u16* Kc  = Qc + per;
    u16* Vtc = Kc + per;

    cvt_x<<<1024, 256, 0, stream>>>(x, xb);
    cvt_w<<<dim3(16, 16, 3), 256, 0, stream>>>(Wq, Wk, Wv, Wt);
    proj_kernel<<<dim3(64, 24), 256, 0, stream>>>(xb, Wt, Qc, Kc, Vtc);
    attn_kernel<<<dim3(16, 16, 4), 256, 0, stream>>>(Qc, Kc, Vtc, out);
}

// Round 2
// 283.805 us; speedup vs baseline: 1.0545x; 1.0042x over previous
//
#include <hip/hip_runtime.h>

// MHA forward.  B=4 T=2048 DM=1024 H=16 DK=DV=64.  f32 in / f32 out.
// R12: swapped-operand attention (m214/T12 structure) at 32x32x16:
//      S^T = mfma(K,Q) -> each lane owns half a P-row in registers; softmax
//      is in-lane tree + one shfl_xor(32); P redistributed to PV B-frags by
//      cvt-pack + hi-swap (NO P LDS).  O^T = mfma(V^T, P^T); V^T comes
//      straight from proj's Vt layout.  2048 1-q-tile blocks (128 thr,
//      2 waves x 32q), big-qt-first for LPT balance, XCD-swizzled grid.
//      Defer-max THR=8 (T13).  proj: + XCD swizzle (bijective, 1536%8==0).

#define B_  4
#define T_  2048
#define DM_ 1024
#define H_  16
#define D_  64
#define DMO 1024   // out row stride = H_*D_

typedef unsigned short u16;
typedef unsigned int   u32;
typedef u16   u16x8  __attribute__((ext_vector_type(8)));
typedef short s16x8  __attribute__((ext_vector_type(8)));
typedef float f32x4  __attribute__((ext_vector_type(4)));
typedef float f32x16 __attribute__((ext_vector_type(16)));
typedef u32   u32x4  __attribute__((ext_vector_type(4)));

#if __has_builtin(__builtin_amdgcn_exp2f)
#define EXP2(x) __builtin_amdgcn_exp2f(x)
#else
#define EXP2(x) __expf((x) * 0.69314718f)
#endif

__device__ __forceinline__ u16 f2bf_hu(float f) {   // round-half-up (ties rare)
    u32 u = __builtin_bit_cast(u32, f) + 0x8000u;
    return (u16)(u >> 16);
}
// pack two f32 -> dword of two bf16 (lo,hi), 3 VALU ops
__device__ __forceinline__ u32 pk2(float lo, float hi) {
    u32 ul = __builtin_bit_cast(u32, lo) + 0x8000u;
    u32 uh = __builtin_bit_cast(u32, hi) + 0x8000u;
    return __builtin_amdgcn_perm(uh, ul, 0x07060302);  // [uh.hi16 : ul.hi16]
}
__device__ __forceinline__ u16x8 cvt8(const float* s) {
    f32x4 a = *(const f32x4*)s;
    f32x4 b = *(const f32x4*)(s + 4);
    u32x4 r { pk2(a[0], a[1]), pk2(a[2], a[3]), pk2(b[0], b[1]), pk2(b[2], b[3]) };
    return __builtin_bit_cast(u16x8, r);
}
__device__ __forceinline__ f32x4 mfma16(u16x8 a, u16x8 b, f32x4 c) {
    return __builtin_amdgcn_mfma_f32_16x16x32_bf16(
        __builtin_bit_cast(s16x8, a), __builtin_bit_cast(s16x8, b), c, 0, 0, 0);
}
__device__ __forceinline__ f32x16 mfma32(u16x8 a, u16x8 b, f32x16 c) {
    return __builtin_amdgcn_mfma_f32_32x32x16_bf16(
        __builtin_bit_cast(s16x8, a), __builtin_bit_cast(s16x8, b), c, 0, 0, 0);
}
// async global->LDS, 16B per lane.  LDS dest must be wave-uniform base + lane*16.
__device__ __forceinline__ void gld_lds16(const u16* g, u16* l) {
    __builtin_amdgcn_global_load_lds(
        (const __attribute__((address_space(1))) u32*)g,
        (__attribute__((address_space(3))) u32*)l, 16, 0, 0);
}

// ---------------------------------------------------------------------------
// cvt_x: x f32 [8192][1024] -> xb bf16 (same layout).  1024 blocks x 256.
// ---------------------------------------------------------------------------
__global__ __launch_bounds__(256) void cvt_x(const float* __restrict__ x,
                                             u16* __restrict__ xb) {
    size_t i0 = ((size_t)blockIdx.x * 256 + threadIdx.x) * 32;
    #pragma unroll
    for (int c = 0; c < 4; c++)
        *(u16x8*)(xb + i0 + c * 8) = cvt8(x + i0 + c * 8);
}

// ---------------------------------------------------------------------------
// cvt_w: W[mat][h][d=1024][dk=64] f32 -> Wt[(mat*16+h)*64+dk][d=1024] bf16.
// grid (16 d-blocks, 16 h, 3 mat), 256 threads; LDS transpose.
// ---------------------------------------------------------------------------
__global__ __launch_bounds__(256) void cvt_w(
    const float* __restrict__ Wq, const float* __restrict__ Wk,
    const float* __restrict__ Wv, u16* __restrict__ Wt) {
    __shared__ u16 L[64][74];
    const int dblk = blockIdx.x, h = blockIdx.y, mat = blockIdx.z;
    const float* W = (mat == 0) ? Wq : (mat == 1) ? Wk : Wv;
    const int tid = threadIdx.x;
    {   // load 64(d) x 64(dk), coalesced, convert
        const int dl = tid >> 2, c = (tid & 3) * 16;
        const float* src = W + ((size_t)h * DM_ + dblk * 64 + dl) * D_ + c;
        #pragma unroll
        for (int g = 0; g < 2; g++)
            *(u16x8*)&L[dl][c + g * 8] = cvt8(src + g * 8);
    }
    __syncthreads();
    {   // write rows of Wt: row = dk, 16 d's per thread
        const int dkr = tid >> 2, g = tid & 3;
        u16 tmp[16];
        #pragma unroll
        for (int j = 0; j < 16; j++) tmp[j] = L[g * 16 + j][dkr];
        u16* dst = Wt + ((size_t)(mat * 16 + h) * 64 + dkr) * DM_ + dblk * 64 + g * 16;
        *(u16x8*)dst = *(u16x8*)tmp;
        *(u16x8*)(dst + 8) = *(u16x8*)(tmp + 8);
    }
}

// ---------------------------------------------------------------------------
// Projection GEMM: C[8192][3072] = xb @ Wt^T (Wt rows are C-columns).
// 1536 blocks (XCD-swizzled), 256 thr = 4 waves 2x2, 128x128 tile, BK=64.
// m97 structure: global_load_lds dwordx4 staging, unpadded LDS + XOR swizzle.
// Q (pre-scaled by 0.125*log2e for exp2-domain softmax), K -> [B,H,T,64];
// V -> transposed [B,H,64,T].
// ---------------------------------------------------------------------------
__global__ __launch_bounds__(256) void proj_kernel(
    const u16* __restrict__ xb, const u16* __restrict__ Wt,
    u16* __restrict__ Qc, u16* __restrict__ Kc, u16* __restrict__ Vtc)
{
    __shared__ __attribute__((aligned(16))) u16 As[128][64];   // [m][k] (swizzled)
    __shared__ __attribute__((aligned(16))) u16 Bs[128][64];   // [n][k] (swizzled)

    // XCD-aware swizzle: 1536 blocks, 192 consecutive per XCD (bijective).
    const int pb = blockIdx.x;
    const int wg = (pb & 7) * 192 + (pb >> 3);
    const int m0 = (wg & 63) * 128;
    const int n0 = (wg >> 6) * 128;           // n = mat*1024 + h*64 + dk
    const int mat = n0 >> 10;
    const int tid  = threadIdx.x;
    const int wave = tid >> 6, lane = tid & 63;
    const int quad = lane >> 4, l16 = lane & 15;
    const int wm   = wave >> 1, wn = wave & 1;

    const int r8 = lane >> 3, g8 = lane & 7;
    const int gs = (g8 ^ r8) * 8;             // pre-swizzled source col (u16)
    const int ax = (l16 & 7) << 4;            // read-side byte XOR
    u16* Asp = &As[0][0];
    u16* Bsp = &Bs[0][0];
    const char* Asb = (const char*)Asp;
    const char* Bsb = (const char*)Bsp;

    f32x4 acc[4][4];
    #pragma unroll
    for (int i = 0; i < 4; i++)
        #pragma unroll
        for (int j = 0; j < 4; j++) acc[i][j] = f32x4{0.f, 0.f, 0.f, 0.f};

    for (int kb = 0; kb < 16; kb++) {
        const int kbase = kb * 64;
        __syncthreads();
        #pragma unroll
        for (int it = 0; it < 4; it++) {
            const int row = it * 32 + wave * 8 + r8;
            const int ldo = (it * 4 + wave) * 512 + lane * 8;   // u16 units
            gld_lds16(xb + (size_t)(m0 + row) * DM_ + kbase + gs, Asp + ldo);
            gld_lds16(Wt + (size_t)(n0 + row) * DM_ + kbase + gs, Bsp + ldo);
        }
        __syncthreads();
        #pragma unroll
        for (int ks = 0; ks < 2; ks++) {
            u16x8 af[4], bf[4];
            #pragma unroll
            for (int i = 0; i < 4; i++)
                af[i] = *(const u16x8*)(Asb +
                    ((((wm * 64 + i * 16 + l16) * 64 + ks * 32 + quad * 8) * 2) ^ ax));
            #pragma unroll
            for (int j = 0; j < 4; j++)
                bf[j] = *(const u16x8*)(Bsb +
                    ((((wn * 64 + j * 16 + l16) * 64 + ks * 32 + quad * 8) * 2) ^ ax));
            #pragma unroll
            for (int i = 0; i < 4; i++)
                #pragma unroll
                for (int j = 0; j < 4; j++)
                    acc[i][j] = mfma16(af[i], bf[j], acc[i][j]);
        }
    }

    // epilogue: C/D row = quad*4+r, col = l16 (m89)
    #pragma unroll
    for (int i = 0; i < 4; i++) {
        #pragma unroll
        for (int j = 0; j < 4; j++) {
            #pragma unroll
            for (int r = 0; r < 4; r++) {
                const int m  = m0 + wm * 64 + i * 16 + quad * 4 + r;
                const int bb = m >> 11, t = m & (T_ - 1);
                const int nloc = wn * 64 + j * 16 + l16;
                const int h  = ((n0 & 1023) >> 6) + (nloc >> 6);
                const int dk = nloc & 63;
                float v = acc[i][j][r];
                if (mat == 0) {        // Q pre-scaled by dk^-0.5 * log2(e)
                    Qc[((size_t)(bb * H_ + h) * T_ + t) * D_ + dk] =
                        f2bf_hu(v * 0.18033688f);
                } else if (mat == 1) {
                    Kc[((size_t)(bb * H_ + h) * T_ + t) * D_ + dk] = f2bf_hu(v);
                } else {
                    Vtc[((size_t)(bb * H_ + h) * D_ + dk) * T_ + t] = f2bf_hu(v);
                }
            }
        }
    }
}

// ---------------------------------------------------------------------------
// Flash attention, swapped-operand (S^T = K.Q^T via 32x32x16 MFMA).
// 2048 blocks x 128 thr (2 waves x 32 q-rows = 64-row q-tile), big-qt first
// (LPT balance), XCD-swizzled so each XCD keeps 8 (b,h) K/V sets in L2.
// Lane = q-column; each lane holds half a P-row in registers ->
// softmax = in-lane tree + one shfl_xor(32); P -> PV B-frags by pk2+hi-swap.
// ---------------------------------------------------------------------------
__global__ __launch_bounds__(128, 3) void attn_kernel(
    const u16* __restrict__ Qc, const u16* __restrict__ Kc,
    const u16* __restrict__ Vtc, float* __restrict__ out)
{
    __shared__ __attribute__((aligned(16))) u16 Ks[64][64];   // swizzled [s][k]
    __shared__ __attribute__((aligned(16))) u16 Vs[64][64];   // swizzled [dv][s]

    const int pb = blockIdx.x;
    const int lb = (pb & 7) * 256 + (pb >> 3);   // XCD swizzle (2048%8==0)
    const int qt = 31 - (lb & 31);               // big q-tiles scheduled first
    const int h  = (lb >> 5) & 15, b = lb >> 9;

    const int tid = threadIdx.x, w = tid >> 6, lane = tid & 63;
    const int l31 = lane & 31, hi = lane >> 5;
    const int r8 = lane >> 3, g8 = lane & 7;
    const int gs = (g8 ^ r8) * 8;             // pre-swizzled source col (u16)
    const int ax = (l31 & 7) << 4;            // read-side byte XOR

    const u16* Qbh = Qc + (size_t)(b * H_ + h) * T_ * D_;
    const u16* Kbh = Kc + (size_t)(b * H_ + h) * T_ * D_;
    const u16* Vbh = Vtc + (size_t)(b * H_ + h) * D_ * T_;
    u16* Ksp = &Ks[0][0];
    u16* Vsp = &Vs[0][0];
    const char* Ksb = (const char*)Ksp;
    const char* Vsb = (const char*)Vsp;

    const int q0 = qt * 64;
    const int qrow = q0 + w * 32 + l31;
    const int qloc = w * 32 + l31;            // q within the 64-row tile

    // Q B-frags (col=lane&31=q, k = hi*8+e per 16-chunk), scaled at proj.
    u16x8 qf[4];
    #pragma unroll
    for (int ks = 0; ks < 4; ks++)
        qf[ks] = *(const u16x8*)(Qbh + (size_t)qrow * D_ + ks * 16 + hi * 8);

    f32x16 ot0, ot1;                          // O^T accum: dv-tiles 0..31/32..63
    #pragma unroll
    for (int r = 0; r < 16; r++) { ot0[r] = 0.f; ot1[r] = 0.f; }
    float mi = -1e30f, li = 0.f;

    const int nst = qt + 1;
    for (int st = 0; st < nst; st++) {
        const int sbase = st * 64;
        __syncthreads();
        #pragma unroll
        for (int i = 0; i < 4; i++) {
            const int seg = i * 2 + w;        // 8 segs of 8 rows each
            const int row = seg * 8 + r8;
            const int ldo = seg * 512 + lane * 8;               // u16 units
            gld_lds16(Kbh + (size_t)(sbase + row) * D_ + gs, Ksp + ldo);
            gld_lds16(Vbh + (size_t)row * T_ + sbase + gs,  Vsp + ldo);
        }
        __syncthreads();

        // S^T = K . Q^T   (two 32-s tiles, log2 domain)
        f32x16 st0, st1;
        #pragma unroll
        for (int r = 0; r < 16; r++) { st0[r] = 0.f; st1[r] = 0.f; }
        #pragma unroll
        for (int ks = 0; ks < 4; ks++) {
            const int co = (ks * 16 + hi * 8) * 2;              // byte col
            u16x8 k0 = *(const u16x8*)(Ksb + ((l31 * 128 + co) ^ ax));
            u16x8 k1 = *(const u16x8*)(Ksb + (((32 + l31) * 128 + co) ^ ax));
            st0 = mfma32(k0, qf[ks], st0);
            st1 = mfma32(k1, qf[ks], st1);
        }

        // causal mask — diagonal tile only (sbase == q0 there).
        // S^T: row s_local = (r&3)+8*(r>>2)+4*hi (+32 for st1), col q = qloc.
        if (st == nst - 1) {
            #pragma unroll
            for (int r = 0; r < 16; r++) {
                const int sl = (r & 3) + 8 * (r >> 2) + 4 * hi;
                if (sl > qloc)      st0[r] = -1e30f;
                if (sl + 32 > qloc) st1[r] = -1e30f;
            }
        }

        // online softmax: in-lane over 32 + one hi-swap
        float mx = -1e30f;
        #pragma unroll
        for (int r = 0; r < 16; r++) mx = fmaxf(mx, fmaxf(st0[r], st1[r]));
        mx = fmaxf(mx, __shfl_xor(mx, 32));
        if (!__all(mx - mi <= 8.f)) {         // defer-max (T13, THR=8)
            const float mn = fmaxf(mi, mx);
            const float al = EXP2(mi - mn);
            li *= al;
            #pragma unroll
            for (int r = 0; r < 16; r++) { ot0[r] *= al; ot1[r] *= al; }
            mi = mn;
        }
        float sum = 0.f;
        #pragma unroll
        for (int r = 0; r < 16; r++) {
            const float p0 = EXP2(st0[r] - mi);
            const float p1 = EXP2(st1[r] - mi);
            st0[r] = p0; st1[r] = p1;
            sum += p0 + p1;
        }
        sum += __shfl_xor(sum, 32);
        li += sum;

        // P^T -> PV B-frags: lane (q,hi) holds s {4hi+0..3, 8+4hi+0..3} per
        // 16-chunk; needs {8hi..8hi+7}.  pk2 pairs + swap d-words across hi.
        u16x8 pb4[4];
        #define PACK(SRC, C, OUT) {                                           \
            u32 d0 = pk2(SRC[8*(C)+0], SRC[8*(C)+1]);                         \
            u32 d1 = pk2(SRC[8*(C)+2], SRC[8*(C)+3]);                         \
            u32 d2 = pk2(SRC[8*(C)+4], SRC[8*(C)+5]);                         \
            u32 d3 = pk2(SRC[8*(C)+6], SRC[8*(C)+7]);                         \
            u32 e0 = __shfl_xor(hi ? d0 : d2, 32);                            \
            u32 e1 = __shfl_xor(hi ? d1 : d3, 32);                            \
            u32x4 wds{ hi ? e0 : d0, hi ? e1 : d1,                            \
                       hi ? d2 : e0, hi ? d3 : e1 };                          \
            OUT = __builtin_bit_cast(u16x8, wds); }
        PACK(st0, 0, pb4[0]); PACK(st0, 1, pb4[1]);
        PACK(st1, 0, pb4[2]); PACK(st1, 1, pb4[3]);
        #undef PACK

        // O^T += V^T . P^T  (A rows = dv, k = s)
        #pragma unroll
        for (int kc = 0; kc < 4; kc++) {
            const int co = (kc * 16 + hi * 8) * 2;
            u16x8 v0 = *(const u16x8*)(Vsb + ((l31 * 128 + co) ^ ax));
            u16x8 v1 = *(const u16x8*)(Vsb + (((32 + l31) * 128 + co) ^ ax));
            ot0 = mfma32(v0, pb4[kc], ot0);
            ot1 = mfma32(v1, pb4[kc], ot1);
        }
    }

    // output: O^T reg r -> dv = td*32 + 16c + 8hf + 4hi + j, q = qrow
    const float inv = 1.0f / li;
    float* orow = out + (size_t)(b * T_ + qrow) * DMO + h * D_;
    #pragma unroll
    for (int c = 0; c < 2; c++)
        #pragma unroll
        for (int hf = 0; hf < 2; hf++) {
            f32x4 v0, v1;
            #pragma unroll
            for (int j = 0; j < 4; j++) {
                v0[j] = ot0[c * 8 + hf * 4 + j] * inv;
                v1[j] = ot1[c * 8 + hf * 4 + j] * inv;
            }
            *(f32x4*)(orow + c * 16 + hf * 8 + hi * 4)      = v0;
            *(f32x4*)(orow + 32 + c * 16 + hf * 8 + hi * 4) = v1;
        }
}

// ---------------------------------------------------------------------------
extern "C" void kernel_launch(void* const* d_in, const int* in_sizes, int n_in,
                              void* d_out, int out_size, void* d_ws, size_t ws_size,
                              hipStream_t stream) {
    int xi = 0, wi[3] = {1, 2, 3};
    {
        int k = 0, found = 0;
        for (int i = 0; i < n_in && i < 8; i++) {
            if (in_sizes[i] == B_ * T_ * DM_) { xi = i; found = 1; }
            else if (in_sizes[i] == H_ * DM_ * D_ && k < 3) wi[k++] = i;
        }
        if (!found || k != 3) { xi = 0; wi[0] = 1; wi[1] = 2; wi[2] = 3; }
    }
    const float* x  = (const float*)d_in[xi];
    const float* Wq = (const float*)d_in[wi[0]];
    const float* Wk = (const float*)d_in[wi[1]];
    const float* Wv = (const float*)d_in[wi[2]];
    float* out = (float*)d_out;

    // bf16 staging scratch lives in d_out (dead before attn writes it):
    //   xb = 8.4M u16 (16.8 MB), Wt = 3.1M u16 (6.3 MB) -> 23.1 of 33.5 MB.
    u16* xb = (u16*)d_out;
    u16* Wt = xb + (size_t)B_ * T_ * DM_;
    // ws: Q + K + Vt bf16 = 50.3 MB (R8-verified to fit).
    const size_t per = (size_t)B_ * H_ * T_ * D_;
    u16* Qc  = (u16*)d_ws;
    u16* Kc  = Qc + per;
    u16* Vtc = Kc + per;

    cvt_x<<<1024, 256, 0, stream>>>(x, xb);
    cvt_w<<<dim3(16, 16, 3), 256, 0, stream>>>(Wq, Wk, Wv, Wt);
    proj_kernel<<<1536, 256, 0, stream>>>(xb, Wt, Qc, Kc, Vtc);
    attn_kernel<<<2048, 128, 0, stream>>>(Qc, Kc, Vtc, out);
}

// Round 3
// 251.377 us; speedup vs baseline: 1.1905x; 1.1290x over previous
//
#include <hip/hip_runtime.h>

// MHA forward.  B=4 T=2048 DM=1024 H=16 DK=DV=64.  f32 in / f32 out.
// R13: proj pipeline + epilogue rework.
//   (1) K-loop -> T3 minimum-2-phase: double-buffered LDS (As0/Bs0,As1/Bs1
//       statically distinct so gld_lds(next) and ds_read(cur) provably
//       don't alias), STAGE(next) issued BEFORE compute(cur), single
//       __syncthreads per K-step (implicit vmcnt(0) drains after the
//       compute window -> staging hides under MFMA).  m228d/m230: 622-682
//       TF at this structure vs measured 437.
//   (2) epilogue: per-mat MFMA operand order so acc's 4 regs are memory-
//       consecutive (Q/K: swapped -> r walks dk; V: normal -> r walks t);
//       pk2-pack to 8B dwordx2 stores.  16 stores/thread instead of 64
//       scalar 2B + 64-bit addr math per element.
//   attn (R12 swapped-operand, <117us) and cvt kernels unchanged.

#define B_  4
#define T_  2048
#define DM_ 1024
#define H_  16
#define D_  64
#define DMO 1024   // out row stride = H_*D_

typedef unsigned short u16;
typedef unsigned int   u32;
typedef u16   u16x8  __attribute__((ext_vector_type(8)));
typedef short s16x8  __attribute__((ext_vector_type(8)));
typedef float f32x4  __attribute__((ext_vector_type(4)));
typedef float f32x16 __attribute__((ext_vector_type(16)));
typedef u32   u32x2  __attribute__((ext_vector_type(2)));
typedef u32   u32x4  __attribute__((ext_vector_type(4)));

#if __has_builtin(__builtin_amdgcn_exp2f)
#define EXP2(x) __builtin_amdgcn_exp2f(x)
#else
#define EXP2(x) __expf((x) * 0.69314718f)
#endif

__device__ __forceinline__ u16 f2bf_hu(float f) {   // round-half-up (ties rare)
    u32 u = __builtin_bit_cast(u32, f) + 0x8000u;
    return (u16)(u >> 16);
}
// pack two f32 -> dword of two bf16 (lo,hi), 3 VALU ops
__device__ __forceinline__ u32 pk2(float lo, float hi) {
    u32 ul = __builtin_bit_cast(u32, lo) + 0x8000u;
    u32 uh = __builtin_bit_cast(u32, hi) + 0x8000u;
    return __builtin_amdgcn_perm(uh, ul, 0x07060302);  // [uh.hi16 : ul.hi16]
}
__device__ __forceinline__ u16x8 cvt8(const float* s) {
    f32x4 a = *(const f32x4*)s;
    f32x4 b = *(const f32x4*)(s + 4);
    u32x4 r { pk2(a[0], a[1]), pk2(a[2], a[3]), pk2(b[0], b[1]), pk2(b[2], b[3]) };
    return __builtin_bit_cast(u16x8, r);
}
__device__ __forceinline__ f32x4 mfma16(u16x8 a, u16x8 b, f32x4 c) {
    return __builtin_amdgcn_mfma_f32_16x16x32_bf16(
        __builtin_bit_cast(s16x8, a), __builtin_bit_cast(s16x8, b), c, 0, 0, 0);
}
__device__ __forceinline__ f32x16 mfma32(u16x8 a, u16x8 b, f32x16 c) {
    return __builtin_amdgcn_mfma_f32_32x32x16_bf16(
        __builtin_bit_cast(s16x8, a), __builtin_bit_cast(s16x8, b), c, 0, 0, 0);
}
// async global->LDS, 16B per lane.  LDS dest must be wave-uniform base + lane*16.
__device__ __forceinline__ void gld_lds16(const u16* g, u16* l) {
    __builtin_amdgcn_global_load_lds(
        (const __attribute__((address_space(1))) u32*)g,
        (__attribute__((address_space(3))) u32*)l, 16, 0, 0);
}

// ---------------------------------------------------------------------------
// cvt_x: x f32 [8192][1024] -> xb bf16 (same layout).  1024 blocks x 256.
// ---------------------------------------------------------------------------
__global__ __launch_bounds__(256) void cvt_x(const float* __restrict__ x,
                                             u16* __restrict__ xb) {
    size_t i0 = ((size_t)blockIdx.x * 256 + threadIdx.x) * 32;
    #pragma unroll
    for (int c = 0; c < 4; c++)
        *(u16x8*)(xb + i0 + c * 8) = cvt8(x + i0 + c * 8);
}

// ---------------------------------------------------------------------------
// cvt_w: W[mat][h][d=1024][dk=64] f32 -> Wt[(mat*16+h)*64+dk][d=1024] bf16.
// grid (16 d-blocks, 16 h, 3 mat), 256 threads; LDS transpose.
// ---------------------------------------------------------------------------
__global__ __launch_bounds__(256) void cvt_w(
    const float* __restrict__ Wq, const float* __restrict__ Wk,
    const float* __restrict__ Wv, u16* __restrict__ Wt) {
    __shared__ u16 L[64][74];
    const int dblk = blockIdx.x, h = blockIdx.y, mat = blockIdx.z;
    const float* W = (mat == 0) ? Wq : (mat == 1) ? Wk : Wv;
    const int tid = threadIdx.x;
    {   // load 64(d) x 64(dk), coalesced, convert
        const int dl = tid >> 2, c = (tid & 3) * 16;
        const float* src = W + ((size_t)h * DM_ + dblk * 64 + dl) * D_ + c;
        #pragma unroll
        for (int g = 0; g < 2; g++)
            *(u16x8*)&L[dl][c + g * 8] = cvt8(src + g * 8);
    }
    __syncthreads();
    {   // write rows of Wt: row = dk, 16 d's per thread
        const int dkr = tid >> 2, g = tid & 3;
        u16 tmp[16];
        #pragma unroll
        for (int j = 0; j < 16; j++) tmp[j] = L[g * 16 + j][dkr];
        u16* dst = Wt + ((size_t)(mat * 16 + h) * 64 + dkr) * DM_ + dblk * 64 + g * 16;
        *(u16x8*)dst = *(u16x8*)tmp;
        *(u16x8*)(dst + 8) = *(u16x8*)(tmp + 8);
    }
}

// ---------------------------------------------------------------------------
// Projection GEMM: C[8192][3072] = xb @ Wt^T (Wt rows are C-columns).
// 1536 blocks (XCD-swizzled), 256 thr = 4 waves 2x2, 128x128 tile, BK=64.
// ---------------------------------------------------------------------------
template<int SWAP>
__device__ __forceinline__ void pcompute(const char* Asb, const char* Bsb,
                                         int wm, int wn, int quad, int l16,
                                         int ax, f32x4 (&acc)[4][4]) {
    #pragma unroll
    for (int ks = 0; ks < 2; ks++) {
        u16x8 af[4], bf[4];
        #pragma unroll
        for (int i = 0; i < 4; i++)
            af[i] = *(const u16x8*)(Asb +
                ((((wm * 64 + i * 16 + l16) * 64 + ks * 32 + quad * 8) * 2) ^ ax));
        #pragma unroll
        for (int j = 0; j < 4; j++)
            bf[j] = *(const u16x8*)(Bsb +
                ((((wn * 64 + j * 16 + l16) * 64 + ks * 32 + quad * 8) * 2) ^ ax));
        #pragma unroll
        for (int i = 0; i < 4; i++)
            #pragma unroll
            for (int j = 0; j < 4; j++)
                acc[i][j] = SWAP ? mfma16(bf[j], af[i], acc[i][j])
                                 : mfma16(af[i], bf[j], acc[i][j]);
    }
}

__global__ __launch_bounds__(256) void proj_kernel(
    const u16* __restrict__ xb, const u16* __restrict__ Wt,
    u16* __restrict__ Qc, u16* __restrict__ Kc, u16* __restrict__ Vtc)
{
    // double-buffer: statically distinct arrays -> provable no-alias between
    // gld_lds(next buffer) and ds_read(current buffer).  64 KB total.
    __shared__ __attribute__((aligned(16))) u16 As0[128][64];
    __shared__ __attribute__((aligned(16))) u16 Bs0[128][64];
    __shared__ __attribute__((aligned(16))) u16 As1[128][64];
    __shared__ __attribute__((aligned(16))) u16 Bs1[128][64];

    // XCD-aware swizzle: 1536 blocks, 192 consecutive per XCD (bijective).
    const int pb = blockIdx.x;
    const int wg = (pb & 7) * 192 + (pb >> 3);
    const int m0 = (wg & 63) * 128;
    const int n0 = (wg >> 6) * 128;           // n = mat*1024 + h*64 + dk
    const int mat = n0 >> 10;
    const int tid  = threadIdx.x;
    const int wave = tid >> 6, lane = tid & 63;
    const int quad = lane >> 4, l16 = lane & 15;
    const int wm   = wave >> 1, wn = wave & 1;

    const int r8 = lane >> 3, g8 = lane & 7;
    const int gs = (g8 ^ r8) * 8;             // pre-swizzled source col (u16)
    const int ax = (l16 & 7) << 4;            // read-side byte XOR

    f32x4 acc[4][4];
    #pragma unroll
    for (int i = 0; i < 4; i++)
        #pragma unroll
        for (int j = 0; j < 4; j++) acc[i][j] = f32x4{0.f, 0.f, 0.f, 0.f};

    auto STAGE = [&](u16* Ad, u16* Bd, int kb) {
        const int kbase = kb * 64;
        #pragma unroll
        for (int it = 0; it < 4; it++) {
            const int row = it * 32 + wave * 8 + r8;
            const int ldo = (it * 4 + wave) * 512 + lane * 8;   // u16 units
            gld_lds16(xb + (size_t)(m0 + row) * DM_ + kbase + gs, Ad + ldo);
            gld_lds16(Wt + (size_t)(n0 + row) * DM_ + kbase + gs, Bd + ldo);
        }
    };

    STAGE(&As0[0][0], &Bs0[0][0], 0);
    __syncthreads();                         // drains prologue vmcnt

    #define PLOOP(SW)                                                        \
        for (int kb = 0; kb < 16; kb += 2) {                                 \
            STAGE(&As1[0][0], &Bs1[0][0], kb + 1);                           \
            pcompute<SW>((const char*)As0, (const char*)Bs0,                 \
                         wm, wn, quad, l16, ax, acc);                        \
            __syncthreads();                                                 \
            if (kb + 2 < 16) STAGE(&As0[0][0], &Bs0[0][0], kb + 2);          \
            pcompute<SW>((const char*)As1, (const char*)Bs1,                 \
                         wm, wn, quad, l16, ax, acc);                        \
            __syncthreads();                                                 \
        }
    if (mat != 2) { PLOOP(1) } else { PLOOP(0) }
    #undef PLOOP

    const int h_base = (n0 & 1023) >> 6;
    if (mat != 2) {
        // SWAPPED: acc[i][j] row' = n_loc = wn*64 + j*16 + quad*4 + r,
        //          col' = m_loc = wm*64 + i*16 + l16.  r walks dk.
        u16* Cm = (mat == 0) ? Qc : Kc;
        const float sc = (mat == 0) ? 0.18033688f : 1.0f;  // Q: dk^-.5*log2e
        #pragma unroll
        for (int i = 0; i < 4; i++) {
            const int m  = m0 + wm * 64 + i * 16 + l16;
            const int bb = m >> 11, t = m & (T_ - 1);
            u16* rowp = Cm + ((size_t)(bb * H_ + h_base + wn) * T_ + t) * D_;
            #pragma unroll
            for (int j = 0; j < 4; j++) {
                const int dk0 = j * 16 + quad * 4;
                u32x2 d { pk2(acc[i][j][0] * sc, acc[i][j][1] * sc),
                          pk2(acc[i][j][2] * sc, acc[i][j][3] * sc) };
                *(u32x2*)(rowp + dk0) = d;
            }
        }
    } else {
        // NORMAL: acc[i][j] row = m_loc = wm*64 + i*16 + quad*4 + r,
        //         col = n_loc = wn*64 + j*16 + l16.  r walks t.
        #pragma unroll
        for (int i = 0; i < 4; i++) {
            const int m  = m0 + wm * 64 + i * 16 + quad * 4;   // r = 0 base
            const int bb = m >> 11, t = m & (T_ - 1);
            #pragma unroll
            for (int j = 0; j < 4; j++) {
                const int dk = j * 16 + l16;
                u32x2 d { pk2(acc[i][j][0], acc[i][j][1]),
                          pk2(acc[i][j][2], acc[i][j][3]) };
                *(u32x2*)(Vtc + ((size_t)(bb * H_ + h_base + wn) * D_ + dk) * T_ + t) = d;
            }
        }
    }
}

// ---------------------------------------------------------------------------
// Flash attention, swapped-operand (S^T = K.Q^T via 32x32x16 MFMA).
// 2048 blocks x 128 thr (2 waves x 32 q-rows = 64-row q-tile), big-qt first
// (LPT balance), XCD-swizzled so each XCD keeps 8 (b,h) K/V sets in L2.
// ---------------------------------------------------------------------------
__global__ __launch_bounds__(128, 3) void attn_kernel(
    const u16* __restrict__ Qc, const u16* __restrict__ Kc,
    const u16* __restrict__ Vtc, float* __restrict__ out)
{
    __shared__ __attribute__((aligned(16))) u16 Ks[64][64];   // swizzled [s][k]
    __shared__ __attribute__((aligned(16))) u16 Vs[64][64];   // swizzled [dv][s]

    const int pb = blockIdx.x;
    const int lb = (pb & 7) * 256 + (pb >> 3);   // XCD swizzle (2048%8==0)
    const int qt = 31 - (lb & 31);               // big q-tiles scheduled first
    const int h  = (lb >> 5) & 15, b = lb >> 9;

    const int tid = threadIdx.x, w = tid >> 6, lane = tid & 63;
    const int l31 = lane & 31, hi = lane >> 5;
    const int r8 = lane >> 3, g8 = lane & 7;
    const int gs = (g8 ^ r8) * 8;             // pre-swizzled source col (u16)
    const int ax = (l31 & 7) << 4;            // read-side byte XOR

    const u16* Qbh = Qc + (size_t)(b * H_ + h) * T_ * D_;
    const u16* Kbh = Kc + (size_t)(b * H_ + h) * T_ * D_;
    const u16* Vbh = Vtc + (size_t)(b * H_ + h) * D_ * T_;
    u16* Ksp = &Ks[0][0];
    u16* Vsp = &Vs[0][0];
    const char* Ksb = (const char*)Ksp;
    const char* Vsb = (const char*)Vsp;

    const int q0 = qt * 64;
    const int qrow = q0 + w * 32 + l31;
    const int qloc = w * 32 + l31;            // q within the 64-row tile

    // Q B-frags (col=lane&31=q, k = hi*8+e per 16-chunk), scaled at proj.
    u16x8 qf[4];
    #pragma unroll
    for (int ks = 0; ks < 4; ks++)
        qf[ks] = *(const u16x8*)(Qbh + (size_t)qrow * D_ + ks * 16 + hi * 8);

    f32x16 ot0, ot1;                          // O^T accum: dv-tiles 0..31/32..63
    #pragma unroll
    for (int r = 0; r < 16; r++) { ot0[r] = 0.f; ot1[r] = 0.f; }
    float mi = -1e30f, li = 0.f;

    const int nst = qt + 1;
    for (int st = 0; st < nst; st++) {
        const int sbase = st * 64;
        __syncthreads();
        #pragma unroll
        for (int i = 0; i < 4; i++) {
            const int seg = i * 2 + w;        // 8 segs of 8 rows each
            const int row = seg * 8 + r8;
            const int ldo = seg * 512 + lane * 8;               // u16 units
            gld_lds16(Kbh + (size_t)(sbase + row) * D_ + gs, Ksp + ldo);
            gld_lds16(Vbh + (size_t)row * T_ + sbase + gs,  Vsp + ldo);
        }
        __syncthreads();

        // S^T = K . Q^T   (two 32-s tiles, log2 domain)
        f32x16 st0, st1;
        #pragma unroll
        for (int r = 0; r < 16; r++) { st0[r] = 0.f; st1[r] = 0.f; }
        #pragma unroll
        for (int ks = 0; ks < 4; ks++) {
            const int co = (ks * 16 + hi * 8) * 2;              // byte col
            u16x8 k0 = *(const u16x8*)(Ksb + ((l31 * 128 + co) ^ ax));
            u16x8 k1 = *(const u16x8*)(Ksb + (((32 + l31) * 128 + co) ^ ax));
            st0 = mfma32(k0, qf[ks], st0);
            st1 = mfma32(k1, qf[ks], st1);
        }

        // causal mask — diagonal tile only (sbase == q0 there).
        // S^T: row s_local = (r&3)+8*(r>>2)+4*hi (+32 for st1), col q = qloc.
        if (st == nst - 1) {
            #pragma unroll
            for (int r = 0; r < 16; r++) {
                const int sl = (r & 3) + 8 * (r >> 2) + 4 * hi;
                if (sl > qloc)      st0[r] = -1e30f;
                if (sl + 32 > qloc) st1[r] = -1e30f;
            }
        }

        // online softmax: in-lane over 32 + one hi-swap
        float mx = -1e30f;
        #pragma unroll
        for (int r = 0; r < 16; r++) mx = fmaxf(mx, fmaxf(st0[r], st1[r]));
        mx = fmaxf(mx, __shfl_xor(mx, 32));
        if (!__all(mx - mi <= 8.f)) {         // defer-max (T13, THR=8)
            const float mn = fmaxf(mi, mx);
            const float al = EXP2(mi - mn);
            li *= al;
            #pragma unroll
            for (int r = 0; r < 16; r++) { ot0[r] *= al; ot1[r] *= al; }
            mi = mn;
        }
        float sum = 0.f;
        #pragma unroll
        for (int r = 0; r < 16; r++) {
            const float p0 = EXP2(st0[r] - mi);
            const float p1 = EXP2(st1[r] - mi);
            st0[r] = p0; st1[r] = p1;
            sum += p0 + p1;
        }
        sum += __shfl_xor(sum, 32);
        li += sum;

        // P^T -> PV B-frags: lane (q,hi) holds s {4hi+0..3, 8+4hi+0..3} per
        // 16-chunk; needs {8hi..8hi+7}.  pk2 pairs + swap d-words across hi.
        u16x8 pb4[4];
        #define PACK(SRC, C, OUT) {                                           \
            u32 d0 = pk2(SRC[8*(C)+0], SRC[8*(C)+1]);                         \
            u32 d1 = pk2(SRC[8*(C)+2], SRC[8*(C)+3]);                         \
            u32 d2 = pk2(SRC[8*(C)+4], SRC[8*(C)+5]);                         \
            u32 d3 = pk2(SRC[8*(C)+6], SRC[8*(C)+7]);                         \
            u32 e0 = __shfl_xor(hi ? d0 : d2, 32);                            \
            u32 e1 = __shfl_xor(hi ? d1 : d3, 32);                            \
            u32x4 wds{ hi ? e0 : d0, hi ? e1 : d1,                            \
                       hi ? d2 : e0, hi ? d3 : e1 };                          \
            OUT = __builtin_bit_cast(u16x8, wds); }
        PACK(st0, 0, pb4[0]); PACK(st0, 1, pb4[1]);
        PACK(st1, 0, pb4[2]); PACK(st1, 1, pb4[3]);
        #undef PACK

        // O^T += V^T . P^T  (A rows = dv, k = s)
        #pragma unroll
        for (int kc = 0; kc < 4; kc++) {
            const int co = (kc * 16 + hi * 8) * 2;
            u16x8 v0 = *(const u16x8*)(Vsb + ((l31 * 128 + co) ^ ax));
            u16x8 v1 = *(const u16x8*)(Vsb + (((32 + l31) * 128 + co) ^ ax));
            ot0 = mfma32(v0, pb4[kc], ot0);
            ot1 = mfma32(v1, pb4[kc], ot1);
        }
    }

    // output: O^T reg r -> dv = td*32 + 16c + 8hf + 4hi + j, q = qrow
    const float inv = 1.0f / li;
    float* orow = out + (size_t)(b * T_ + qrow) * DMO + h * D_;
    #pragma unroll
    for (int c = 0; c < 2; c++)
        #pragma unroll
        for (int hf = 0; hf < 2; hf++) {
            f32x4 v0, v1;
            #pragma unroll
            for (int j = 0; j < 4; j++) {
                v0[j] = ot0[c * 8 + hf * 4 + j] * inv;
                v1[j] = ot1[c * 8 + hf * 4 + j] * inv;
            }
            *(f32x4*)(orow + c * 16 + hf * 8 + hi * 4)      = v0;
            *(f32x4*)(orow + 32 + c * 16 + hf * 8 + hi * 4) = v1;
        }
}

// ---------------------------------------------------------------------------
extern "C" void kernel_launch(void* const* d_in, const int* in_sizes, int n_in,
                              void* d_out, int out_size, void* d_ws, size_t ws_size,
                              hipStream_t stream) {
    int xi = 0, wi[3] = {1, 2, 3};
    {
        int k = 0, found = 0;
        for (int i = 0; i < n_in && i < 8; i++) {
            if (in_sizes[i] == B_ * T_ * DM_) { xi = i; found = 1; }
            else if (in_sizes[i] == H_ * DM_ * D_ && k < 3) wi[k++] = i;
        }
        if (!found || k != 3) { xi = 0; wi[0] = 1; wi[1] = 2; wi[2] = 3; }
    }
    const float* x  = (const float*)d_in[xi];
    const float* Wq = (const float*)d_in[wi[0]];
    const float* Wk = (const float*)d_in[wi[1]];
    const float* Wv = (const float*)d_in[wi[2]];
    float* out = (float*)d_out;

    // bf16 staging scratch lives in d_out (dead before attn writes it):
    //   xb = 8.4M u16 (16.8 MB), Wt = 3.1M u16 (6.3 MB) -> 23.1 of 33.5 MB.
    u16* xb = (u16*)d_out;
    u16* Wt = xb + (size_t)B_ * T_ * DM_;
    // ws: Q + K + Vt bf16 = 50.3 MB (R8-verified to fit).
    const size_t per = (size_t)B_ * H_ * T_ * D_;
    u16* Qc  = (u16*)d_ws;
    u16* Kc  = Qc + per;
    u16* Vtc = Kc + per;

    cvt_x<<<1024, 256, 0, stream>>>(x, xb);
    cvt_w<<<dim3(16, 16, 3), 256, 0, stream>>>(Wq, Wk, Wv, Wt);
    proj_kernel<<<1536, 256, 0, stream>>>(xb, Wt, Qc, Kc, Vtc);
    attn_kernel<<<2048, 128, 0, stream>>>(Qc, Kc, Vtc, out);
}

// Round 4
// 240.234 us; speedup vs baseline: 1.2457x; 1.0464x over previous
//
#include <hip/hip_runtime.h>

// MHA forward.  B=4 T=2048 DM=1024 H=16 DK=DV=64.  f32 in / f32 out.
// R14: attn occupancy/latency rework.
//   (1) paired q-tiles {pr, 31-pr} per block -> exactly 33 s-tiles/block
//       (perfect balance, no LPT tail).  1024 blocks x 128 thr, XCD-swizzled
//       (8 bh K/V sets per XCD = 4 MB = L2-resident).
//   (2) double-buffered K/V (Ks[2]/Vs[2], 32 KB): STAGE(t+1) issued before
//       compute(t), single __syncthreads per s-tile -> staging L2 latency
//       hides under MFMA+softmax (same T3 minimum-2-phase as proj R13).
//       Flat 33-iter pipeline across the phase switch (B re-stages tile 0).
//   (3) s_setprio(1) around QK/PV MFMA clusters (T5; 2 waves/SIMD now
//       co-resident at different phases).
//   (4) cvt_x+cvt_w merged into cvt_all (one fewer launch).
//   proj (R13 dbuf + packed epilogue) unchanged.

#define B_  4
#define T_  2048
#define DM_ 1024
#define H_  16
#define D_  64
#define DMO 1024   // out row stride = H_*D_

typedef unsigned short u16;
typedef unsigned int   u32;
typedef u16   u16x8  __attribute__((ext_vector_type(8)));
typedef short s16x8  __attribute__((ext_vector_type(8)));
typedef float f32x4  __attribute__((ext_vector_type(4)));
typedef float f32x16 __attribute__((ext_vector_type(16)));
typedef u32   u32x2  __attribute__((ext_vector_type(2)));
typedef u32   u32x4  __attribute__((ext_vector_type(4)));

#if __has_builtin(__builtin_amdgcn_exp2f)
#define EXP2(x) __builtin_amdgcn_exp2f(x)
#else
#define EXP2(x) __expf((x) * 0.69314718f)
#endif

__device__ __forceinline__ u16 f2bf_hu(float f) {   // round-half-up (ties rare)
    u32 u = __builtin_bit_cast(u32, f) + 0x8000u;
    return (u16)(u >> 16);
}
// pack two f32 -> dword of two bf16 (lo,hi), 3 VALU ops
__device__ __forceinline__ u32 pk2(float lo, float hi) {
    u32 ul = __builtin_bit_cast(u32, lo) + 0x8000u;
    u32 uh = __builtin_bit_cast(u32, hi) + 0x8000u;
    return __builtin_amdgcn_perm(uh, ul, 0x07060302);  // [uh.hi16 : ul.hi16]
}
__device__ __forceinline__ u16x8 cvt8(const float* s) {
    f32x4 a = *(const f32x4*)s;
    f32x4 b = *(const f32x4*)(s + 4);
    u32x4 r { pk2(a[0], a[1]), pk2(a[2], a[3]), pk2(b[0], b[1]), pk2(b[2], b[3]) };
    return __builtin_bit_cast(u16x8, r);
}
__device__ __forceinline__ f32x4 mfma16(u16x8 a, u16x8 b, f32x4 c) {
    return __builtin_amdgcn_mfma_f32_16x16x32_bf16(
        __builtin_bit_cast(s16x8, a), __builtin_bit_cast(s16x8, b), c, 0, 0, 0);
}
__device__ __forceinline__ f32x16 mfma32(u16x8 a, u16x8 b, f32x16 c) {
    return __builtin_amdgcn_mfma_f32_32x32x16_bf16(
        __builtin_bit_cast(s16x8, a), __builtin_bit_cast(s16x8, b), c, 0, 0, 0);
}
// async global->LDS, 16B per lane.  LDS dest must be wave-uniform base + lane*16.
__device__ __forceinline__ void gld_lds16(const u16* g, u16* l) {
    __builtin_amdgcn_global_load_lds(
        (const __attribute__((address_space(1))) u32*)g,
        (__attribute__((address_space(3))) u32*)l, 16, 0, 0);
}

// ---------------------------------------------------------------------------
// cvt_all: blocks [0,1024): x f32 [8192][1024] -> xb bf16 (same layout).
//          blocks [1024,1792): W[mat][h][1024][64] f32 -> Wt bf16 transposed.
// ---------------------------------------------------------------------------
__global__ __launch_bounds__(256) void cvt_all(
    const float* __restrict__ x,  const float* __restrict__ Wq,
    const float* __restrict__ Wk, const float* __restrict__ Wv,
    u16* __restrict__ xb, u16* __restrict__ Wt)
{
    __shared__ u16 L[64][74];
    const int bx = blockIdx.x;
    if (bx < 1024) {
        size_t i0 = ((size_t)bx * 256 + threadIdx.x) * 32;
        #pragma unroll
        for (int c = 0; c < 4; c++)
            *(u16x8*)(xb + i0 + c * 8) = cvt8(x + i0 + c * 8);
        return;
    }
    const int wb = bx - 1024;
    const int dblk = wb & 15, h = (wb >> 4) & 15, mat = wb >> 8;
    const float* W = (mat == 0) ? Wq : (mat == 1) ? Wk : Wv;
    const int tid = threadIdx.x;
    {   // load 64(d) x 64(dk), coalesced, convert
        const int dl = tid >> 2, c = (tid & 3) * 16;
        const float* src = W + ((size_t)h * DM_ + dblk * 64 + dl) * D_ + c;
        #pragma unroll
        for (int g = 0; g < 2; g++)
            *(u16x8*)&L[dl][c + g * 8] = cvt8(src + g * 8);
    }
    __syncthreads();
    {   // write rows of Wt: row = dk, 16 d's per thread
        const int dkr = tid >> 2, g = tid & 3;
        u16 tmp[16];
        #pragma unroll
        for (int j = 0; j < 16; j++) tmp[j] = L[g * 16 + j][dkr];
        u16* dst = Wt + ((size_t)(mat * 16 + h) * 64 + dkr) * DM_ + dblk * 64 + g * 16;
        *(u16x8*)dst = *(u16x8*)tmp;
        *(u16x8*)(dst + 8) = *(u16x8*)(tmp + 8);
    }
}

// ---------------------------------------------------------------------------
// Projection GEMM: C[8192][3072] = xb @ Wt^T (Wt rows are C-columns).
// 1536 blocks (XCD-swizzled), 256 thr = 4 waves 2x2, 128x128 tile, BK=64.
// ---------------------------------------------------------------------------
template<int SWAP>
__device__ __forceinline__ void pcompute(const char* Asb, const char* Bsb,
                                         int wm, int wn, int quad, int l16,
                                         int ax, f32x4 (&acc)[4][4]) {
    #pragma unroll
    for (int ks = 0; ks < 2; ks++) {
        u16x8 af[4], bf[4];
        #pragma unroll
        for (int i = 0; i < 4; i++)
            af[i] = *(const u16x8*)(Asb +
                ((((wm * 64 + i * 16 + l16) * 64 + ks * 32 + quad * 8) * 2) ^ ax));
        #pragma unroll
        for (int j = 0; j < 4; j++)
            bf[j] = *(const u16x8*)(Bsb +
                ((((wn * 64 + j * 16 + l16) * 64 + ks * 32 + quad * 8) * 2) ^ ax));
        #pragma unroll
        for (int i = 0; i < 4; i++)
            #pragma unroll
            for (int j = 0; j < 4; j++)
                acc[i][j] = SWAP ? mfma16(bf[j], af[i], acc[i][j])
                                 : mfma16(af[i], bf[j], acc[i][j]);
    }
}

__global__ __launch_bounds__(256) void proj_kernel(
    const u16* __restrict__ xb, const u16* __restrict__ Wt,
    u16* __restrict__ Qc, u16* __restrict__ Kc, u16* __restrict__ Vtc)
{
    __shared__ __attribute__((aligned(16))) u16 As0[128][64];
    __shared__ __attribute__((aligned(16))) u16 Bs0[128][64];
    __shared__ __attribute__((aligned(16))) u16 As1[128][64];
    __shared__ __attribute__((aligned(16))) u16 Bs1[128][64];

    const int pb = blockIdx.x;
    const int wg = (pb & 7) * 192 + (pb >> 3);
    const int m0 = (wg & 63) * 128;
    const int n0 = (wg >> 6) * 128;           // n = mat*1024 + h*64 + dk
    const int mat = n0 >> 10;
    const int tid  = threadIdx.x;
    const int wave = tid >> 6, lane = tid & 63;
    const int quad = lane >> 4, l16 = lane & 15;
    const int wm   = wave >> 1, wn = wave & 1;

    const int r8 = lane >> 3, g8 = lane & 7;
    const int gs = (g8 ^ r8) * 8;             // pre-swizzled source col (u16)
    const int ax = (l16 & 7) << 4;            // read-side byte XOR

    f32x4 acc[4][4];
    #pragma unroll
    for (int i = 0; i < 4; i++)
        #pragma unroll
        for (int j = 0; j < 4; j++) acc[i][j] = f32x4{0.f, 0.f, 0.f, 0.f};

    auto STAGE = [&](u16* Ad, u16* Bd, int kb) {
        const int kbase = kb * 64;
        #pragma unroll
        for (int it = 0; it < 4; it++) {
            const int row = it * 32 + wave * 8 + r8;
            const int ldo = (it * 4 + wave) * 512 + lane * 8;   // u16 units
            gld_lds16(xb + (size_t)(m0 + row) * DM_ + kbase + gs, Ad + ldo);
            gld_lds16(Wt + (size_t)(n0 + row) * DM_ + kbase + gs, Bd + ldo);
        }
    };

    STAGE(&As0[0][0], &Bs0[0][0], 0);
    __syncthreads();                         // drains prologue vmcnt

    #define PLOOP(SW)                                                        \
        for (int kb = 0; kb < 16; kb += 2) {                                 \
            STAGE(&As1[0][0], &Bs1[0][0], kb + 1);                           \
            pcompute<SW>((const char*)As0, (const char*)Bs0,                 \
                         wm, wn, quad, l16, ax, acc);                        \
            __syncthreads();                                                 \
            if (kb + 2 < 16) STAGE(&As0[0][0], &Bs0[0][0], kb + 2);          \
            pcompute<SW>((const char*)As1, (const char*)Bs1,                 \
                         wm, wn, quad, l16, ax, acc);                        \
            __syncthreads();                                                 \
        }
    if (mat != 2) { PLOOP(1) } else { PLOOP(0) }
    #undef PLOOP

    const int h_base = (n0 & 1023) >> 6;
    if (mat != 2) {
        // SWAPPED: r walks dk.
        u16* Cm = (mat == 0) ? Qc : Kc;
        const float sc = (mat == 0) ? 0.18033688f : 1.0f;  // Q: dk^-.5*log2e
        #pragma unroll
        for (int i = 0; i < 4; i++) {
            const int m  = m0 + wm * 64 + i * 16 + l16;
            const int bb = m >> 11, t = m & (T_ - 1);
            u16* rowp = Cm + ((size_t)(bb * H_ + h_base + wn) * T_ + t) * D_;
            #pragma unroll
            for (int j = 0; j < 4; j++) {
                const int dk0 = j * 16 + quad * 4;
                u32x2 d { pk2(acc[i][j][0] * sc, acc[i][j][1] * sc),
                          pk2(acc[i][j][2] * sc, acc[i][j][3] * sc) };
                *(u32x2*)(rowp + dk0) = d;
            }
        }
    } else {
        // NORMAL: r walks t.
        #pragma unroll
        for (int i = 0; i < 4; i++) {
            const int m  = m0 + wm * 64 + i * 16 + quad * 4;   // r = 0 base
            const int bb = m >> 11, t = m & (T_ - 1);
            #pragma unroll
            for (int j = 0; j < 4; j++) {
                const int dk = j * 16 + l16;
                u32x2 d { pk2(acc[i][j][0], acc[i][j][1]),
                          pk2(acc[i][j][2], acc[i][j][3]) };
                *(u32x2*)(Vtc + ((size_t)(bb * H_ + h_base + wn) * D_ + dk) * T_ + t) = d;
            }
        }
    }
}

// ---------------------------------------------------------------------------
// Flash attention, swapped-operand (S^T = K.Q^T via 32x32x16 MFMA).
// Paired q-tiles {qa=pr, qb=31-pr}: 1024 blocks x 128 thr, 33 s-tiles each
// (perfect balance).  Double-buffered K/V staging, prefetch-before-compute,
// one barrier per s-tile.  XCD-swizzled grid (8 bh-sets/XCD in L2).
// ---------------------------------------------------------------------------
__global__ __launch_bounds__(128, 2) void attn_kernel(
    const u16* __restrict__ Qc, const u16* __restrict__ Kc,
    const u16* __restrict__ Vtc, float* __restrict__ out)
{
    __shared__ __attribute__((aligned(16))) u16 Ks[2][64][64];  // swz [s][k]
    __shared__ __attribute__((aligned(16))) u16 Vs[2][64][64];  // swz [dv][s]

    const int pb = blockIdx.x;
    const int lb = (pb & 7) * 128 + (pb >> 3);   // XCD swizzle (1024%8==0)
    const int pr = lb & 15;                       // pair id
    const int bh = lb >> 4;
    const int h  = bh & 15, b = bh >> 4;
    const int qa = pr, qb = 31 - pr;              // 33 s-tiles total

    const int tid = threadIdx.x, w = tid >> 6, lane = tid & 63;
    const int l31 = lane & 31, hi = lane >> 5;
    const int r8 = lane >> 3, g8 = lane & 7;
    const int gs = (g8 ^ r8) * 8;             // pre-swizzled source col (u16)
    const int ax = (l31 & 7) << 4;            // read-side byte XOR
    const int qloc = w * 32 + l31;            // q within the 64-row tile

    const u16* Qbh = Qc + (size_t)(b * H_ + h) * T_ * D_;
    const u16* Kbh = Kc + (size_t)(b * H_ + h) * T_ * D_;
    const u16* Vbh = Vtc + (size_t)(b * H_ + h) * D_ * T_;

    auto STAGE = [&](int buf, int t) {
        const int sbase = t * 64;
        u16* Kd = &Ks[buf][0][0];
        u16* Vd = &Vs[buf][0][0];
        #pragma unroll
        for (int i2 = 0; i2 < 4; i2++) {
            const int seg = i2 * 2 + w;       // 8 segs of 8 rows each
            const int row = seg * 8 + r8;
            const int ldo = seg * 512 + lane * 8;               // u16 units
            gld_lds16(Kbh + (size_t)(sbase + row) * D_ + gs, Kd + ldo);
            gld_lds16(Vbh + (size_t)row * T_ + sbase + gs,  Vd + ldo);
        }
    };

    // phase state (A first: q-tile qa)
    int qrow = qa * 64 + qloc;
    u16x8 qf[4];
    #pragma unroll
    for (int ks = 0; ks < 4; ks++)
        qf[ks] = *(const u16x8*)(Qbh + (size_t)qrow * D_ + ks * 16 + hi * 8);

    f32x16 ot0, ot1;
    #pragma unroll
    for (int r = 0; r < 16; r++) { ot0[r] = 0.f; ot1[r] = 0.f; }
    float mi = -1e30f, li = 0.f;

    auto EPI = [&]() {
        const float inv = 1.0f / li;
        float* orow = out + (size_t)(b * T_ + qrow) * DMO + h * D_;
        #pragma unroll
        for (int c = 0; c < 2; c++)
            #pragma unroll
            for (int hf = 0; hf < 2; hf++) {
                f32x4 v0, v1;
                #pragma unroll
                for (int j = 0; j < 4; j++) {
                    v0[j] = ot0[c * 8 + hf * 4 + j] * inv;
                    v1[j] = ot1[c * 8 + hf * 4 + j] * inv;
                }
                *(f32x4*)(orow + c * 16 + hf * 8 + hi * 4)      = v0;
                *(f32x4*)(orow + 32 + c * 16 + hf * 8 + hi * 4) = v1;
            }
    };

    STAGE(0, 0);
    __syncthreads();
    int cur = 0;

    for (int i = 0; i <= 32; i++) {
        if (i < 32) {                          // prefetch next s-tile
            const int nx = i + 1;
            const int tn = (nx <= qa) ? nx : nx - qa - 1;
            STAGE(cur ^ 1, tn);
        }
        const char* Ksb = (const char*)&Ks[cur][0][0];
        const char* Vsb = (const char*)&Vs[cur][0][0];

        // S^T = K . Q^T   (two 32-s tiles, log2 domain)
        f32x16 st0, st1;
        #pragma unroll
        for (int r = 0; r < 16; r++) { st0[r] = 0.f; st1[r] = 0.f; }
        __builtin_amdgcn_s_setprio(1);
        #pragma unroll
        for (int ks = 0; ks < 4; ks++) {
            const int co = (ks * 16 + hi * 8) * 2;              // byte col
            u16x8 k0 = *(const u16x8*)(Ksb + ((l31 * 128 + co) ^ ax));
            u16x8 k1 = *(const u16x8*)(Ksb + (((32 + l31) * 128 + co) ^ ax));
            st0 = mfma32(k0, qf[ks], st0);
            st1 = mfma32(k1, qf[ks], st1);
        }
        __builtin_amdgcn_s_setprio(0);

        // causal mask — last tile of each phase is its diagonal (s0 == q0)
        if (i == qa || i == 32) {
            #pragma unroll
            for (int r = 0; r < 16; r++) {
                const int sl = (r & 3) + 8 * (r >> 2) + 4 * hi;
                if (sl > qloc)      st0[r] = -1e30f;
                if (sl + 32 > qloc) st1[r] = -1e30f;
            }
        }

        // online softmax: in-lane over 32 + one hi-swap
        float mx = -1e30f;
        #pragma unroll
        for (int r = 0; r < 16; r++) mx = fmaxf(mx, fmaxf(st0[r], st1[r]));
        mx = fmaxf(mx, __shfl_xor(mx, 32));
        if (!__all(mx - mi <= 8.f)) {         // defer-max (T13, THR=8)
            const float mn = fmaxf(mi, mx);
            const float al = EXP2(mi - mn);
            li *= al;
            #pragma unroll
            for (int r = 0; r < 16; r++) { ot0[r] *= al; ot1[r] *= al; }
            mi = mn;
        }
        float sum = 0.f;
        #pragma unroll
        for (int r = 0; r < 16; r++) {
            const float p0 = EXP2(st0[r] - mi);
            const float p1 = EXP2(st1[r] - mi);
            st0[r] = p0; st1[r] = p1;
            sum += p0 + p1;
        }
        sum += __shfl_xor(sum, 32);
        li += sum;

        // P^T -> PV B-frags: pk2 pairs + swap dwords across hi halves
        u16x8 pb4[4];
        #define PACK(SRC, C, OUT) {                                           \
            u32 d0 = pk2(SRC[8*(C)+0], SRC[8*(C)+1]);                         \
            u32 d1 = pk2(SRC[8*(C)+2], SRC[8*(C)+3]);                         \
            u32 d2 = pk2(SRC[8*(C)+4], SRC[8*(C)+5]);                         \
            u32 d3 = pk2(SRC[8*(C)+6], SRC[8*(C)+7]);                         \
            u32 e0 = __shfl_xor(hi ? d0 : d2, 32);                            \
            u32 e1 = __shfl_xor(hi ? d1 : d3, 32);                            \
            u32x4 wds{ hi ? e0 : d0, hi ? e1 : d1,                            \
                       hi ? d2 : e0, hi ? d3 : e1 };                          \
            OUT = __builtin_bit_cast(u16x8, wds); }
        PACK(st0, 0, pb4[0]); PACK(st0, 1, pb4[1]);
        PACK(st1, 0, pb4[2]); PACK(st1, 1, pb4[3]);
        #undef PACK

        // O^T += V^T . P^T  (A rows = dv, k = s)
        __builtin_amdgcn_s_setprio(1);
        #pragma unroll
        for (int kc = 0; kc < 4; kc++) {
            const int co = (kc * 16 + hi * 8) * 2;
            u16x8 v0 = *(const u16x8*)(Vsb + ((l31 * 128 + co) ^ ax));
            u16x8 v1 = *(const u16x8*)(Vsb + (((32 + l31) * 128 + co) ^ ax));
            ot0 = mfma32(v0, pb4[kc], ot0);
            ot1 = mfma32(v1, pb4[kc], ot1);
        }
        __builtin_amdgcn_s_setprio(0);

        if (i == qa) {                         // phase switch A -> B
            EPI();
            qrow = qb * 64 + qloc;
            #pragma unroll
            for (int ks = 0; ks < 4; ks++)
                qf[ks] = *(const u16x8*)(Qbh + (size_t)qrow * D_ + ks * 16 + hi * 8);
            #pragma unroll
            for (int r = 0; r < 16; r++) { ot0[r] = 0.f; ot1[r] = 0.f; }
            mi = -1e30f; li = 0.f;
        }
        __syncthreads();
        cur ^= 1;
    }
    EPI();                                     // phase B output
}

// ---------------------------------------------------------------------------
extern "C" void kernel_launch(void* const* d_in, const int* in_sizes, int n_in,
                              void* d_out, int out_size, void* d_ws, size_t ws_size,
                              hipStream_t stream) {
    int xi = 0, wi[3] = {1, 2, 3};
    {
        int k = 0, found = 0;
        for (int i = 0; i < n_in && i < 8; i++) {
            if (in_sizes[i] == B_ * T_ * DM_) { xi = i; found = 1; }
            else if (in_sizes[i] == H_ * DM_ * D_ && k < 3) wi[k++] = i;
        }
        if (!found || k != 3) { xi = 0; wi[0] = 1; wi[1] = 2; wi[2] = 3; }
    }
    const float* x  = (const float*)d_in[xi];
    const float* Wq = (const float*)d_in[wi[0]];
    const float* Wk = (const float*)d_in[wi[1]];
    const float* Wv = (const float*)d_in[wi[2]];
    float* out = (float*)d_out;

    // bf16 staging scratch lives in d_out (dead before attn writes it):
    //   xb = 8.4M u16 (16.8 MB), Wt = 3.1M u16 (6.3 MB) -> 23.1 of 33.5 MB.
    u16* xb = (u16*)d_out;
    u16* Wt = xb + (size_t)B_ * T_ * DM_;
    // ws: Q + K + Vt bf16 = 50.3 MB (R8-verified to fit).
    const size_t per = (size_t)B_ * H_ * T_ * D_;
    u16* Qc  = (u16*)d_ws;
    u16* Kc  = Qc + per;
    u16* Vtc = Kc + per;

    cvt_all<<<1792, 256, 0, stream>>>(x, Wq, Wk, Wv, xb, Wt);
    proj_kernel<<<1536, 256, 0, stream>>>(xb, Wt, Qc, Kc, Vtc);
    attn_kernel<<<1024, 128, 0, stream>>>(Qc, Kc, Vtc, out);
}

// Round 5
// 233.009 us; speedup vs baseline: 1.2843x; 1.0310x over previous
//
#include <hip/hip_runtime.h>

// MHA forward.  B=4 T=2048 DM=1024 H=16 DK=DV=64.  f32 in / f32 out.
// R15: counted-vmcnt pipelines (T4) in BOTH hot kernels.
//   attn: R14's runtime-indexed Ks[2] defeated the prefetch — compiler
//   couldn't prove gld_lds(next) !alias ds_read(cur) and drained vmcnt(0)
//   every tile (the R13 proj lesson, unlearned).  Now: statically distinct
//   Ks0/Vs0/Ks1/Vs1 + raw s_barrier + s_waitcnt vmcnt(8) (8 loads/STAGE
//   stay in flight across barriers; drain 0 only at tail).  Same schedule
//   in proj (replaces __syncthreads' implicit vmcnt(0) drain each half-
//   iter — m218: counted vs drain0 = +38-73%).
//   Schedule per tile: vmcnt(8); s_barrier; compute(bufX); s_barrier;
//   STAGE(bufX, t+2).  Each wave waits own vmcnt then barriers.

#define B_  4
#define T_  2048
#define DM_ 1024
#define H_  16
#define D_  64
#define DMO 1024   // out row stride = H_*D_

typedef unsigned short u16;
typedef unsigned int   u32;
typedef u16   u16x8  __attribute__((ext_vector_type(8)));
typedef short s16x8  __attribute__((ext_vector_type(8)));
typedef float f32x4  __attribute__((ext_vector_type(4)));
typedef float f32x16 __attribute__((ext_vector_type(16)));
typedef u32   u32x2  __attribute__((ext_vector_type(2)));
typedef u32   u32x4  __attribute__((ext_vector_type(4)));

#if __has_builtin(__builtin_amdgcn_exp2f)
#define EXP2(x) __builtin_amdgcn_exp2f(x)
#else
#define EXP2(x) __expf((x) * 0.69314718f)
#endif

// counted-vmcnt barrier: wait own loads down to N, then sync, then pin.
#define WAIT_BAR(N) do {                                                      \
    asm volatile("s_waitcnt vmcnt(" #N ")" ::: "memory");                     \
    __builtin_amdgcn_s_barrier();                                             \
    __builtin_amdgcn_sched_barrier(0); } while (0)
#define BAR_ONLY() do {                                                       \
    __builtin_amdgcn_s_barrier();                                             \
    __builtin_amdgcn_sched_barrier(0); } while (0)

__device__ __forceinline__ u16 f2bf_hu(float f) {   // round-half-up (ties rare)
    u32 u = __builtin_bit_cast(u32, f) + 0x8000u;
    return (u16)(u >> 16);
}
// pack two f32 -> dword of two bf16 (lo,hi), 3 VALU ops
__device__ __forceinline__ u32 pk2(float lo, float hi) {
    u32 ul = __builtin_bit_cast(u32, lo) + 0x8000u;
    u32 uh = __builtin_bit_cast(u32, hi) + 0x8000u;
    return __builtin_amdgcn_perm(uh, ul, 0x07060302);  // [uh.hi16 : ul.hi16]
}
__device__ __forceinline__ u16x8 cvt8(const float* s) {
    f32x4 a = *(const f32x4*)s;
    f32x4 b = *(const f32x4*)(s + 4);
    u32x4 r { pk2(a[0], a[1]), pk2(a[2], a[3]), pk2(b[0], b[1]), pk2(b[2], b[3]) };
    return __builtin_bit_cast(u16x8, r);
}
__device__ __forceinline__ f32x4 mfma16(u16x8 a, u16x8 b, f32x4 c) {
    return __builtin_amdgcn_mfma_f32_16x16x32_bf16(
        __builtin_bit_cast(s16x8, a), __builtin_bit_cast(s16x8, b), c, 0, 0, 0);
}
__device__ __forceinline__ f32x16 mfma32(u16x8 a, u16x8 b, f32x16 c) {
    return __builtin_amdgcn_mfma_f32_32x32x16_bf16(
        __builtin_bit_cast(s16x8, a), __builtin_bit_cast(s16x8, b), c, 0, 0, 0);
}
// async global->LDS, 16B per lane.  LDS dest must be wave-uniform base + lane*16.
__device__ __forceinline__ void gld_lds16(const u16* g, u16* l) {
    __builtin_amdgcn_global_load_lds(
        (const __attribute__((address_space(1))) u32*)g,
        (__attribute__((address_space(3))) u32*)l, 16, 0, 0);
}

// ---------------------------------------------------------------------------
// cvt_all: blocks [0,1024): x f32 [8192][1024] -> xb bf16 (same layout).
//          blocks [1024,1792): W[mat][h][1024][64] f32 -> Wt bf16 transposed.
// ---------------------------------------------------------------------------
__global__ __launch_bounds__(256) void cvt_all(
    const float* __restrict__ x,  const float* __restrict__ Wq,
    const float* __restrict__ Wk, const float* __restrict__ Wv,
    u16* __restrict__ xb, u16* __restrict__ Wt)
{
    __shared__ u16 L[64][74];
    const int bx = blockIdx.x;
    if (bx < 1024) {
        size_t i0 = ((size_t)bx * 256 + threadIdx.x) * 32;
        #pragma unroll
        for (int c = 0; c < 4; c++)
            *(u16x8*)(xb + i0 + c * 8) = cvt8(x + i0 + c * 8);
        return;
    }
    const int wb = bx - 1024;
    const int dblk = wb & 15, h = (wb >> 4) & 15, mat = wb >> 8;
    const float* W = (mat == 0) ? Wq : (mat == 1) ? Wk : Wv;
    const int tid = threadIdx.x;
    {   // load 64(d) x 64(dk), coalesced, convert
        const int dl = tid >> 2, c = (tid & 3) * 16;
        const float* src = W + ((size_t)h * DM_ + dblk * 64 + dl) * D_ + c;
        #pragma unroll
        for (int g = 0; g < 2; g++)
            *(u16x8*)&L[dl][c + g * 8] = cvt8(src + g * 8);
    }
    __syncthreads();
    {   // write rows of Wt: row = dk, 16 d's per thread
        const int dkr = tid >> 2, g = tid & 3;
        u16 tmp[16];
        #pragma unroll
        for (int j = 0; j < 16; j++) tmp[j] = L[g * 16 + j][dkr];
        u16* dst = Wt + ((size_t)(mat * 16 + h) * 64 + dkr) * DM_ + dblk * 64 + g * 16;
        *(u16x8*)dst = *(u16x8*)tmp;
        *(u16x8*)(dst + 8) = *(u16x8*)(tmp + 8);
    }
}

// ---------------------------------------------------------------------------
// Projection GEMM: C[8192][3072] = xb @ Wt^T (Wt rows are C-columns).
// 1536 blocks (XCD-swizzled), 256 thr = 4 waves 2x2, 128x128 tile, BK=64.
// Counted-vmcnt pipeline: 8 gld_lds per STAGE per wave; vmcnt(8) steady.
// ---------------------------------------------------------------------------
template<int SWAP>
__device__ __forceinline__ void pcompute(const char* Asb, const char* Bsb,
                                         int wm, int wn, int quad, int l16,
                                         int ax, f32x4 (&acc)[4][4]) {
    #pragma unroll
    for (int ks = 0; ks < 2; ks++) {
        u16x8 af[4], bf[4];
        #pragma unroll
        for (int i = 0; i < 4; i++)
            af[i] = *(const u16x8*)(Asb +
                ((((wm * 64 + i * 16 + l16) * 64 + ks * 32 + quad * 8) * 2) ^ ax));
        #pragma unroll
        for (int j = 0; j < 4; j++)
            bf[j] = *(const u16x8*)(Bsb +
                ((((wn * 64 + j * 16 + l16) * 64 + ks * 32 + quad * 8) * 2) ^ ax));
        __builtin_amdgcn_s_setprio(1);
        #pragma unroll
        for (int i = 0; i < 4; i++)
            #pragma unroll
            for (int j = 0; j < 4; j++)
                acc[i][j] = SWAP ? mfma16(bf[j], af[i], acc[i][j])
                                 : mfma16(af[i], bf[j], acc[i][j]);
        __builtin_amdgcn_s_setprio(0);
    }
}

__global__ __launch_bounds__(256) void proj_kernel(
    const u16* __restrict__ xb, const u16* __restrict__ Wt,
    u16* __restrict__ Qc, u16* __restrict__ Kc, u16* __restrict__ Vtc)
{
    __shared__ __attribute__((aligned(16))) u16 As0[128][64];
    __shared__ __attribute__((aligned(16))) u16 Bs0[128][64];
    __shared__ __attribute__((aligned(16))) u16 As1[128][64];
    __shared__ __attribute__((aligned(16))) u16 Bs1[128][64];

    const int pb = blockIdx.x;
    const int wg = (pb & 7) * 192 + (pb >> 3);
    const int m0 = (wg & 63) * 128;
    const int n0 = (wg >> 6) * 128;           // n = mat*1024 + h*64 + dk
    const int mat = n0 >> 10;
    const int tid  = threadIdx.x;
    const int wave = tid >> 6, lane = tid & 63;
    const int quad = lane >> 4, l16 = lane & 15;
    const int wm   = wave >> 1, wn = wave & 1;

    const int r8 = lane >> 3, g8 = lane & 7;
    const int gs = (g8 ^ r8) * 8;             // pre-swizzled source col (u16)
    const int ax = (l16 & 7) << 4;            // read-side byte XOR

    f32x4 acc[4][4];
    #pragma unroll
    for (int i = 0; i < 4; i++)
        #pragma unroll
        for (int j = 0; j < 4; j++) acc[i][j] = f32x4{0.f, 0.f, 0.f, 0.f};

    auto STAGE = [&](u16* Ad, u16* Bd, int kb) {
        const int kbase = kb * 64;
        #pragma unroll
        for (int it = 0; it < 4; it++) {
            const int row = it * 32 + wave * 8 + r8;
            const int ldo = (it * 4 + wave) * 512 + lane * 8;   // u16 units
            gld_lds16(xb + (size_t)(m0 + row) * DM_ + kbase + gs, Ad + ldo);
            gld_lds16(Wt + (size_t)(n0 + row) * DM_ + kbase + gs, Bd + ldo);
        }
    };

    STAGE(&As0[0][0], &Bs0[0][0], 0);
    STAGE(&As1[0][0], &Bs1[0][0], 1);        // 16 outstanding / wave

    #define PLOOP(SW)                                                        \
        for (int j = 0; j < 8; j++) {                                        \
            WAIT_BAR(8);                                                     \
            pcompute<SW>((const char*)As0, (const char*)Bs0,                 \
                         wm, wn, quad, l16, ax, acc);                        \
            BAR_ONLY();                                                      \
            if (2 * j + 2 < 16) STAGE(&As0[0][0], &Bs0[0][0], 2 * j + 2);    \
            if (j < 7) { WAIT_BAR(8); } else { WAIT_BAR(0); }                \
            pcompute<SW>((const char*)As1, (const char*)Bs1,                 \
                         wm, wn, quad, l16, ax, acc);                        \
            BAR_ONLY();                                                      \
            if (2 * j + 3 < 16) STAGE(&As1[0][0], &Bs1[0][0], 2 * j + 3);    \
        }
    if (mat != 2) { PLOOP(1) } else { PLOOP(0) }
    #undef PLOOP

    const int h_base = (n0 & 1023) >> 6;
    if (mat != 2) {
        // SWAPPED: r walks dk.
        u16* Cm = (mat == 0) ? Qc : Kc;
        const float sc = (mat == 0) ? 0.18033688f : 1.0f;  // Q: dk^-.5*log2e
        #pragma unroll
        for (int i = 0; i < 4; i++) {
            const int m  = m0 + wm * 64 + i * 16 + l16;
            const int bb = m >> 11, t = m & (T_ - 1);
            u16* rowp = Cm + ((size_t)(bb * H_ + h_base + wn) * T_ + t) * D_;
            #pragma unroll
            for (int j = 0; j < 4; j++) {
                const int dk0 = j * 16 + quad * 4;
                u32x2 d { pk2(acc[i][j][0] * sc, acc[i][j][1] * sc),
                          pk2(acc[i][j][2] * sc, acc[i][j][3] * sc) };
                *(u32x2*)(rowp + dk0) = d;
            }
        }
    } else {
        // NORMAL: r walks t.
        #pragma unroll
        for (int i = 0; i < 4; i++) {
            const int m  = m0 + wm * 64 + i * 16 + quad * 4;   // r = 0 base
            const int bb = m >> 11, t = m & (T_ - 1);
            #pragma unroll
            for (int j = 0; j < 4; j++) {
                const int dk = j * 16 + l16;
                u32x2 d { pk2(acc[i][j][0], acc[i][j][1]),
                          pk2(acc[i][j][2], acc[i][j][3]) };
                *(u32x2*)(Vtc + ((size_t)(bb * H_ + h_base + wn) * D_ + dk) * T_ + t) = d;
            }
        }
    }
}

// ---------------------------------------------------------------------------
// Flash attention, swapped-operand (S^T = K.Q^T via 32x32x16 MFMA).
// Paired q-tiles {qa=pr, qb=31-pr}: 1024 blocks x 128 thr, 33 s-tiles each.
// Statically-distinct double buffers + counted-vmcnt raw-barrier pipeline:
// STAGE = 8 gld_lds per wave; steady-state vmcnt(8), drain 0 only at tail.
// ---------------------------------------------------------------------------
__global__ __launch_bounds__(128, 2) void attn_kernel(
    const u16* __restrict__ Qc, const u16* __restrict__ Kc,
    const u16* __restrict__ Vtc, float* __restrict__ out)
{
    __shared__ __attribute__((aligned(16))) u16 Ks0[64][64];  // swz [s][k]
    __shared__ __attribute__((aligned(16))) u16 Vs0[64][64];  // swz [dv][s]
    __shared__ __attribute__((aligned(16))) u16 Ks1[64][64];
    __shared__ __attribute__((aligned(16))) u16 Vs1[64][64];

    const int pb = blockIdx.x;
    const int lb = (pb & 7) * 128 + (pb >> 3);   // XCD swizzle (1024%8==0)
    const int pr = lb & 15;                       // pair id
    const int bh = lb >> 4;
    const int h  = bh & 15, b = bh >> 4;
    const int qa = pr, qb = 31 - pr;              // 33 s-tiles total

    const int tid = threadIdx.x, w = tid >> 6, lane = tid & 63;
    const int l31 = lane & 31, hi = lane >> 5;
    const int r8 = lane >> 3, g8 = lane & 7;
    const int gs = (g8 ^ r8) * 8;             // pre-swizzled source col (u16)
    const int ax = (l31 & 7) << 4;            // read-side byte XOR
    const int qloc = w * 32 + l31;            // q within the 64-row tile

    const u16* Qbh = Qc + (size_t)(b * H_ + h) * T_ * D_;
    const u16* Kbh = Kc + (size_t)(b * H_ + h) * T_ * D_;
    const u16* Vbh = Vtc + (size_t)(b * H_ + h) * D_ * T_;

    auto TS = [&](int i) { return (i <= qa) ? i : i - qa - 1; };

    auto STAGE = [&](u16* Kd, u16* Vd, int t) {
        const int sbase = t * 64;
        #pragma unroll
        for (int i2 = 0; i2 < 4; i2++) {
            const int seg = i2 * 2 + w;       // 8 segs of 8 rows each
            const int row = seg * 8 + r8;
            const int ldo = seg * 512 + lane * 8;               // u16 units
            gld_lds16(Kbh + (size_t)(sbase + row) * D_ + gs, Kd + ldo);
            gld_lds16(Vbh + (size_t)row * T_ + sbase + gs,  Vd + ldo);
        }
    };

    // phase state (A first: q-tile qa)
    int qrow = qa * 64 + qloc;
    u16x8 qf[4];
    #pragma unroll
    for (int ks = 0; ks < 4; ks++)
        qf[ks] = *(const u16x8*)(Qbh + (size_t)qrow * D_ + ks * 16 + hi * 8);

    f32x16 ot0, ot1;
    #pragma unroll
    for (int r = 0; r < 16; r++) { ot0[r] = 0.f; ot1[r] = 0.f; }
    float mi = -1e30f, li = 0.f;

    auto EPI = [&]() {
        const float inv = 1.0f / li;
        float* orow = out + (size_t)(b * T_ + qrow) * DMO + h * D_;
        #pragma unroll
        for (int c = 0; c < 2; c++)
            #pragma unroll
            for (int hf = 0; hf < 2; hf++) {
                f32x4 v0, v1;
                #pragma unroll
                for (int j = 0; j < 4; j++) {
                    v0[j] = ot0[c * 8 + hf * 4 + j] * inv;
                    v1[j] = ot1[c * 8 + hf * 4 + j] * inv;
                }
                *(f32x4*)(orow + c * 16 + hf * 8 + hi * 4)      = v0;
                *(f32x4*)(orow + 32 + c * 16 + hf * 8 + hi * 4) = v1;
            }
    };

    auto COMPUTE = [&](const char* Ksb, const char* Vsb, int i) {
        // S^T = K . Q^T   (two 32-s tiles, log2 domain)
        f32x16 st0, st1;
        #pragma unroll
        for (int r = 0; r < 16; r++) { st0[r] = 0.f; st1[r] = 0.f; }
        __builtin_amdgcn_s_setprio(1);
        #pragma unroll
        for (int ks = 0; ks < 4; ks++) {
            const int co = (ks * 16 + hi * 8) * 2;              // byte col
            u16x8 k0 = *(const u16x8*)(Ksb + ((l31 * 128 + co) ^ ax));
            u16x8 k1 = *(const u16x8*)(Ksb + (((32 + l31) * 128 + co) ^ ax));
            st0 = mfma32(k0, qf[ks], st0);
            st1 = mfma32(k1, qf[ks], st1);
        }
        __builtin_amdgcn_s_setprio(0);

        // causal mask — last tile of each phase is its diagonal (s0 == q0)
        if (i == qa || i == 32) {
            #pragma unroll
            for (int r = 0; r < 16; r++) {
                const int sl = (r & 3) + 8 * (r >> 2) + 4 * hi;
                if (sl > qloc)      st0[r] = -1e30f;
                if (sl + 32 > qloc) st1[r] = -1e30f;
            }
        }

        // online softmax: in-lane over 32 + one hi-swap
        float mx = -1e30f;
        #pragma unroll
        for (int r = 0; r < 16; r++) mx = fmaxf(mx, fmaxf(st0[r], st1[r]));
        mx = fmaxf(mx, __shfl_xor(mx, 32));
        if (!__all(mx - mi <= 8.f)) {         // defer-max (T13, THR=8)
            const float mn = fmaxf(mi, mx);
            const float al = EXP2(mi - mn);
            li *= al;
            #pragma unroll
            for (int r = 0; r < 16; r++) { ot0[r] *= al; ot1[r] *= al; }
            mi = mn;
        }
        float sum = 0.f;
        #pragma unroll
        for (int r = 0; r < 16; r++) {
            const float p0 = EXP2(st0[r] - mi);
            const float p1 = EXP2(st1[r] - mi);
            st0[r] = p0; st1[r] = p1;
            sum += p0 + p1;
        }
        sum += __shfl_xor(sum, 32);
        li += sum;

        // P^T -> PV B-frags: pk2 pairs + swap dwords across hi halves
        u16x8 pb4[4];
        #define PACK(SRC, C, OUT) {                                           \
            u32 d0 = pk2(SRC[8*(C)+0], SRC[8*(C)+1]);                         \
            u32 d1 = pk2(SRC[8*(C)+2], SRC[8*(C)+3]);                         \
            u32 d2 = pk2(SRC[8*(C)+4], SRC[8*(C)+5]);                         \
            u32 d3 = pk2(SRC[8*(C)+6], SRC[8*(C)+7]);                         \
            u32 e0 = __shfl_xor(hi ? d0 : d2, 32);                            \
            u32 e1 = __shfl_xor(hi ? d1 : d3, 32);                            \
            u32x4 wds{ hi ? e0 : d0, hi ? e1 : d1,                            \
                       hi ? d2 : e0, hi ? d3 : e1 };                          \
            OUT = __builtin_bit_cast(u16x8, wds); }
        PACK(st0, 0, pb4[0]); PACK(st0, 1, pb4[1]);
        PACK(st1, 0, pb4[2]); PACK(st1, 1, pb4[3]);
        #undef PACK

        // O^T += V^T . P^T  (A rows = dv, k = s)
        __builtin_amdgcn_s_setprio(1);
        #pragma unroll
        for (int kc = 0; kc < 4; kc++) {
            const int co = (kc * 16 + hi * 8) * 2;
            u16x8 v0 = *(const u16x8*)(Vsb + ((l31 * 128 + co) ^ ax));
            u16x8 v1 = *(const u16x8*)(Vsb + (((32 + l31) * 128 + co) ^ ax));
            ot0 = mfma32(v0, pb4[kc], ot0);
            ot1 = mfma32(v1, pb4[kc], ot1);
        }
        __builtin_amdgcn_s_setprio(0);

        if (i == qa) {                         // phase switch A -> B
            EPI();
            qrow = qb * 64 + qloc;
            #pragma unroll
            for (int ks = 0; ks < 4; ks++)
                qf[ks] = *(const u16x8*)(Qbh + (size_t)qrow * D_ + ks * 16 + hi * 8);
            #pragma unroll
            for (int r = 0; r < 16; r++) { ot0[r] = 0.f; ot1[r] = 0.f; }
            mi = -1e30f; li = 0.f;
        }
    };

    STAGE(&Ks0[0][0], &Vs0[0][0], 0);         // TS(0) = 0
    STAGE(&Ks1[0][0], &Vs1[0][0], TS(1));     // 16 outstanding / wave

    for (int j = 0; j < 16; j++) {
        const int i0 = 2 * j, i1 = 2 * j + 1;
        WAIT_BAR(8);
        COMPUTE((const char*)Ks0, (const char*)Vs0, i0);
        BAR_ONLY();
        if (i0 + 2 <= 32) STAGE(&Ks0[0][0], &Vs0[0][0], TS(i0 + 2));
        WAIT_BAR(8);
        COMPUTE((const char*)Ks1, (const char*)Vs1, i1);
        BAR_ONLY();
        if (i1 + 2 <= 32) STAGE(&Ks1[0][0], &Vs1[0][0], TS(i1 + 2));
    }
    WAIT_BAR(0);
    COMPUTE((const char*)Ks0, (const char*)Vs0, 32);   // tile 32 lives in buf0
    EPI();                                             // phase B output
}

// ---------------------------------------------------------------------------
extern "C" void kernel_launch(void* const* d_in, const int* in_sizes, int n_in,
                              void* d_out, int out_size, void* d_ws, size_t ws_size,
                              hipStream_t stream) {
    int xi = 0, wi[3] = {1, 2, 3};
    {
        int k = 0, found = 0;
        for (int i = 0; i < n_in && i < 8; i++) {
            if (in_sizes[i] == B_ * T_ * DM_) { xi = i; found = 1; }
            else if (in_sizes[i] == H_ * DM_ * D_ && k < 3) wi[k++] = i;
        }
        if (!found || k != 3) { xi = 0; wi[0] = 1; wi[1] = 2; wi[2] = 3; }
    }
    const float* x  = (const float*)d_in[xi];
    const float* Wq = (const float*)d_in[wi[0]];
    const float* Wk = (const float*)d_in[wi[1]];
    const float* Wv = (const float*)d_in[wi[2]];
    float* out = (float*)d_out;

    // bf16 staging scratch lives in d_out (dead before attn writes it):
    //   xb = 8.4M u16 (16.8 MB), Wt = 3.1M u16 (6.3 MB) -> 23.1 of 33.5 MB.
    u16* xb = (u16*)d_out;
    u16* Wt = xb + (size_t)B_ * T_ * DM_;
    // ws: Q + K + Vt bf16 = 50.3 MB (R8-verified to fit).
    const size_t per = (size_t)B_ * H_ * T_ * D_;
    u16* Qc  = (u16*)d_ws;
    u16* Kc  = Qc + per;
    u16* Vtc = Kc + per;

    cvt_all<<<1792, 256, 0, stream>>>(x, Wq, Wk, Wv, xb, Wt);
    proj_kernel<<<1536, 256, 0, stream>>>(xb, Wt, Qc, Kc, Vtc);
    attn_kernel<<<1024, 128, 0, stream>>>(Qc, Kc, Vtc, out);
}

// Round 6
// 227.004 us; speedup vs baseline: 1.3183x; 1.0265x over previous
//
#include <hip/hip_runtime.h>

// MHA forward.  B=4 T=2048 DM=1024 H=16 DK=DV=64.  f32 in / f32 out.
// R16: attn -> 8-wave shared-staging blocks (m214 shape).
//   R15 post-mortem: counted vmcnt was neutral -> stall wasn't load drain;
//   it was 2 waves/SIMD + private per-q-tile staging (528 tile-fills/bh).
//   Now: 512-thr block = 8 waves x 32 q-rows = 256 q-rows/block; K/V tile
//   staged once per block shared by 8 waves (144 tile-fills/bh, 3.7x less;
//   STAGE = 2 gld_lds/lane).  512 blocks = 2/CU = 4 waves/SIMD.  Causal:
//   wave-uniform skip of tiles past the wave diagonal (i_d = 4g + w/2).
//   LPT: big q-blocks (g=7) dispatch first; XCD decomposition keeps 8 bh
//   K/V sets (4 MB) per XCD L2.  Counted-vmcnt dbuf kept (WAIT 2 / tail 0).
//   proj (R15) and cvt unchanged.

#define B_  4
#define T_  2048
#define DM_ 1024
#define H_  16
#define D_  64
#define DMO 1024   // out row stride = H_*D_

typedef unsigned short u16;
typedef unsigned int   u32;
typedef u16   u16x8  __attribute__((ext_vector_type(8)));
typedef short s16x8  __attribute__((ext_vector_type(8)));
typedef float f32x4  __attribute__((ext_vector_type(4)));
typedef float f32x16 __attribute__((ext_vector_type(16)));
typedef u32   u32x2  __attribute__((ext_vector_type(2)));
typedef u32   u32x4  __attribute__((ext_vector_type(4)));

#if __has_builtin(__builtin_amdgcn_exp2f)
#define EXP2(x) __builtin_amdgcn_exp2f(x)
#else
#define EXP2(x) __expf((x) * 0.69314718f)
#endif

// counted-vmcnt barrier: wait own loads down to N, then sync, then pin.
#define WAIT_BAR(N) do {                                                      \
    asm volatile("s_waitcnt vmcnt(" #N ")" ::: "memory");                     \
    __builtin_amdgcn_s_barrier();                                             \
    __builtin_amdgcn_sched_barrier(0); } while (0)
#define BAR_ONLY() do {                                                       \
    __builtin_amdgcn_s_barrier();                                             \
    __builtin_amdgcn_sched_barrier(0); } while (0)

__device__ __forceinline__ u16 f2bf_hu(float f) {   // round-half-up (ties rare)
    u32 u = __builtin_bit_cast(u32, f) + 0x8000u;
    return (u16)(u >> 16);
}
// pack two f32 -> dword of two bf16 (lo,hi), 3 VALU ops
__device__ __forceinline__ u32 pk2(float lo, float hi) {
    u32 ul = __builtin_bit_cast(u32, lo) + 0x8000u;
    u32 uh = __builtin_bit_cast(u32, hi) + 0x8000u;
    return __builtin_amdgcn_perm(uh, ul, 0x07060302);  // [uh.hi16 : ul.hi16]
}
__device__ __forceinline__ u16x8 cvt8(const float* s) {
    f32x4 a = *(const f32x4*)s;
    f32x4 b = *(const f32x4*)(s + 4);
    u32x4 r { pk2(a[0], a[1]), pk2(a[2], a[3]), pk2(b[0], b[1]), pk2(b[2], b[3]) };
    return __builtin_bit_cast(u16x8, r);
}
__device__ __forceinline__ f32x4 mfma16(u16x8 a, u16x8 b, f32x4 c) {
    return __builtin_amdgcn_mfma_f32_16x16x32_bf16(
        __builtin_bit_cast(s16x8, a), __builtin_bit_cast(s16x8, b), c, 0, 0, 0);
}
__device__ __forceinline__ f32x16 mfma32(u16x8 a, u16x8 b, f32x16 c) {
    return __builtin_amdgcn_mfma_f32_32x32x16_bf16(
        __builtin_bit_cast(s16x8, a), __builtin_bit_cast(s16x8, b), c, 0, 0, 0);
}
// async global->LDS, 16B per lane.  LDS dest must be wave-uniform base + lane*16.
__device__ __forceinline__ void gld_lds16(const u16* g, u16* l) {
    __builtin_amdgcn_global_load_lds(
        (const __attribute__((address_space(1))) u32*)g,
        (__attribute__((address_space(3))) u32*)l, 16, 0, 0);
}

// ---------------------------------------------------------------------------
// cvt_all: blocks [0,1024): x f32 [8192][1024] -> xb bf16 (same layout).
//          blocks [1024,1792): W[mat][h][1024][64] f32 -> Wt bf16 transposed.
// ---------------------------------------------------------------------------
__global__ __launch_bounds__(256) void cvt_all(
    const float* __restrict__ x,  const float* __restrict__ Wq,
    const float* __restrict__ Wk, const float* __restrict__ Wv,
    u16* __restrict__ xb, u16* __restrict__ Wt)
{
    __shared__ u16 L[64][74];
    const int bx = blockIdx.x;
    if (bx < 1024) {
        size_t i0 = ((size_t)bx * 256 + threadIdx.x) * 32;
        #pragma unroll
        for (int c = 0; c < 4; c++)
            *(u16x8*)(xb + i0 + c * 8) = cvt8(x + i0 + c * 8);
        return;
    }
    const int wb = bx - 1024;
    const int dblk = wb & 15, h = (wb >> 4) & 15, mat = wb >> 8;
    const float* W = (mat == 0) ? Wq : (mat == 1) ? Wk : Wv;
    const int tid = threadIdx.x;
    {   // load 64(d) x 64(dk), coalesced, convert
        const int dl = tid >> 2, c = (tid & 3) * 16;
        const float* src = W + ((size_t)h * DM_ + dblk * 64 + dl) * D_ + c;
        #pragma unroll
        for (int g = 0; g < 2; g++)
            *(u16x8*)&L[dl][c + g * 8] = cvt8(src + g * 8);
    }
    __syncthreads();
    {   // write rows of Wt: row = dk, 16 d's per thread
        const int dkr = tid >> 2, g = tid & 3;
        u16 tmp[16];
        #pragma unroll
        for (int j = 0; j < 16; j++) tmp[j] = L[g * 16 + j][dkr];
        u16* dst = Wt + ((size_t)(mat * 16 + h) * 64 + dkr) * DM_ + dblk * 64 + g * 16;
        *(u16x8*)dst = *(u16x8*)tmp;
        *(u16x8*)(dst + 8) = *(u16x8*)(tmp + 8);
    }
}

// ---------------------------------------------------------------------------
// Projection GEMM: C[8192][3072] = xb @ Wt^T (Wt rows are C-columns).
// 1536 blocks (XCD-swizzled), 256 thr = 4 waves 2x2, 128x128 tile, BK=64.
// Counted-vmcnt pipeline: 8 gld_lds per STAGE per wave; vmcnt(8) steady.
// ---------------------------------------------------------------------------
template<int SWAP>
__device__ __forceinline__ void pcompute(const char* Asb, const char* Bsb,
                                         int wm, int wn, int quad, int l16,
                                         int ax, f32x4 (&acc)[4][4]) {
    #pragma unroll
    for (int ks = 0; ks < 2; ks++) {
        u16x8 af[4], bf[4];
        #pragma unroll
        for (int i = 0; i < 4; i++)
            af[i] = *(const u16x8*)(Asb +
                ((((wm * 64 + i * 16 + l16) * 64 + ks * 32 + quad * 8) * 2) ^ ax));
        #pragma unroll
        for (int j = 0; j < 4; j++)
            bf[j] = *(const u16x8*)(Bsb +
                ((((wn * 64 + j * 16 + l16) * 64 + ks * 32 + quad * 8) * 2) ^ ax));
        __builtin_amdgcn_s_setprio(1);
        #pragma unroll
        for (int i = 0; i < 4; i++)
            #pragma unroll
            for (int j = 0; j < 4; j++)
                acc[i][j] = SWAP ? mfma16(bf[j], af[i], acc[i][j])
                                 : mfma16(af[i], bf[j], acc[i][j]);
        __builtin_amdgcn_s_setprio(0);
    }
}

__global__ __launch_bounds__(256) void proj_kernel(
    const u16* __restrict__ xb, const u16* __restrict__ Wt,
    u16* __restrict__ Qc, u16* __restrict__ Kc, u16* __restrict__ Vtc)
{
    __shared__ __attribute__((aligned(16))) u16 As0[128][64];
    __shared__ __attribute__((aligned(16))) u16 Bs0[128][64];
    __shared__ __attribute__((aligned(16))) u16 As1[128][64];
    __shared__ __attribute__((aligned(16))) u16 Bs1[128][64];

    const int pb = blockIdx.x;
    const int wg = (pb & 7) * 192 + (pb >> 3);
    const int m0 = (wg & 63) * 128;
    const int n0 = (wg >> 6) * 128;           // n = mat*1024 + h*64 + dk
    const int mat = n0 >> 10;
    const int tid  = threadIdx.x;
    const int wave = tid >> 6, lane = tid & 63;
    const int quad = lane >> 4, l16 = lane & 15;
    const int wm   = wave >> 1, wn = wave & 1;

    const int r8 = lane >> 3, g8 = lane & 7;
    const int gs = (g8 ^ r8) * 8;             // pre-swizzled source col (u16)
    const int ax = (l16 & 7) << 4;            // read-side byte XOR

    f32x4 acc[4][4];
    #pragma unroll
    for (int i = 0; i < 4; i++)
        #pragma unroll
        for (int j = 0; j < 4; j++) acc[i][j] = f32x4{0.f, 0.f, 0.f, 0.f};

    auto STAGE = [&](u16* Ad, u16* Bd, int kb) {
        const int kbase = kb * 64;
        #pragma unroll
        for (int it = 0; it < 4; it++) {
            const int row = it * 32 + wave * 8 + r8;
            const int ldo = (it * 4 + wave) * 512 + lane * 8;   // u16 units
            gld_lds16(xb + (size_t)(m0 + row) * DM_ + kbase + gs, Ad + ldo);
            gld_lds16(Wt + (size_t)(n0 + row) * DM_ + kbase + gs, Bd + ldo);
        }
    };

    STAGE(&As0[0][0], &Bs0[0][0], 0);
    STAGE(&As1[0][0], &Bs1[0][0], 1);        // 16 outstanding / wave

    #define PLOOP(SW)                                                        \
        for (int j = 0; j < 8; j++) {                                        \
            WAIT_BAR(8);                                                     \
            pcompute<SW>((const char*)As0, (const char*)Bs0,                 \
                         wm, wn, quad, l16, ax, acc);                        \
            BAR_ONLY();                                                      \
            if (2 * j + 2 < 16) STAGE(&As0[0][0], &Bs0[0][0], 2 * j + 2);    \
            if (j < 7) { WAIT_BAR(8); } else { WAIT_BAR(0); }                \
            pcompute<SW>((const char*)As1, (const char*)Bs1,                 \
                         wm, wn, quad, l16, ax, acc);                        \
            BAR_ONLY();                                                      \
            if (2 * j + 3 < 16) STAGE(&As1[0][0], &Bs1[0][0], 2 * j + 3);    \
        }
    if (mat != 2) { PLOOP(1) } else { PLOOP(0) }
    #undef PLOOP

    const int h_base = (n0 & 1023) >> 6;
    if (mat != 2) {
        // SWAPPED: r walks dk.
        u16* Cm = (mat == 0) ? Qc : Kc;
        const float sc = (mat == 0) ? 0.18033688f : 1.0f;  // Q: dk^-.5*log2e
        #pragma unroll
        for (int i = 0; i < 4; i++) {
            const int m  = m0 + wm * 64 + i * 16 + l16;
            const int bb = m >> 11, t = m & (T_ - 1);
            u16* rowp = Cm + ((size_t)(bb * H_ + h_base + wn) * T_ + t) * D_;
            #pragma unroll
            for (int j = 0; j < 4; j++) {
                const int dk0 = j * 16 + quad * 4;
                u32x2 d { pk2(acc[i][j][0] * sc, acc[i][j][1] * sc),
                          pk2(acc[i][j][2] * sc, acc[i][j][3] * sc) };
                *(u32x2*)(rowp + dk0) = d;
            }
        }
    } else {
        // NORMAL: r walks t.
        #pragma unroll
        for (int i = 0; i < 4; i++) {
            const int m  = m0 + wm * 64 + i * 16 + quad * 4;   // r = 0 base
            const int bb = m >> 11, t = m & (T_ - 1);
            #pragma unroll
            for (int j = 0; j < 4; j++) {
                const int dk = j * 16 + l16;
                u32x2 d { pk2(acc[i][j][0], acc[i][j][1]),
                          pk2(acc[i][j][2], acc[i][j][3]) };
                *(u32x2*)(Vtc + ((size_t)(bb * H_ + h_base + wn) * D_ + dk) * T_ + t) = d;
            }
        }
    }
}

// ---------------------------------------------------------------------------
// Flash attention, swapped-operand (S^T = K.Q^T via 32x32x16 MFMA).
// 8-wave blocks: 512 thr own 256 consecutive q-rows (wave w -> 32 rows);
// K/V tile staged ONCE per block (STAGE = 2 gld_lds/lane), shared by all
// waves.  512 blocks (64 bh x 8 q-blocks) = 2/CU = 4 waves/SIMD.  Causal:
// wave-uniform skip of tiles past wave diagonal i_d = 4g + (w>>1); big
// q-blocks dispatch first (LPT).  Counted-vmcnt double buffer.
// ---------------------------------------------------------------------------
__global__ __launch_bounds__(512, 2) void attn_kernel(
    const u16* __restrict__ Qc, const u16* __restrict__ Kc,
    const u16* __restrict__ Vtc, float* __restrict__ out)
{
    __shared__ __attribute__((aligned(16))) u16 Ks0[64][64];  // swz [s][k]
    __shared__ __attribute__((aligned(16))) u16 Vs0[64][64];  // swz [dv][s]
    __shared__ __attribute__((aligned(16))) u16 Ks1[64][64];
    __shared__ __attribute__((aligned(16))) u16 Vs1[64][64];

    const int pb  = blockIdx.x;
    const int bh  = (pb & 7) * 8 + ((pb >> 3) & 7);  // 8 bh-sets per XCD (L2)
    const int g   = 7 - (pb >> 6);                   // big q-blocks first (LPT)
    const int h   = bh & 15, b = bh >> 4;

    const int tid = threadIdx.x, w = tid >> 6, lane = tid & 63;
    const int l31 = lane & 31, hi = lane >> 5;
    const int r8 = (tid >> 3) & 7, g8 = tid & 7;
    const int gs = (g8 ^ r8) * 8;             // pre-swizzled source col (u16)
    const int ax = (l31 & 7) << 4;            // read-side byte XOR

    const int qrow = g * 256 + w * 32 + l31;  // this lane's q (S^T column)
    const int i_d  = g * 4 + (w >> 1);        // wave's diagonal s-tile
    const int nt   = g * 4 + 4;               // s-tiles this block stages
    const int qmask = 32 * (w & 1) + l31;     // q within the diagonal tile

    const u16* Qbh = Qc + (size_t)(b * H_ + h) * T_ * D_;
    const u16* Kbh = Kc + (size_t)(b * H_ + h) * T_ * D_;
    const u16* Vbh = Vtc + (size_t)(b * H_ + h) * D_ * T_;

    auto STAGE = [&](u16* Kd, u16* Vd, int t) {
        const int sbase = t * 64;
        const int row = tid >> 3;             // 512 thr cover 64 rows x 8 gran
        const int ldo = tid * 8;              // u16 units (lane*16B, wave-lin)
        gld_lds16(Kbh + (size_t)(sbase + row) * D_ + gs, Kd + ldo);
        gld_lds16(Vbh + (size_t)row * T_ + sbase + gs,  Vd + ldo);
    };

    // Q B-frags (col=lane&31=q, k = hi*8+e per 16-chunk), scaled at proj.
    u16x8 qf[4];
    #pragma unroll
    for (int ks = 0; ks < 4; ks++)
        qf[ks] = *(const u16x8*)(Qbh + (size_t)qrow * D_ + ks * 16 + hi * 8);

    f32x16 ot0, ot1;                          // O^T accum: dv 0..31 / 32..63
    #pragma unroll
    for (int r = 0; r < 16; r++) { ot0[r] = 0.f; ot1[r] = 0.f; }
    float mi = -1e30f, li = 0.f;

    auto COMPUTE = [&](const char* Ksb, const char* Vsb, int i) {
        // S^T = K . Q^T   (two 32-s tiles, log2 domain)
        f32x16 st0, st1;
        #pragma unroll
        for (int r = 0; r < 16; r++) { st0[r] = 0.f; st1[r] = 0.f; }
        __builtin_amdgcn_s_setprio(1);
        #pragma unroll
        for (int ks = 0; ks < 4; ks++) {
            const int co = (ks * 16 + hi * 8) * 2;              // byte col
            u16x8 k0 = *(const u16x8*)(Ksb + ((l31 * 128 + co) ^ ax));
            u16x8 k1 = *(const u16x8*)(Ksb + (((32 + l31) * 128 + co) ^ ax));
            st0 = mfma32(k0, qf[ks], st0);
            st1 = mfma32(k1, qf[ks], st1);
        }
        __builtin_amdgcn_s_setprio(0);

        // causal mask — only the wave's diagonal s-tile is partial
        if (i == i_d) {
            #pragma unroll
            for (int r = 0; r < 16; r++) {
                const int sl = (r & 3) + 8 * (r >> 2) + 4 * hi;
                if (sl > qmask)      st0[r] = -1e30f;
                if (sl + 32 > qmask) st1[r] = -1e30f;
            }
        }

        // online softmax: in-lane over 32 + one hi-swap
        float mx = -1e30f;
        #pragma unroll
        for (int r = 0; r < 16; r++) mx = fmaxf(mx, fmaxf(st0[r], st1[r]));
        mx = fmaxf(mx, __shfl_xor(mx, 32));
        if (!__all(mx - mi <= 8.f)) {         // defer-max (T13, THR=8)
            const float mn = fmaxf(mi, mx);
            const float al = EXP2(mi - mn);
            li *= al;
            #pragma unroll
            for (int r = 0; r < 16; r++) { ot0[r] *= al; ot1[r] *= al; }
            mi = mn;
        }
        float sum = 0.f;
        #pragma unroll
        for (int r = 0; r < 16; r++) {
            const float p0 = EXP2(st0[r] - mi);
            const float p1 = EXP2(st1[r] - mi);
            st0[r] = p0; st1[r] = p1;
            sum += p0 + p1;
        }
        sum += __shfl_xor(sum, 32);
        li += sum;

        // P^T -> PV B-frags: pk2 pairs + swap dwords across hi halves
        u16x8 pb4[4];
        #define PACK(SRC, C, OUT) {                                           \
            u32 d0 = pk2(SRC[8*(C)+0], SRC[8*(C)+1]);                         \
            u32 d1 = pk2(SRC[8*(C)+2], SRC[8*(C)+3]);                         \
            u32 d2 = pk2(SRC[8*(C)+4], SRC[8*(C)+5]);                         \
            u32 d3 = pk2(SRC[8*(C)+6], SRC[8*(C)+7]);                         \
            u32 e0 = __shfl_xor(hi ? d0 : d2, 32);                            \
            u32 e1 = __shfl_xor(hi ? d1 : d3, 32);                            \
            u32x4 wds{ hi ? e0 : d0, hi ? e1 : d1,                            \
                       hi ? d2 : e0, hi ? d3 : e1 };                          \
            OUT = __builtin_bit_cast(u16x8, wds); }
        PACK(st0, 0, pb4[0]); PACK(st0, 1, pb4[1]);
        PACK(st1, 0, pb4[2]); PACK(st1, 1, pb4[3]);
        #undef PACK

        // O^T += V^T . P^T  (A rows = dv, k = s)
        __builtin_amdgcn_s_setprio(1);
        #pragma unroll
        for (int kc = 0; kc < 4; kc++) {
            const int co = (kc * 16 + hi * 8) * 2;
            u16x8 v0 = *(const u16x8*)(Vsb + ((l31 * 128 + co) ^ ax));
            u16x8 v1 = *(const u16x8*)(Vsb + (((32 + l31) * 128 + co) ^ ax));
            ot0 = mfma32(v0, pb4[kc], ot0);
            ot1 = mfma32(v1, pb4[kc], ot1);
        }
        __builtin_amdgcn_s_setprio(0);
    };

    STAGE(&Ks0[0][0], &Vs0[0][0], 0);
    STAGE(&Ks1[0][0], &Vs1[0][0], 1);         // 4 outstanding / lane

    const int np = nt >> 1;                   // nt is even (4g+4)
    for (int j = 0; j < np; j++) {
        const int i0 = 2 * j, i1 = 2 * j + 1;
        WAIT_BAR(2);
        if (i0 <= i_d) COMPUTE((const char*)Ks0, (const char*)Vs0, i0);
        BAR_ONLY();
        if (i0 + 2 < nt) STAGE(&Ks0[0][0], &Vs0[0][0], i0 + 2);
        if (j < np - 1) { WAIT_BAR(2); } else { WAIT_BAR(0); }
        if (i1 <= i_d) COMPUTE((const char*)Ks1, (const char*)Vs1, i1);
        BAR_ONLY();
        if (i1 + 2 < nt) STAGE(&Ks1[0][0], &Vs1[0][0], i1 + 2);
    }

    // output: O^T reg r -> dv = td*32 + 16c + 8hf + 4hi + j, q = qrow
    const float inv = 1.0f / li;
    float* orow = out + (size_t)(b * T_ + qrow) * DMO + h * D_;
    #pragma unroll
    for (int c = 0; c < 2; c++)
        #pragma unroll
        for (int hf = 0; hf < 2; hf++) {
            f32x4 v0, v1;
            #pragma unroll
            for (int j = 0; j < 4; j++) {
                v0[j] = ot0[c * 8 + hf * 4 + j] * inv;
                v1[j] = ot1[c * 8 + hf * 4 + j] * inv;
            }
            *(f32x4*)(orow + c * 16 + hf * 8 + hi * 4)      = v0;
            *(f32x4*)(orow + 32 + c * 16 + hf * 8 + hi * 4) = v1;
        }
}

// ---------------------------------------------------------------------------
extern "C" void kernel_launch(void* const* d_in, const int* in_sizes, int n_in,
                              void* d_out, int out_size, void* d_ws, size_t ws_size,
                              hipStream_t stream) {
    int xi = 0, wi[3] = {1, 2, 3};
    {
        int k = 0, found = 0;
        for (int i = 0; i < n_in && i < 8; i++) {
            if (in_sizes[i] == B_ * T_ * DM_) { xi = i; found = 1; }
            else if (in_sizes[i] == H_ * DM_ * D_ && k < 3) wi[k++] = i;
        }
        if (!found || k != 3) { xi = 0; wi[0] = 1; wi[1] = 2; wi[2] = 3; }
    }
    const float* x  = (const float*)d_in[xi];
    const float* Wq = (const float*)d_in[wi[0]];
    const float* Wk = (const float*)d_in[wi[1]];
    const float* Wv = (const float*)d_in[wi[2]];
    float* out = (float*)d_out;

    // bf16 staging scratch lives in d_out (dead before attn writes it):
    //   xb = 8.4M u16 (16.8 MB), Wt = 3.1M u16 (6.3 MB) -> 23.1 of 33.5 MB.
    u16* xb = (u16*)d_out;
    u16* Wt = xb + (size_t)B_ * T_ * DM_;
    // ws: Q + K + Vt bf16 = 50.3 MB (R8-verified to fit).
    const size_t per = (size_t)B_ * H_ * T_ * D_;
    u16* Qc  = (u16*)d_ws;
    u16* Kc  = Qc + per;
    u16* Vtc = Kc + per;

    cvt_all<<<1792, 256, 0, stream>>>(x, Wq, Wk, Wv, xb, Wt);
    proj_kernel<<<1536, 256, 0, stream>>>(xb, Wt, Qc, Kc, Vtc);
    attn_kernel<<<512, 512, 0, stream>>>(Qc, Kc, Vtc, out);
}

// Round 7
// 216.456 us; speedup vs baseline: 1.3825x; 1.0487x over previous
//
#include <hip/hip_runtime.h>

// MHA forward.  B=4 T=2048 DM=1024 H=16 DK=DV=64.  f32 in / f32 out.
// R17: proj L2-locality fix + attn zero-init hoist.
//   proj: R12's XCD mapping gave each XCD 3 n-cols x ALL 64 m-tiles ->
//   the full 16.8 MB A-panel streamed through each 4 MB L2 three times
//   (FETCH 200 MB vs 23 ideal; 2.6 TB/s stream = dispatch duration).
//   Now XCD x owns m-tiles [8x,8x+8) x all 24 n (m-fastest): resident
//   set = 2 MB A-slice + streaming Wt cols ~= L2.  Index-only change.
//   attn: per-tile S^T re-zero (32 v_mov/tile/wave) replaced by a
//   loop-invariant zero accumulator fed to the first MFMA (ks=0 inits,
//   ks=1..3 accumulate).  Everything else = R16 (passed).

#define B_  4
#define T_  2048
#define DM_ 1024
#define H_  16
#define D_  64
#define DMO 1024   // out row stride = H_*D_

typedef unsigned short u16;
typedef unsigned int   u32;
typedef u16   u16x8  __attribute__((ext_vector_type(8)));
typedef short s16x8  __attribute__((ext_vector_type(8)));
typedef float f32x4  __attribute__((ext_vector_type(4)));
typedef float f32x16 __attribute__((ext_vector_type(16)));
typedef u32   u32x2  __attribute__((ext_vector_type(2)));
typedef u32   u32x4  __attribute__((ext_vector_type(4)));

#if __has_builtin(__builtin_amdgcn_exp2f)
#define EXP2(x) __builtin_amdgcn_exp2f(x)
#else
#define EXP2(x) __expf((x) * 0.69314718f)
#endif

// counted-vmcnt barrier: wait own loads down to N, then sync, then pin.
#define WAIT_BAR(N) do {                                                      \
    asm volatile("s_waitcnt vmcnt(" #N ")" ::: "memory");                     \
    __builtin_amdgcn_s_barrier();                                             \
    __builtin_amdgcn_sched_barrier(0); } while (0)
#define BAR_ONLY() do {                                                       \
    __builtin_amdgcn_s_barrier();                                             \
    __builtin_amdgcn_sched_barrier(0); } while (0)

__device__ __forceinline__ u16 f2bf_hu(float f) {   // round-half-up (ties rare)
    u32 u = __builtin_bit_cast(u32, f) + 0x8000u;
    return (u16)(u >> 16);
}
// pack two f32 -> dword of two bf16 (lo,hi), 3 VALU ops
__device__ __forceinline__ u32 pk2(float lo, float hi) {
    u32 ul = __builtin_bit_cast(u32, lo) + 0x8000u;
    u32 uh = __builtin_bit_cast(u32, hi) + 0x8000u;
    return __builtin_amdgcn_perm(uh, ul, 0x07060302);  // [uh.hi16 : ul.hi16]
}
__device__ __forceinline__ u16x8 cvt8(const float* s) {
    f32x4 a = *(const f32x4*)s;
    f32x4 b = *(const f32x4*)(s + 4);
    u32x4 r { pk2(a[0], a[1]), pk2(a[2], a[3]), pk2(b[0], b[1]), pk2(b[2], b[3]) };
    return __builtin_bit_cast(u16x8, r);
}
__device__ __forceinline__ f32x4 mfma16(u16x8 a, u16x8 b, f32x4 c) {
    return __builtin_amdgcn_mfma_f32_16x16x32_bf16(
        __builtin_bit_cast(s16x8, a), __builtin_bit_cast(s16x8, b), c, 0, 0, 0);
}
__device__ __forceinline__ f32x16 mfma32(u16x8 a, u16x8 b, f32x16 c) {
    return __builtin_amdgcn_mfma_f32_32x32x16_bf16(
        __builtin_bit_cast(s16x8, a), __builtin_bit_cast(s16x8, b), c, 0, 0, 0);
}
// async global->LDS, 16B per lane.  LDS dest must be wave-uniform base + lane*16.
__device__ __forceinline__ void gld_lds16(const u16* g, u16* l) {
    __builtin_amdgcn_global_load_lds(
        (const __attribute__((address_space(1))) u32*)g,
        (__attribute__((address_space(3))) u32*)l, 16, 0, 0);
}

// ---------------------------------------------------------------------------
// cvt_all: blocks [0,1024): x f32 [8192][1024] -> xb bf16 (same layout).
//          blocks [1024,1792): W[mat][h][1024][64] f32 -> Wt bf16 transposed.
// ---------------------------------------------------------------------------
__global__ __launch_bounds__(256) void cvt_all(
    const float* __restrict__ x,  const float* __restrict__ Wq,
    const float* __restrict__ Wk, const float* __restrict__ Wv,
    u16* __restrict__ xb, u16* __restrict__ Wt)
{
    __shared__ u16 L[64][74];
    const int bx = blockIdx.x;
    if (bx < 1024) {
        size_t i0 = ((size_t)bx * 256 + threadIdx.x) * 32;
        #pragma unroll
        for (int c = 0; c < 4; c++)
            *(u16x8*)(xb + i0 + c * 8) = cvt8(x + i0 + c * 8);
        return;
    }
    const int wb = bx - 1024;
    const int dblk = wb & 15, h = (wb >> 4) & 15, mat = wb >> 8;
    const float* W = (mat == 0) ? Wq : (mat == 1) ? Wk : Wv;
    const int tid = threadIdx.x;
    {   // load 64(d) x 64(dk), coalesced, convert
        const int dl = tid >> 2, c = (tid & 3) * 16;
        const float* src = W + ((size_t)h * DM_ + dblk * 64 + dl) * D_ + c;
        #pragma unroll
        for (int g = 0; g < 2; g++)
            *(u16x8*)&L[dl][c + g * 8] = cvt8(src + g * 8);
    }
    __syncthreads();
    {   // write rows of Wt: row = dk, 16 d's per thread
        const int dkr = tid >> 2, g = tid & 3;
        u16 tmp[16];
        #pragma unroll
        for (int j = 0; j < 16; j++) tmp[j] = L[g * 16 + j][dkr];
        u16* dst = Wt + ((size_t)(mat * 16 + h) * 64 + dkr) * DM_ + dblk * 64 + g * 16;
        *(u16x8*)dst = *(u16x8*)tmp;
        *(u16x8*)(dst + 8) = *(u16x8*)(tmp + 8);
    }
}

// ---------------------------------------------------------------------------
// Projection GEMM: C[8192][3072] = xb @ Wt^T (Wt rows are C-columns).
// 1536 blocks, 256 thr = 4 waves 2x2, 128x128 tile, BK=64.
// XCD m-slice mapping: XCD x owns m-tiles [8x,8x+8) x all 24 n, m-fastest
// -> per-XCD L2 working set = 2 MB A-slice + streaming Wt cols.
// Counted-vmcnt pipeline: 8 gld_lds per STAGE per wave; vmcnt(8) steady.
// ---------------------------------------------------------------------------
template<int SWAP>
__device__ __forceinline__ void pcompute(const char* Asb, const char* Bsb,
                                         int wm, int wn, int quad, int l16,
                                         int ax, f32x4 (&acc)[4][4]) {
    #pragma unroll
    for (int ks = 0; ks < 2; ks++) {
        u16x8 af[4], bf[4];
        #pragma unroll
        for (int i = 0; i < 4; i++)
            af[i] = *(const u16x8*)(Asb +
                ((((wm * 64 + i * 16 + l16) * 64 + ks * 32 + quad * 8) * 2) ^ ax));
        #pragma unroll
        for (int j = 0; j < 4; j++)
            bf[j] = *(const u16x8*)(Bsb +
                ((((wn * 64 + j * 16 + l16) * 64 + ks * 32 + quad * 8) * 2) ^ ax));
        __builtin_amdgcn_s_setprio(1);
        #pragma unroll
        for (int i = 0; i < 4; i++)
            #pragma unroll
            for (int j = 0; j < 4; j++)
                acc[i][j] = SWAP ? mfma16(bf[j], af[i], acc[i][j])
                                 : mfma16(af[i], bf[j], acc[i][j]);
        __builtin_amdgcn_s_setprio(0);
    }
}

__global__ __launch_bounds__(256) void proj_kernel(
    const u16* __restrict__ xb, const u16* __restrict__ Wt,
    u16* __restrict__ Qc, u16* __restrict__ Kc, u16* __restrict__ Vtc)
{
    __shared__ __attribute__((aligned(16))) u16 As0[128][64];
    __shared__ __attribute__((aligned(16))) u16 Bs0[128][64];
    __shared__ __attribute__((aligned(16))) u16 As1[128][64];
    __shared__ __attribute__((aligned(16))) u16 Bs1[128][64];

    // XCD m-slice supertiling: pb = xcd + 8*mid + 64*ntile (bijective).
    const int pb = blockIdx.x;
    const int mt = (pb & 7) * 8 + ((pb >> 3) & 7);   // m-tile 0..63
    const int nti = pb >> 6;                         // n-tile 0..23
    const int m0 = mt * 128;
    const int n0 = nti * 128;                 // n = mat*1024 + h*64 + dk
    const int mat = n0 >> 10;
    const int tid  = threadIdx.x;
    const int wave = tid >> 6, lane = tid & 63;
    const int quad = lane >> 4, l16 = lane & 15;
    const int wm   = wave >> 1, wn = wave & 1;

    const int r8 = lane >> 3, g8 = lane & 7;
    const int gs = (g8 ^ r8) * 8;             // pre-swizzled source col (u16)
    const int ax = (l16 & 7) << 4;            // read-side byte XOR

    f32x4 acc[4][4];
    #pragma unroll
    for (int i = 0; i < 4; i++)
        #pragma unroll
        for (int j = 0; j < 4; j++) acc[i][j] = f32x4{0.f, 0.f, 0.f, 0.f};

    auto STAGE = [&](u16* Ad, u16* Bd, int kb) {
        const int kbase = kb * 64;
        #pragma unroll
        for (int it = 0; it < 4; it++) {
            const int row = it * 32 + wave * 8 + r8;
            const int ldo = (it * 4 + wave) * 512 + lane * 8;   // u16 units
            gld_lds16(xb + (size_t)(m0 + row) * DM_ + kbase + gs, Ad + ldo);
            gld_lds16(Wt + (size_t)(n0 + row) * DM_ + kbase + gs, Bd + ldo);
        }
    };

    STAGE(&As0[0][0], &Bs0[0][0], 0);
    STAGE(&As1[0][0], &Bs1[0][0], 1);        // 16 outstanding / wave

    #define PLOOP(SW)                                                        \
        for (int j = 0; j < 8; j++) {                                        \
            WAIT_BAR(8);                                                     \
            pcompute<SW>((const char*)As0, (const char*)Bs0,                 \
                         wm, wn, quad, l16, ax, acc);                        \
            BAR_ONLY();                                                      \
            if (2 * j + 2 < 16) STAGE(&As0[0][0], &Bs0[0][0], 2 * j + 2);    \
            if (j < 7) { WAIT_BAR(8); } else { WAIT_BAR(0); }                \
            pcompute<SW>((const char*)As1, (const char*)Bs1,                 \
                         wm, wn, quad, l16, ax, acc);                        \
            BAR_ONLY();                                                      \
            if (2 * j + 3 < 16) STAGE(&As1[0][0], &Bs1[0][0], 2 * j + 3);    \
        }
    if (mat != 2) { PLOOP(1) } else { PLOOP(0) }
    #undef PLOOP

    const int h_base = (n0 & 1023) >> 6;
    if (mat != 2) {
        // SWAPPED: r walks dk.
        u16* Cm = (mat == 0) ? Qc : Kc;
        const float sc = (mat == 0) ? 0.18033688f : 1.0f;  // Q: dk^-.5*log2e
        #pragma unroll
        for (int i = 0; i < 4; i++) {
            const int m  = m0 + wm * 64 + i * 16 + l16;
            const int bb = m >> 11, t = m & (T_ - 1);
            u16* rowp = Cm + ((size_t)(bb * H_ + h_base + wn) * T_ + t) * D_;
            #pragma unroll
            for (int j = 0; j < 4; j++) {
                const int dk0 = j * 16 + quad * 4;
                u32x2 d { pk2(acc[i][j][0] * sc, acc[i][j][1] * sc),
                          pk2(acc[i][j][2] * sc, acc[i][j][3] * sc) };
                *(u32x2*)(rowp + dk0) = d;
            }
        }
    } else {
        // NORMAL: r walks t.
        #pragma unroll
        for (int i = 0; i < 4; i++) {
            const int m  = m0 + wm * 64 + i * 16 + quad * 4;   // r = 0 base
            const int bb = m >> 11, t = m & (T_ - 1);
            #pragma unroll
            for (int j = 0; j < 4; j++) {
                const int dk = j * 16 + l16;
                u32x2 d { pk2(acc[i][j][0], acc[i][j][1]),
                          pk2(acc[i][j][2], acc[i][j][3]) };
                *(u32x2*)(Vtc + ((size_t)(bb * H_ + h_base + wn) * D_ + dk) * T_ + t) = d;
            }
        }
    }
}

// ---------------------------------------------------------------------------
// Flash attention, swapped-operand (S^T = K.Q^T via 32x32x16 MFMA).
// 8-wave blocks: 512 thr own 256 consecutive q-rows (wave w -> 32 rows);
// K/V tile staged ONCE per block, shared by all waves.  512 blocks
// (64 bh x 8 q-blocks) = 2/CU = 4 waves/SIMD.  Causal: wave-uniform skip
// past wave diagonal i_d = 4g + (w>>1); big q-blocks first (LPT).
// Counted-vmcnt double buffer; zero-const MFMA C-init (no per-tile re-zero).
// ---------------------------------------------------------------------------
__global__ __launch_bounds__(512, 2) void attn_kernel(
    const u16* __restrict__ Qc, const u16* __restrict__ Kc,
    const u16* __restrict__ Vtc, float* __restrict__ out)
{
    __shared__ __attribute__((aligned(16))) u16 Ks0[64][64];  // swz [s][k]
    __shared__ __attribute__((aligned(16))) u16 Vs0[64][64];  // swz [dv][s]
    __shared__ __attribute__((aligned(16))) u16 Ks1[64][64];
    __shared__ __attribute__((aligned(16))) u16 Vs1[64][64];

    const int pb  = blockIdx.x;
    const int bh  = (pb & 7) * 8 + ((pb >> 3) & 7);  // 8 bh-sets per XCD (L2)
    const int g   = 7 - (pb >> 6);                   // big q-blocks first (LPT)
    const int h   = bh & 15, b = bh >> 4;

    const int tid = threadIdx.x, w = tid >> 6, lane = tid & 63;
    const int l31 = lane & 31, hi = lane >> 5;
    const int r8 = (tid >> 3) & 7, g8 = tid & 7;
    const int gs = (g8 ^ r8) * 8;             // pre-swizzled source col (u16)
    const int ax = (l31 & 7) << 4;            // read-side byte XOR

    const int qrow = g * 256 + w * 32 + l31;  // this lane's q (S^T column)
    const int i_d  = g * 4 + (w >> 1);        // wave's diagonal s-tile
    const int nt   = g * 4 + 4;               // s-tiles this block stages
    const int qmask = 32 * (w & 1) + l31;     // q within the diagonal tile

    const u16* Qbh = Qc + (size_t)(b * H_ + h) * T_ * D_;
    const u16* Kbh = Kc + (size_t)(b * H_ + h) * T_ * D_;
    const u16* Vbh = Vtc + (size_t)(b * H_ + h) * D_ * T_;

    auto STAGE = [&](u16* Kd, u16* Vd, int t) {
        const int sbase = t * 64;
        const int row = tid >> 3;             // 512 thr cover 64 rows x 8 gran
        const int ldo = tid * 8;              // u16 units (lane*16B, wave-lin)
        gld_lds16(Kbh + (size_t)(sbase + row) * D_ + gs, Kd + ldo);
        gld_lds16(Vbh + (size_t)row * T_ + sbase + gs,  Vd + ldo);
    };

    // Q B-frags (col=lane&31=q, k = hi*8+e per 16-chunk), scaled at proj.
    u16x8 qf[4];
    #pragma unroll
    for (int ks = 0; ks < 4; ks++)
        qf[ks] = *(const u16x8*)(Qbh + (size_t)qrow * D_ + ks * 16 + hi * 8);

    // loop-invariant zero accumulator (hoisted out of the tile loop)
    f32x16 zz;
    #pragma unroll
    for (int r = 0; r < 16; r++) zz[r] = 0.f;

    f32x16 ot0, ot1;                          // O^T accum: dv 0..31 / 32..63
    #pragma unroll
    for (int r = 0; r < 16; r++) { ot0[r] = 0.f; ot1[r] = 0.f; }
    float mi = -1e30f, li = 0.f;

    auto COMPUTE = [&](const char* Ksb, const char* Vsb, int i) {
        // S^T = K . Q^T   (two 32-s tiles, log2 domain); ks=0 inits from zz
        f32x16 st0, st1;
        __builtin_amdgcn_s_setprio(1);
        {
            const int co = (hi * 8) * 2;                        // ks = 0
            u16x8 k0 = *(const u16x8*)(Ksb + ((l31 * 128 + co) ^ ax));
            u16x8 k1 = *(const u16x8*)(Ksb + (((32 + l31) * 128 + co) ^ ax));
            st0 = mfma32(k0, qf[0], zz);
            st1 = mfma32(k1, qf[0], zz);
        }
        #pragma unroll
        for (int ks = 1; ks < 4; ks++) {
            const int co = (ks * 16 + hi * 8) * 2;              // byte col
            u16x8 k0 = *(const u16x8*)(Ksb + ((l31 * 128 + co) ^ ax));
            u16x8 k1 = *(const u16x8*)(Ksb + (((32 + l31) * 128 + co) ^ ax));
            st0 = mfma32(k0, qf[ks], st0);
            st1 = mfma32(k1, qf[ks], st1);
        }
        __builtin_amdgcn_s_setprio(0);

        // causal mask — only the wave's diagonal s-tile is partial
        if (i == i_d) {
            #pragma unroll
            for (int r = 0; r < 16; r++) {
                const int sl = (r & 3) + 8 * (r >> 2) + 4 * hi;
                if (sl > qmask)      st0[r] = -1e30f;
                if (sl + 32 > qmask) st1[r] = -1e30f;
            }
        }

        // online softmax: in-lane over 32 + one hi-swap
        float mx = -1e30f;
        #pragma unroll
        for (int r = 0; r < 16; r++) mx = fmaxf(mx, fmaxf(st0[r], st1[r]));
        mx = fmaxf(mx, __shfl_xor(mx, 32));
        if (!__all(mx - mi <= 8.f)) {         // defer-max (T13, THR=8)
            const float mn = fmaxf(mi, mx);
            const float al = EXP2(mi - mn);
            li *= al;
            #pragma unroll
            for (int r = 0; r < 16; r++) { ot0[r] *= al; ot1[r] *= al; }
            mi = mn;
        }
        float sum = 0.f;
        #pragma unroll
        for (int r = 0; r < 16; r++) {
            const float p0 = EXP2(st0[r] - mi);
            const float p1 = EXP2(st1[r] - mi);
            st0[r] = p0; st1[r] = p1;
            sum += p0 + p1;
        }
        sum += __shfl_xor(sum, 32);
        li += sum;

        // P^T -> PV B-frags: pk2 pairs + swap dwords across hi halves
        u16x8 pb4[4];
        #define PACK(SRC, C, OUT) {                                           \
            u32 d0 = pk2(SRC[8*(C)+0], SRC[8*(C)+1]);                         \
            u32 d1 = pk2(SRC[8*(C)+2], SRC[8*(C)+3]);                         \
            u32 d2 = pk2(SRC[8*(C)+4], SRC[8*(C)+5]);                         \
            u32 d3 = pk2(SRC[8*(C)+6], SRC[8*(C)+7]);                         \
            u32 e0 = __shfl_xor(hi ? d0 : d2, 32);                            \
            u32 e1 = __shfl_xor(hi ? d1 : d3, 32);                            \
            u32x4 wds{ hi ? e0 : d0, hi ? e1 : d1,                            \
                       hi ? d2 : e0, hi ? d3 : e1 };                          \
            OUT = __builtin_bit_cast(u16x8, wds); }
        PACK(st0, 0, pb4[0]); PACK(st0, 1, pb4[1]);
        PACK(st1, 0, pb4[2]); PACK(st1, 1, pb4[3]);
        #undef PACK

        // O^T += V^T . P^T  (A rows = dv, k = s)
        __builtin_amdgcn_s_setprio(1);
        #pragma unroll
        for (int kc = 0; kc < 4; kc++) {
            const int co = (kc * 16 + hi * 8) * 2;
            u16x8 v0 = *(const u16x8*)(Vsb + ((l31 * 128 + co) ^ ax));
            u16x8 v1 = *(const u16x8*)(Vsb + (((32 + l31) * 128 + co) ^ ax));
            ot0 = mfma32(v0, pb4[kc], ot0);
            ot1 = mfma32(v1, pb4[kc], ot1);
        }
        __builtin_amdgcn_s_setprio(0);
    };

    STAGE(&Ks0[0][0], &Vs0[0][0], 0);
    STAGE(&Ks1[0][0], &Vs1[0][0], 1);         // 4 outstanding / lane

    const int np = nt >> 1;                   // nt is even (4g+4)
    for (int j = 0; j < np; j++) {
        const int i0 = 2 * j, i1 = 2 * j + 1;
        WAIT_BAR(2);
        if (i0 <= i_d) COMPUTE((const char*)Ks0, (const char*)Vs0, i0);
        BAR_ONLY();
        if (i0 + 2 < nt) STAGE(&Ks0[0][0], &Vs0[0][0], i0 + 2);
        if (j < np - 1) { WAIT_BAR(2); } else { WAIT_BAR(0); }
        if (i1 <= i_d) COMPUTE((const char*)Ks1, (const char*)Vs1, i1);
        BAR_ONLY();
        if (i1 + 2 < nt) STAGE(&Ks1[0][0], &Vs1[0][0], i1 + 2);
    }

    // output: O^T reg r -> dv = td*32 + 16c + 8hf + 4hi + j, q = qrow
    const float inv = 1.0f / li;
    float* orow = out + (size_t)(b * T_ + qrow) * DMO + h * D_;
    #pragma unroll
    for (int c = 0; c < 2; c++)
        #pragma unroll
        for (int hf = 0; hf < 2; hf++) {
            f32x4 v0, v1;
            #pragma unroll
            for (int j = 0; j < 4; j++) {
                v0[j] = ot0[c * 8 + hf * 4 + j] * inv;
                v1[j] = ot1[c * 8 + hf * 4 + j] * inv;
            }
            *(f32x4*)(orow + c * 16 + hf * 8 + hi * 4)      = v0;
            *(f32x4*)(orow + 32 + c * 16 + hf * 8 + hi * 4) = v1;
        }
}

// ---------------------------------------------------------------------------
extern "C" void kernel_launch(void* const* d_in, const int* in_sizes, int n_in,
                              void* d_out, int out_size, void* d_ws, size_t ws_size,
                              hipStream_t stream) {
    int xi = 0, wi[3] = {1, 2, 3};
    {
        int k = 0, found = 0;
        for (int i = 0; i < n_in && i < 8; i++) {
            if (in_sizes[i] == B_ * T_ * DM_) { xi = i; found = 1; }
            else if (in_sizes[i] == H_ * DM_ * D_ && k < 3) wi[k++] = i;
        }
        if (!found || k != 3) { xi = 0; wi[0] = 1; wi[1] = 2; wi[2] = 3; }
    }
    const float* x  = (const float*)d_in[xi];
    const float* Wq = (const float*)d_in[wi[0]];
    const float* Wk = (const float*)d_in[wi[1]];
    const float* Wv = (const float*)d_in[wi[2]];
    float* out = (float*)d_out;

    // bf16 staging scratch lives in d_out (dead before attn writes it):
    //   xb = 8.4M u16 (16.8 MB), Wt = 3.1M u16 (6.3 MB) -> 23.1 of 33.5 MB.
    u16* xb = (u16*)d_out;
    u16* Wt = xb + (size_t)B_ * T_ * DM_;
    // ws: Q + K + Vt bf16 = 50.3 MB (R8-verified to fit).
    const size_t per = (size_t)B_ * H_ * T_ * D_;
    u16* Qc  = (u16*)d_ws;
    u16* Kc  = Qc + per;
    u16* Vtc = Kc + per;

    cvt_all<<<1792, 256, 0, stream>>>(x, Wq, Wk, Wv, xb, Wt);
    proj_kernel<<<1536, 256, 0, stream>>>(xb, Wt, Qc, Kc, Vtc);
    attn_kernel<<<512, 512, 0, stream>>>(Qc, Kc, Vtc, out);
}

// Round 8
// 213.897 us; speedup vs baseline: 1.3991x; 1.0120x over previous
//
#include <hip/hip_runtime.h>

// MHA forward.  B=4 T=2048 DM=1024 H=16 DK=DV=64.  f32 in / f32 out.
// R18: attn balance + softmax VALU diet.
//   (1) complementary CU pairing: blocks dispatch round-robin over XCDs so
//       CU c runs {pb=c, pb=c+256}.  g = pb<256 ? 7-(pb>>6) : (pb-256)>>6
//       makes the pair (g, 7-g) with the SAME bh -> every CU gets exactly
//       36 tile-phases and both blocks share K/V in L2.  (R17 pairing left
//       half the kernel at 8/16 waves resident -> Occupancy 28.5%.)
//   (2) softmax VALU trims: v_cvt_pk_bf16_f32 asm for P-pack (1 op/dword
//       vs 3, T12), v_max3_f32-fused max tree (T17), float2 packed
//       sub/exp-accum (v_pk_add_f32).  ~-80 VALU/tile of ~600.
//   proj (R17 XCD m-slice) and cvt unchanged.

#define B_  4
#define T_  2048
#define DM_ 1024
#define H_  16
#define D_  64
#define DMO 1024   // out row stride = H_*D_

typedef unsigned short u16;
typedef unsigned int   u32;
typedef u16   u16x8  __attribute__((ext_vector_type(8)));
typedef short s16x8  __attribute__((ext_vector_type(8)));
typedef float f32x2  __attribute__((ext_vector_type(2)));
typedef float f32x4  __attribute__((ext_vector_type(4)));
typedef float f32x16 __attribute__((ext_vector_type(16)));
typedef u32   u32x2  __attribute__((ext_vector_type(2)));
typedef u32   u32x4  __attribute__((ext_vector_type(4)));

#if __has_builtin(__builtin_amdgcn_exp2f)
#define EXP2(x) __builtin_amdgcn_exp2f(x)
#else
#define EXP2(x) __expf((x) * 0.69314718f)
#endif

// counted-vmcnt barrier: wait own loads down to N, then sync, then pin.
#define WAIT_BAR(N) do {                                                      \
    asm volatile("s_waitcnt vmcnt(" #N ")" ::: "memory");                     \
    __builtin_amdgcn_s_barrier();                                             \
    __builtin_amdgcn_sched_barrier(0); } while (0)
#define BAR_ONLY() do {                                                       \
    __builtin_amdgcn_s_barrier();                                             \
    __builtin_amdgcn_sched_barrier(0); } while (0)

__device__ __forceinline__ u16 f2bf_hu(float f) {   // round-half-up (ties rare)
    u32 u = __builtin_bit_cast(u32, f) + 0x8000u;
    return (u16)(u >> 16);
}
// pack two f32 -> dword of two bf16 (lo,hi), 3 VALU ops
__device__ __forceinline__ u32 pk2(float lo, float hi) {
    u32 ul = __builtin_bit_cast(u32, lo) + 0x8000u;
    u32 uh = __builtin_bit_cast(u32, hi) + 0x8000u;
    return __builtin_amdgcn_perm(uh, ul, 0x07060302);  // [uh.hi16 : ul.hi16]
}
// 1-op packed f32->bf16 (RNE); lo -> low16, hi -> high16 (same as pk2)
__device__ __forceinline__ u32 cvtpk(float lo, float hi) {
    u32 r;
    asm("v_cvt_pk_bf16_f32 %0, %1, %2" : "=v"(r) : "v"(lo), "v"(hi));
    return r;
}
__device__ __forceinline__ u16x8 cvt8(const float* s) {
    f32x4 a = *(const f32x4*)s;
    f32x4 b = *(const f32x4*)(s + 4);
    u32x4 r { pk2(a[0], a[1]), pk2(a[2], a[3]), pk2(b[0], b[1]), pk2(b[2], b[3]) };
    return __builtin_bit_cast(u16x8, r);
}
__device__ __forceinline__ f32x4 mfma16(u16x8 a, u16x8 b, f32x4 c) {
    return __builtin_amdgcn_mfma_f32_16x16x32_bf16(
        __builtin_bit_cast(s16x8, a), __builtin_bit_cast(s16x8, b), c, 0, 0, 0);
}
__device__ __forceinline__ f32x16 mfma32(u16x8 a, u16x8 b, f32x16 c) {
    return __builtin_amdgcn_mfma_f32_32x32x16_bf16(
        __builtin_bit_cast(s16x8, a), __builtin_bit_cast(s16x8, b), c, 0, 0, 0);
}
// async global->LDS, 16B per lane.  LDS dest must be wave-uniform base + lane*16.
__device__ __forceinline__ void gld_lds16(const u16* g, u16* l) {
    __builtin_amdgcn_global_load_lds(
        (const __attribute__((address_space(1))) u32*)g,
        (__attribute__((address_space(3))) u32*)l, 16, 0, 0);
}

// ---------------------------------------------------------------------------
// cvt_all: blocks [0,1024): x f32 [8192][1024] -> xb bf16 (same layout).
//          blocks [1024,1792): W[mat][h][1024][64] f32 -> Wt bf16 transposed.
// ---------------------------------------------------------------------------
__global__ __launch_bounds__(256) void cvt_all(
    const float* __restrict__ x,  const float* __restrict__ Wq,
    const float* __restrict__ Wk, const float* __restrict__ Wv,
    u16* __restrict__ xb, u16* __restrict__ Wt)
{
    __shared__ u16 L[64][74];
    const int bx = blockIdx.x;
    if (bx < 1024) {
        size_t i0 = ((size_t)bx * 256 + threadIdx.x) * 32;
        #pragma unroll
        for (int c = 0; c < 4; c++)
            *(u16x8*)(xb + i0 + c * 8) = cvt8(x + i0 + c * 8);
        return;
    }
    const int wb = bx - 1024;
    const int dblk = wb & 15, h = (wb >> 4) & 15, mat = wb >> 8;
    const float* W = (mat == 0) ? Wq : (mat == 1) ? Wk : Wv;
    const int tid = threadIdx.x;
    {   // load 64(d) x 64(dk), coalesced, convert
        const int dl = tid >> 2, c = (tid & 3) * 16;
        const float* src = W + ((size_t)h * DM_ + dblk * 64 + dl) * D_ + c;
        #pragma unroll
        for (int g = 0; g < 2; g++)
            *(u16x8*)&L[dl][c + g * 8] = cvt8(src + g * 8);
    }
    __syncthreads();
    {   // write rows of Wt: row = dk, 16 d's per thread
        const int dkr = tid >> 2, g = tid & 3;
        u16 tmp[16];
        #pragma unroll
        for (int j = 0; j < 16; j++) tmp[j] = L[g * 16 + j][dkr];
        u16* dst = Wt + ((size_t)(mat * 16 + h) * 64 + dkr) * DM_ + dblk * 64 + g * 16;
        *(u16x8*)dst = *(u16x8*)tmp;
        *(u16x8*)(dst + 8) = *(u16x8*)(tmp + 8);
    }
}

// ---------------------------------------------------------------------------
// Projection GEMM: C[8192][3072] = xb @ Wt^T (Wt rows are C-columns).
// 1536 blocks, 256 thr = 4 waves 2x2, 128x128 tile, BK=64.
// XCD m-slice mapping: XCD x owns m-tiles [8x,8x+8) x all 24 n, m-fastest.
// Counted-vmcnt pipeline: 8 gld_lds per STAGE per wave; vmcnt(8) steady.
// ---------------------------------------------------------------------------
template<int SWAP>
__device__ __forceinline__ void pcompute(const char* Asb, const char* Bsb,
                                         int wm, int wn, int quad, int l16,
                                         int ax, f32x4 (&acc)[4][4]) {
    #pragma unroll
    for (int ks = 0; ks < 2; ks++) {
        u16x8 af[4], bf[4];
        #pragma unroll
        for (int i = 0; i < 4; i++)
            af[i] = *(const u16x8*)(Asb +
                ((((wm * 64 + i * 16 + l16) * 64 + ks * 32 + quad * 8) * 2) ^ ax));
        #pragma unroll
        for (int j = 0; j < 4; j++)
            bf[j] = *(const u16x8*)(Bsb +
                ((((wn * 64 + j * 16 + l16) * 64 + ks * 32 + quad * 8) * 2) ^ ax));
        __builtin_amdgcn_s_setprio(1);
        #pragma unroll
        for (int i = 0; i < 4; i++)
            #pragma unroll
            for (int j = 0; j < 4; j++)
                acc[i][j] = SWAP ? mfma16(bf[j], af[i], acc[i][j])
                                 : mfma16(af[i], bf[j], acc[i][j]);
        __builtin_amdgcn_s_setprio(0);
    }
}

__global__ __launch_bounds__(256) void proj_kernel(
    const u16* __restrict__ xb, const u16* __restrict__ Wt,
    u16* __restrict__ Qc, u16* __restrict__ Kc, u16* __restrict__ Vtc)
{
    __shared__ __attribute__((aligned(16))) u16 As0[128][64];
    __shared__ __attribute__((aligned(16))) u16 Bs0[128][64];
    __shared__ __attribute__((aligned(16))) u16 As1[128][64];
    __shared__ __attribute__((aligned(16))) u16 Bs1[128][64];

    // XCD m-slice supertiling: pb = xcd + 8*mid + 64*ntile (bijective).
    const int pb = blockIdx.x;
    const int mt = (pb & 7) * 8 + ((pb >> 3) & 7);   // m-tile 0..63
    const int nti = pb >> 6;                         // n-tile 0..23
    const int m0 = mt * 128;
    const int n0 = nti * 128;                 // n = mat*1024 + h*64 + dk
    const int mat = n0 >> 10;
    const int tid  = threadIdx.x;
    const int wave = tid >> 6, lane = tid & 63;
    const int quad = lane >> 4, l16 = lane & 15;
    const int wm   = wave >> 1, wn = wave & 1;

    const int r8 = lane >> 3, g8 = lane & 7;
    const int gs = (g8 ^ r8) * 8;             // pre-swizzled source col (u16)
    const int ax = (l16 & 7) << 4;            // read-side byte XOR

    f32x4 acc[4][4];
    #pragma unroll
    for (int i = 0; i < 4; i++)
        #pragma unroll
        for (int j = 0; j < 4; j++) acc[i][j] = f32x4{0.f, 0.f, 0.f, 0.f};

    auto STAGE = [&](u16* Ad, u16* Bd, int kb) {
        const int kbase = kb * 64;
        #pragma unroll
        for (int it = 0; it < 4; it++) {
            const int row = it * 32 + wave * 8 + r8;
            const int ldo = (it * 4 + wave) * 512 + lane * 8;   // u16 units
            gld_lds16(xb + (size_t)(m0 + row) * DM_ + kbase + gs, Ad + ldo);
            gld_lds16(Wt + (size_t)(n0 + row) * DM_ + kbase + gs, Bd + ldo);
        }
    };

    STAGE(&As0[0][0], &Bs0[0][0], 0);
    STAGE(&As1[0][0], &Bs1[0][0], 1);        // 16 outstanding / wave

    #define PLOOP(SW)                                                        \
        for (int j = 0; j < 8; j++) {                                        \
            WAIT_BAR(8);                                                     \
            pcompute<SW>((const char*)As0, (const char*)Bs0,                 \
                         wm, wn, quad, l16, ax, acc);                        \
            BAR_ONLY();                                                      \
            if (2 * j + 2 < 16) STAGE(&As0[0][0], &Bs0[0][0], 2 * j + 2);    \
            if (j < 7) { WAIT_BAR(8); } else { WAIT_BAR(0); }                \
            pcompute<SW>((const char*)As1, (const char*)Bs1,                 \
                         wm, wn, quad, l16, ax, acc);                        \
            BAR_ONLY();                                                      \
            if (2 * j + 3 < 16) STAGE(&As1[0][0], &Bs1[0][0], 2 * j + 3);    \
        }
    if (mat != 2) { PLOOP(1) } else { PLOOP(0) }
    #undef PLOOP

    const int h_base = (n0 & 1023) >> 6;
    if (mat != 2) {
        // SWAPPED: r walks dk.
        u16* Cm = (mat == 0) ? Qc : Kc;
        const float sc = (mat == 0) ? 0.18033688f : 1.0f;  // Q: dk^-.5*log2e
        #pragma unroll
        for (int i = 0; i < 4; i++) {
            const int m  = m0 + wm * 64 + i * 16 + l16;
            const int bb = m >> 11, t = m & (T_ - 1);
            u16* rowp = Cm + ((size_t)(bb * H_ + h_base + wn) * T_ + t) * D_;
            #pragma unroll
            for (int j = 0; j < 4; j++) {
                const int dk0 = j * 16 + quad * 4;
                u32x2 d { pk2(acc[i][j][0] * sc, acc[i][j][1] * sc),
                          pk2(acc[i][j][2] * sc, acc[i][j][3] * sc) };
                *(u32x2*)(rowp + dk0) = d;
            }
        }
    } else {
        // NORMAL: r walks t.
        #pragma unroll
        for (int i = 0; i < 4; i++) {
            const int m  = m0 + wm * 64 + i * 16 + quad * 4;   // r = 0 base
            const int bb = m >> 11, t = m & (T_ - 1);
            #pragma unroll
            for (int j = 0; j < 4; j++) {
                const int dk = j * 16 + l16;
                u32x2 d { pk2(acc[i][j][0], acc[i][j][1]),
                          pk2(acc[i][j][2], acc[i][j][3]) };
                *(u32x2*)(Vtc + ((size_t)(bb * H_ + h_base + wn) * D_ + dk) * T_ + t) = d;
            }
        }
    }
}

// ---------------------------------------------------------------------------
// Flash attention, swapped-operand (S^T = K.Q^T via 32x32x16 MFMA).
// 8-wave blocks: 512 thr own 256 consecutive q-rows.  K/V tile staged once
// per block.  512 blocks; CU c runs {c, c+256} which are the SAME bh with
// complementary g (g, 7-g) -> exactly 36 tile-phases per CU, shared K/V L2.
// Counted-vmcnt double buffer; zero-const MFMA C-init; cvt_pk/max3/pk-f32
// softmax.
// ---------------------------------------------------------------------------
__global__ __launch_bounds__(512, 2) void attn_kernel(
    const u16* __restrict__ Qc, const u16* __restrict__ Kc,
    const u16* __restrict__ Vtc, float* __restrict__ out)
{
    __shared__ __attribute__((aligned(16))) u16 Ks0[64][64];  // swz [s][k]
    __shared__ __attribute__((aligned(16))) u16 Vs0[64][64];  // swz [dv][s]
    __shared__ __attribute__((aligned(16))) u16 Ks1[64][64];
    __shared__ __attribute__((aligned(16))) u16 Vs1[64][64];

    const int pb  = blockIdx.x;
    const int bh  = (pb & 7) * 8 + ((pb >> 3) & 7);  // 8 bh-sets per XCD (L2)
    // complementary pairing: pb and pb+256 share bh; g + g' = 7.
    const int g   = (pb < 256) ? (7 - (pb >> 6)) : ((pb - 256) >> 6);
    const int h   = bh & 15, b = bh >> 4;

    const int tid = threadIdx.x, w = tid >> 6, lane = tid & 63;
    const int l31 = lane & 31, hi = lane >> 5;
    const int r8 = (tid >> 3) & 7, g8 = tid & 7;
    const int gs = (g8 ^ r8) * 8;             // pre-swizzled source col (u16)
    const int ax = (l31 & 7) << 4;            // read-side byte XOR

    const int qrow = g * 256 + w * 32 + l31;  // this lane's q (S^T column)
    const int i_d  = g * 4 + (w >> 1);        // wave's diagonal s-tile
    const int nt   = g * 4 + 4;               // s-tiles this block stages
    const int qmask = 32 * (w & 1) + l31;     // q within the diagonal tile

    const u16* Qbh = Qc + (size_t)(b * H_ + h) * T_ * D_;
    const u16* Kbh = Kc + (size_t)(b * H_ + h) * T_ * D_;
    const u16* Vbh = Vtc + (size_t)(b * H_ + h) * D_ * T_;

    auto STAGE = [&](u16* Kd, u16* Vd, int t) {
        const int sbase = t * 64;
        const int row = tid >> 3;             // 512 thr cover 64 rows x 8 gran
        const int ldo = tid * 8;              // u16 units (lane*16B, wave-lin)
        gld_lds16(Kbh + (size_t)(sbase + row) * D_ + gs, Kd + ldo);
        gld_lds16(Vbh + (size_t)row * T_ + sbase + gs,  Vd + ldo);
    };

    // Q B-frags (col=lane&31=q, k = hi*8+e per 16-chunk), scaled at proj.
    u16x8 qf[4];
    #pragma unroll
    for (int ks = 0; ks < 4; ks++)
        qf[ks] = *(const u16x8*)(Qbh + (size_t)qrow * D_ + ks * 16 + hi * 8);

    // loop-invariant zero accumulator (hoisted out of the tile loop)
    f32x16 zz;
    #pragma unroll
    for (int r = 0; r < 16; r++) zz[r] = 0.f;

    f32x16 ot0, ot1;                          // O^T accum: dv 0..31 / 32..63
    #pragma unroll
    for (int r = 0; r < 16; r++) { ot0[r] = 0.f; ot1[r] = 0.f; }
    float mi = -1e30f, li = 0.f;

    auto COMPUTE = [&](const char* Ksb, const char* Vsb, int i) {
        // S^T = K . Q^T   (two 32-s tiles, log2 domain); ks=0 inits from zz
        f32x16 st0, st1;
        __builtin_amdgcn_s_setprio(1);
        {
            const int co = (hi * 8) * 2;                        // ks = 0
            u16x8 k0 = *(const u16x8*)(Ksb + ((l31 * 128 + co) ^ ax));
            u16x8 k1 = *(const u16x8*)(Ksb + (((32 + l31) * 128 + co) ^ ax));
            st0 = mfma32(k0, qf[0], zz);
            st1 = mfma32(k1, qf[0], zz);
        }
        #pragma unroll
        for (int ks = 1; ks < 4; ks++) {
            const int co = (ks * 16 + hi * 8) * 2;              // byte col
            u16x8 k0 = *(const u16x8*)(Ksb + ((l31 * 128 + co) ^ ax));
            u16x8 k1 = *(const u16x8*)(Ksb + (((32 + l31) * 128 + co) ^ ax));
            st0 = mfma32(k0, qf[ks], st0);
            st1 = mfma32(k1, qf[ks], st1);
        }
        __builtin_amdgcn_s_setprio(0);

        // causal mask — only the wave's diagonal s-tile is partial
        if (i == i_d) {
            #pragma unroll
            for (int r = 0; r < 16; r++) {
                const int sl = (r & 3) + 8 * (r >> 2) + 4 * hi;
                if (sl > qmask)      st0[r] = -1e30f;
                if (sl + 32 > qmask) st1[r] = -1e30f;
            }
        }

        // max: v_max3-fused tree (fmaxf(fmaxf(m,a),b) -> v_max3_f32)
        float mx = fmaxf(st0[0], st0[1]);
        #pragma unroll
        for (int r = 2; r < 16; r += 2) mx = fmaxf(fmaxf(mx, st0[r]), st0[r + 1]);
        #pragma unroll
        for (int r = 0; r < 16; r += 2) mx = fmaxf(fmaxf(mx, st1[r]), st1[r + 1]);
        mx = fmaxf(mx, __shfl_xor(mx, 32));
        if (!__all(mx - mi <= 8.f)) {         // defer-max (T13, THR=8)
            const float mn = fmaxf(mi, mx);
            const float al = EXP2(mi - mn);
            li *= al;
            #pragma unroll
            for (int r = 0; r < 16; r++) { ot0[r] *= al; ot1[r] *= al; }
            mi = mn;
        }

        // packed sub + exp + packed accumulate (v_pk_add_f32)
        f32x2 mm; mm[0] = mi; mm[1] = mi;
        f32x2 sac; sac[0] = 0.f; sac[1] = 0.f;
        #pragma unroll
        for (int k = 0; k < 8; k++) {
            f32x2 a; a[0] = st0[2 * k]; a[1] = st0[2 * k + 1];
            f32x2 c; c[0] = st1[2 * k]; c[1] = st1[2 * k + 1];
            a = a - mm; c = c - mm;
            a[0] = EXP2(a[0]); a[1] = EXP2(a[1]);
            c[0] = EXP2(c[0]); c[1] = EXP2(c[1]);
            st0[2 * k] = a[0]; st0[2 * k + 1] = a[1];
            st1[2 * k] = c[0]; st1[2 * k + 1] = c[1];
            sac = sac + a; sac = sac + c;
        }
        float sum = sac[0] + sac[1];
        sum += __shfl_xor(sum, 32);
        li += sum;

        // P^T -> PV B-frags: cvt_pk pairs + swap dwords across hi halves
        u16x8 pb4[4];
        #define PACK(SRC, C, OUT) {                                           \
            u32 d0 = cvtpk(SRC[8*(C)+0], SRC[8*(C)+1]);                       \
            u32 d1 = cvtpk(SRC[8*(C)+2], SRC[8*(C)+3]);                       \
            u32 d2 = cvtpk(SRC[8*(C)+4], SRC[8*(C)+5]);                       \
            u32 d3 = cvtpk(SRC[8*(C)+6], SRC[8*(C)+7]);                       \
            u32 e0 = __shfl_xor(hi ? d0 : d2, 32);                            \
            u32 e1 = __shfl_xor(hi ? d1 : d3, 32);                            \
            u32x4 wds{ hi ? e0 : d0, hi ? e1 : d1,                            \
                       hi ? d2 : e0, hi ? d3 : e1 };                          \
            OUT = __builtin_bit_cast(u16x8, wds); }
        PACK(st0, 0, pb4[0]); PACK(st0, 1, pb4[1]);
        PACK(st1, 0, pb4[2]); PACK(st1, 1, pb4[3]);
        #undef PACK

        // O^T += V^T . P^T  (A rows = dv, k = s)
        __builtin_amdgcn_s_setprio(1);
        #pragma unroll
        for (int kc = 0; kc < 4; kc++) {
            const int co = (kc * 16 + hi * 8) * 2;
            u16x8 v0 = *(const u16x8*)(Vsb + ((l31 * 128 + co) ^ ax));
            u16x8 v1 = *(const u16x8*)(Vsb + (((32 + l31) * 128 + co) ^ ax));
            ot0 = mfma32(v0, pb4[kc], ot0);
            ot1 = mfma32(v1, pb4[kc], ot1);
        }
        __builtin_amdgcn_s_setprio(0);
    };

    STAGE(&Ks0[0][0], &Vs0[0][0], 0);
    STAGE(&Ks1[0][0], &Vs1[0][0], 1);         // 4 outstanding / lane

    const int np = nt >> 1;                   // nt is even (4g+4)
    for (int j = 0; j < np; j++) {
        const int i0 = 2 * j, i1 = 2 * j + 1;
        WAIT_BAR(2);
        if (i0 <= i_d) COMPUTE((const char*)Ks0, (const char*)Vs0, i0);
        BAR_ONLY();
        if (i0 + 2 < nt) STAGE(&Ks0[0][0], &Vs0[0][0], i0 + 2);
        if (j < np - 1) { WAIT_BAR(2); } else { WAIT_BAR(0); }
        if (i1 <= i_d) COMPUTE((const char*)Ks1, (const char*)Vs1, i1);
        BAR_ONLY();
        if (i1 + 2 < nt) STAGE(&Ks1[0][0], &Vs1[0][0], i1 + 2);
    }

    // output: O^T reg r -> dv = td*32 + 16c + 8hf + 4hi + j, q = qrow
    const float inv = 1.0f / li;
    float* orow = out + (size_t)(b * T_ + qrow) * DMO + h * D_;
    #pragma unroll
    for (int c = 0; c < 2; c++)
        #pragma unroll
        for (int hf = 0; hf < 2; hf++) {
            f32x4 v0, v1;
            #pragma unroll
            for (int j = 0; j < 4; j++) {
                v0[j] = ot0[c * 8 + hf * 4 + j] * inv;
                v1[j] = ot1[c * 8 + hf * 4 + j] * inv;
            }
            *(f32x4*)(orow + c * 16 + hf * 8 + hi * 4)      = v0;
            *(f32x4*)(orow + 32 + c * 16 + hf * 8 + hi * 4) = v1;
        }
}

// ---------------------------------------------------------------------------
extern "C" void kernel_launch(void* const* d_in, const int* in_sizes, int n_in,
                              void* d_out, int out_size, void* d_ws, size_t ws_size,
                              hipStream_t stream) {
    int xi = 0, wi[3] = {1, 2, 3};
    {
        int k = 0, found = 0;
        for (int i = 0; i < n_in && i < 8; i++) {
            if (in_sizes[i] == B_ * T_ * DM_) { xi = i; found = 1; }
            else if (in_sizes[i] == H_ * DM_ * D_ && k < 3) wi[k++] = i;
        }
        if (!found || k != 3) { xi = 0; wi[0] = 1; wi[1] = 2; wi[2] = 3; }
    }
    const float* x  = (const float*)d_in[xi];
    const float* Wq = (const float*)d_in[wi[0]];
    const float* Wk = (const float*)d_in[wi[1]];
    const float* Wv = (const float*)d_in[wi[2]];
    float* out = (float*)d_out;

    // bf16 staging scratch lives in d_out (dead before attn writes it):
    //   xb = 8.4M u16 (16.8 MB), Wt = 3.1M u16 (6.3 MB) -> 23.1 of 33.5 MB.
    u16* xb = (u16*)d_out;
    u16* Wt = xb + (size_t)B_ * T_ * DM_;
    // ws: Q + K + Vt bf16 = 50.3 MB (R8-verified to fit).
    const size_t per = (size_t)B_ * H_ * T_ * D_;
    u16* Qc  = (u16*)d_ws;
    u16* Kc  = Qc + per;
    u16* Vtc = Kc + per;

    cvt_all<<<1792, 256, 0, stream>>>(x, Wq, Wk, Wv, xb, Wt);
    proj_kernel<<<1536, 256, 0, stream>>>(xb, Wt, Qc, Kc, Vtc);
    attn_kernel<<<512, 512, 0, stream>>>(Qc, Kc, Vtc, out);
}

// Round 12
// 212.342 us; speedup vs baseline: 1.4093x; 1.0073x over previous
//
#include <hip/hip_runtime.h>

// MHA forward.  B=4 T=2048 DM=1024 H=16 DK=DV=64.  f32 in / f32 out.
// R22: bank the verified wins; revert the unverified permlane exchange.
//   R21 post-mortem: inf -> 3.36 localized the bug to PACK's permlane —
//   v_permlane32_swap_b32 swaps vdst-high <-> vsrc-low (opposite of the
//   assumed direction), so swap(d2,d0) gave each lane the OTHER half's
//   fragment words.  Rather than a third guess at the semantics, PACK's
//   exchange reverts to the R18-VERIFIED shfl_xor+select form (R18 passed
//   at 213.9 us with cvtpk + this exact exchange).
//   Kept (all verified or provably bijective):
//   (1) cvt_x lane-contiguous coalescing (the arc's target: removes the
//       hidden ~25-40 us in cvt_all from 128 B/lane strided access).
//   (2) R18 attn: complementary CU pairing, zero-init hoist via zz,
//       max3-fused tree, packed exp, cvtpk, counted-vmcnt dbuf.
//   (3) proj R17 XCD m-slice + counted vmcnt.

#define B_  4
#define T_  2048
#define DM_ 1024
#define H_  16
#define D_  64
#define DMO 1024   // out row stride = H_*D_

typedef unsigned short u16;
typedef unsigned int   u32;
typedef u16   u16x8  __attribute__((ext_vector_type(8)));
typedef short s16x8  __attribute__((ext_vector_type(8)));
typedef float f32x2  __attribute__((ext_vector_type(2)));
typedef float f32x4  __attribute__((ext_vector_type(4)));
typedef float f32x16 __attribute__((ext_vector_type(16)));
typedef u32   u32x2  __attribute__((ext_vector_type(2)));
typedef u32   u32x4  __attribute__((ext_vector_type(4)));

#if __has_builtin(__builtin_amdgcn_exp2f)
#define EXP2(x) __builtin_amdgcn_exp2f(x)
#else
#define EXP2(x) __expf((x) * 0.69314718f)
#endif

// counted-vmcnt barrier: wait own loads down to N, then sync, then pin.
#define WAIT_BAR(N) do {                                                      \
    asm volatile("s_waitcnt vmcnt(" #N ")" ::: "memory");                     \
    __builtin_amdgcn_s_barrier();                                             \
    __builtin_amdgcn_sched_barrier(0); } while (0)
#define BAR_ONLY() do {                                                       \
    __builtin_amdgcn_s_barrier();                                             \
    __builtin_amdgcn_sched_barrier(0); } while (0)

__device__ __forceinline__ u16 f2bf_hu(float f) {   // round-half-up (ties rare)
    u32 u = __builtin_bit_cast(u32, f) + 0x8000u;
    return (u16)(u >> 16);
}
// pack two f32 -> dword of two bf16 (lo,hi), 3 VALU ops
__device__ __forceinline__ u32 pk2(float lo, float hi) {
    u32 ul = __builtin_bit_cast(u32, lo) + 0x8000u;
    u32 uh = __builtin_bit_cast(u32, hi) + 0x8000u;
    return __builtin_amdgcn_perm(uh, ul, 0x07060302);  // [uh.hi16 : ul.hi16]
}
// 1-op packed f32->bf16 (RNE); lo -> low16, hi -> high16 (R18-verified)
__device__ __forceinline__ u32 cvtpk(float lo, float hi) {
    u32 r;
    asm("v_cvt_pk_bf16_f32 %0, %1, %2" : "=v"(r) : "v"(lo), "v"(hi));
    return r;
}
__device__ __forceinline__ u16x8 cvt8(const float* s) {
    f32x4 a = *(const f32x4*)s;
    f32x4 b = *(const f32x4*)(s + 4);
    u32x4 r { pk2(a[0], a[1]), pk2(a[2], a[3]), pk2(b[0], b[1]), pk2(b[2], b[3]) };
    return __builtin_bit_cast(u16x8, r);
}
__device__ __forceinline__ f32x4 mfma16(u16x8 a, u16x8 b, f32x4 c) {
    return __builtin_amdgcn_mfma_f32_16x16x32_bf16(
        __builtin_bit_cast(s16x8, a), __builtin_bit_cast(s16x8, b), c, 0, 0, 0);
}
__device__ __forceinline__ f32x16 mfma32(u16x8 a, u16x8 b, f32x16 c) {
    return __builtin_amdgcn_mfma_f32_32x32x16_bf16(
        __builtin_bit_cast(s16x8, a), __builtin_bit_cast(s16x8, b), c, 0, 0, 0);
}
// async global->LDS, 16B per lane.  LDS dest must be wave-uniform base + lane*16.
__device__ __forceinline__ void gld_lds16(const u16* g, u16* l) {
    __builtin_amdgcn_global_load_lds(
        (const __attribute__((address_space(1))) u32*)g,
        (__attribute__((address_space(3))) u32*)l, 16, 0, 0);
}

// ---------------------------------------------------------------------------
// cvt_all: blocks [0,1024): x f32 [8192][1024] -> xb bf16, lane-contiguous.
//          blocks [1024,1792): W[mat][h][1024][64] f32 -> Wt bf16 transposed.
// ---------------------------------------------------------------------------
__global__ __launch_bounds__(256) void cvt_all(
    const float* __restrict__ x,  const float* __restrict__ Wq,
    const float* __restrict__ Wk, const float* __restrict__ Wv,
    u16* __restrict__ xb, u16* __restrict__ Wt)
{
    __shared__ u16 L[64][74];
    const int bx = blockIdx.x;
    if (bx < 1024) {
        const size_t base = (size_t)bx * 8192;
        #pragma unroll
        for (int c = 0; c < 4; c++) {
            const size_t o = base + c * 2048 + threadIdx.x * 8;
            *(u16x8*)(xb + o) = cvt8(x + o);
        }
        return;
    }
    const int wb = bx - 1024;
    const int dblk = wb & 15, h = (wb >> 4) & 15, mat = wb >> 8;
    const float* W = (mat == 0) ? Wq : (mat == 1) ? Wk : Wv;
    const int tid = threadIdx.x;
    {   // load 64(d) x 64(dk), coalesced, convert
        const int dl = tid >> 2, c = (tid & 3) * 16;
        const float* src = W + ((size_t)h * DM_ + dblk * 64 + dl) * D_ + c;
        #pragma unroll
        for (int g = 0; g < 2; g++)
            *(u16x8*)&L[dl][c + g * 8] = cvt8(src + g * 8);
    }
    __syncthreads();
    {   // write rows of Wt: row = dk, 16 d's per thread
        const int dkr = tid >> 2, g = tid & 3;
        u16 tmp[16];
        #pragma unroll
        for (int j = 0; j < 16; j++) tmp[j] = L[g * 16 + j][dkr];
        u16* dst = Wt + ((size_t)(mat * 16 + h) * 64 + dkr) * DM_ + dblk * 64 + g * 16;
        *(u16x8*)dst = *(u16x8*)tmp;
        *(u16x8*)(dst + 8) = *(u16x8*)(tmp + 8);
    }
}

// ---------------------------------------------------------------------------
// Projection GEMM: C[8192][3072] = xb @ Wt^T (Wt rows are C-columns).
// 1536 blocks, 256 thr = 4 waves 2x2, 128x128 tile, BK=64.
// XCD m-slice mapping: XCD x owns m-tiles [8x,8x+8) x all 24 n, m-fastest.
// Counted-vmcnt pipeline: 8 gld_lds per STAGE per wave; vmcnt(8) steady.
// ---------------------------------------------------------------------------
template<int SWAP>
__device__ __forceinline__ void pcompute(const char* Asb, const char* Bsb,
                                         int wm, int wn, int quad, int l16,
                                         int ax, f32x4 (&acc)[4][4]) {
    #pragma unroll
    for (int ks = 0; ks < 2; ks++) {
        u16x8 af[4], bf[4];
        #pragma unroll
        for (int i = 0; i < 4; i++)
            af[i] = *(const u16x8*)(Asb +
                ((((wm * 64 + i * 16 + l16) * 64 + ks * 32 + quad * 8) * 2) ^ ax));
        #pragma unroll
        for (int j = 0; j < 4; j++)
            bf[j] = *(const u16x8*)(Bsb +
                ((((wn * 64 + j * 16 + l16) * 64 + ks * 32 + quad * 8) * 2) ^ ax));
        __builtin_amdgcn_s_setprio(1);
        #pragma unroll
        for (int i = 0; i < 4; i++)
            #pragma unroll
            for (int j = 0; j < 4; j++)
                acc[i][j] = SWAP ? mfma16(bf[j], af[i], acc[i][j])
                                 : mfma16(af[i], bf[j], acc[i][j]);
        __builtin_amdgcn_s_setprio(0);
    }
}

__global__ __launch_bounds__(256) void proj_kernel(
    const u16* __restrict__ xb, const u16* __restrict__ Wt,
    u16* __restrict__ Qc, u16* __restrict__ Kc, u16* __restrict__ Vtc)
{
    __shared__ __attribute__((aligned(16))) u16 As0[128][64];
    __shared__ __attribute__((aligned(16))) u16 Bs0[128][64];
    __shared__ __attribute__((aligned(16))) u16 As1[128][64];
    __shared__ __attribute__((aligned(16))) u16 Bs1[128][64];

    // XCD m-slice supertiling: pb = xcd + 8*mid + 64*ntile (bijective).
    const int pb = blockIdx.x;
    const int mt = (pb & 7) * 8 + ((pb >> 3) & 7);   // m-tile 0..63
    const int nti = pb >> 6;                         // n-tile 0..23
    const int m0 = mt * 128;
    const int n0 = nti * 128;                 // n = mat*1024 + h*64 + dk
    const int mat = n0 >> 10;
    const int tid  = threadIdx.x;
    const int wave = tid >> 6, lane = tid & 63;
    const int quad = lane >> 4, l16 = lane & 15;
    const int wm   = wave >> 1, wn = wave & 1;

    const int r8 = lane >> 3, g8 = lane & 7;
    const int gs = (g8 ^ r8) * 8;             // pre-swizzled source col (u16)
    const int ax = (l16 & 7) << 4;            // read-side byte XOR

    f32x4 acc[4][4];
    #pragma unroll
    for (int i = 0; i < 4; i++)
        #pragma unroll
        for (int j = 0; j < 4; j++) acc[i][j] = f32x4{0.f, 0.f, 0.f, 0.f};

    auto STAGE = [&](u16* Ad, u16* Bd, int kb) {
        const int kbase = kb * 64;
        #pragma unroll
        for (int it = 0; it < 4; it++) {
            const int row = it * 32 + wave * 8 + r8;
            const int ldo = (it * 4 + wave) * 512 + lane * 8;   // u16 units
            gld_lds16(xb + (size_t)(m0 + row) * DM_ + kbase + gs, Ad + ldo);
            gld_lds16(Wt + (size_t)(n0 + row) * DM_ + kbase + gs, Bd + ldo);
        }
    };

    STAGE(&As0[0][0], &Bs0[0][0], 0);
    STAGE(&As1[0][0], &Bs1[0][0], 1);        // 16 outstanding / wave

    #define PLOOP(SW)                                                        \
        for (int j = 0; j < 8; j++) {                                        \
            WAIT_BAR(8);                                                     \
            pcompute<SW>((const char*)As0, (const char*)Bs0,                 \
                         wm, wn, quad, l16, ax, acc);                        \
            BAR_ONLY();                                                      \
            if (2 * j + 2 < 16) STAGE(&As0[0][0], &Bs0[0][0], 2 * j + 2);    \
            if (j < 7) { WAIT_BAR(8); } else { WAIT_BAR(0); }                \
            pcompute<SW>((const char*)As1, (const char*)Bs1,                 \
                         wm, wn, quad, l16, ax, acc);                        \
            BAR_ONLY();                                                      \
            if (2 * j + 3 < 16) STAGE(&As1[0][0], &Bs1[0][0], 2 * j + 3);    \
        }
    if (mat != 2) { PLOOP(1) } else { PLOOP(0) }
    #undef PLOOP

    const int h_base = (n0 & 1023) >> 6;
    if (mat != 2) {
        // SWAPPED: r walks dk.
        u16* Cm = (mat == 0) ? Qc : Kc;
        const float sc = (mat == 0) ? 0.18033688f : 1.0f;  // Q: dk^-.5*log2e
        #pragma unroll
        for (int i = 0; i < 4; i++) {
            const int m  = m0 + wm * 64 + i * 16 + l16;
            const int bb = m >> 11, t = m & (T_ - 1);
            u16* rowp = Cm + ((size_t)(bb * H_ + h_base + wn) * T_ + t) * D_;
            #pragma unroll
            for (int j = 0; j < 4; j++) {
                const int dk0 = j * 16 + quad * 4;
                u32x2 d { pk2(acc[i][j][0] * sc, acc[i][j][1] * sc),
                          pk2(acc[i][j][2] * sc, acc[i][j][3] * sc) };
                *(u32x2*)(rowp + dk0) = d;
            }
        }
    } else {
        // NORMAL: r walks t.
        #pragma unroll
        for (int i = 0; i < 4; i++) {
            const int m  = m0 + wm * 64 + i * 16 + quad * 4;   // r = 0 base
            const int bb = m >> 11, t = m & (T_ - 1);
            #pragma unroll
            for (int j = 0; j < 4; j++) {
                const int dk = j * 16 + l16;
                u32x2 d { pk2(acc[i][j][0], acc[i][j][1]),
                          pk2(acc[i][j][2], acc[i][j][3]) };
                *(u32x2*)(Vtc + ((size_t)(bb * H_ + h_base + wn) * D_ + dk) * T_ + t) = d;
            }
        }
    }
}

// ---------------------------------------------------------------------------
// Flash attention, swapped-operand (S^T = K.Q^T via 32x32x16 MFMA).
// 8-wave blocks: 512 thr own 256 consecutive q-rows.  K/V tile staged once
// per block.  512 blocks; CU c runs {c, c+256} = same bh, complementary g.
// Counted-vmcnt double buffer; R18-verified shfl exchange throughout.
// ---------------------------------------------------------------------------
__global__ __launch_bounds__(512, 2) void attn_kernel(
    const u16* __restrict__ Qc, const u16* __restrict__ Kc,
    const u16* __restrict__ Vtc, float* __restrict__ out)
{
    __shared__ __attribute__((aligned(16))) u16 Ks0[64][64];  // swz [s][k]
    __shared__ __attribute__((aligned(16))) u16 Vs0[64][64];  // swz [dv][s]
    __shared__ __attribute__((aligned(16))) u16 Ks1[64][64];
    __shared__ __attribute__((aligned(16))) u16 Vs1[64][64];

    const int pb  = blockIdx.x;
    const int bh  = (pb & 7) * 8 + ((pb >> 3) & 7);  // 8 bh-sets per XCD (L2)
    // complementary pairing: pb and pb+256 share bh; g + g' = 7.
    const int g   = (pb < 256) ? (7 - (pb >> 6)) : ((pb - 256) >> 6);
    const int h   = bh & 15, b = bh >> 4;

    const int tid = threadIdx.x, w = tid >> 6, lane = tid & 63;
    const int l31 = lane & 31, hi = lane >> 5;
    const int r8 = (tid >> 3) & 7, g8 = tid & 7;
    const int gs = (g8 ^ r8) * 8;             // pre-swizzled source col (u16)
    const int ax = (l31 & 7) << 4;            // read-side byte XOR

    const int qrow = g * 256 + w * 32 + l31;  // this lane's q (S^T column)
    const int i_d  = g * 4 + (w >> 1);        // wave's diagonal s-tile
    const int nt   = g * 4 + 4;               // s-tiles this block stages
    const int qmask = 32 * (w & 1) + l31;     // q within the diagonal tile

    const u16* Qbh = Qc + (size_t)(b * H_ + h) * T_ * D_;
    const u16* Kbh = Kc + (size_t)(b * H_ + h) * T_ * D_;
    const u16* Vbh = Vtc + (size_t)(b * H_ + h) * D_ * T_;

    auto STAGE = [&](u16* Kd, u16* Vd, int t) {
        const int sbase = t * 64;
        const int row = tid >> 3;             // 512 thr cover 64 rows x 8 gran
        const int ldo = tid * 8;              // u16 units (lane*16B, wave-lin)
        gld_lds16(Kbh + (size_t)(sbase + row) * D_ + gs, Kd + ldo);
        gld_lds16(Vbh + (size_t)row * T_ + sbase + gs,  Vd + ldo);
    };

    // Q B-frags (col=lane&31=q, k = hi*8+e per 16-chunk), scaled at proj.
    u16x8 qf[4];
    #pragma unroll
    for (int ks = 0; ks < 4; ks++)
        qf[ks] = *(const u16x8*)(Qbh + (size_t)qrow * D_ + ks * 16 + hi * 8);

    // loop-invariant zero accumulator (hoisted out of the tile loop)
    f32x16 zz;
    #pragma unroll
    for (int r = 0; r < 16; r++) zz[r] = 0.f;

    f32x16 ot0, ot1;                          // O^T accum: dv 0..31 / 32..63
    #pragma unroll
    for (int r = 0; r < 16; r++) { ot0[r] = 0.f; ot1[r] = 0.f; }
    float mi = -1e30f, li = 0.f;

    auto COMPUTE = [&](const char* Ksb, const char* Vsb, int i) {
        // S^T = K . Q^T   (two 32-s tiles, log2 domain); ks=0 inits from zz
        f32x16 st0, st1;
        __builtin_amdgcn_s_setprio(1);
        {
            const int co = (hi * 8) * 2;                        // ks = 0
            u16x8 k0 = *(const u16x8*)(Ksb + ((l31 * 128 + co) ^ ax));
            u16x8 k1 = *(const u16x8*)(Ksb + (((32 + l31) * 128 + co) ^ ax));
            st0 = mfma32(k0, qf[0], zz);
            st1 = mfma32(k1, qf[0], zz);
        }
        #pragma unroll
        for (int ks = 1; ks < 4; ks++) {
            const int co = (ks * 16 + hi * 8) * 2;              // byte col
            u16x8 k0 = *(const u16x8*)(Ksb + ((l31 * 128 + co) ^ ax));
            u16x8 k1 = *(const u16x8*)(Ksb + (((32 + l31) * 128 + co) ^ ax));
            st0 = mfma32(k0, qf[ks], st0);
            st1 = mfma32(k1, qf[ks], st1);
        }
        __builtin_amdgcn_s_setprio(0);

        // causal mask — only the wave's diagonal s-tile is partial
        if (i == i_d) {
            #pragma unroll
            for (int r = 0; r < 16; r++) {
                const int sl = (r & 3) + 8 * (r >> 2) + 4 * hi;
                if (sl > qmask)      st0[r] = -1e30f;
                if (sl + 32 > qmask) st1[r] = -1e30f;
            }
        }

        // max: v_max3-fused tree + lane^32 combine via shfl (R18-verified)
        float mx = fmaxf(st0[0], st0[1]);
        #pragma unroll
        for (int r = 2; r < 16; r += 2) mx = fmaxf(fmaxf(mx, st0[r]), st0[r + 1]);
        #pragma unroll
        for (int r = 0; r < 16; r += 2) mx = fmaxf(fmaxf(mx, st1[r]), st1[r + 1]);
        mx = fmaxf(mx, __shfl_xor(mx, 32));
        if (!__all(mx - mi <= 8.f)) {         // defer-max (T13, THR=8)
            const float mn = fmaxf(mi, mx);
            const float al = EXP2(mi - mn);
            li *= al;
            #pragma unroll
            for (int r = 0; r < 16; r++) { ot0[r] *= al; ot1[r] *= al; }
            mi = mn;
        }

        // packed sub + exp + packed accumulate
        f32x2 mm; mm[0] = mi; mm[1] = mi;
        f32x2 sac; sac[0] = 0.f; sac[1] = 0.f;
        #pragma unroll
        for (int k = 0; k < 8; k++) {
            f32x2 a; a[0] = st0[2 * k]; a[1] = st0[2 * k + 1];
            f32x2 c; c[0] = st1[2 * k]; c[1] = st1[2 * k + 1];
            a = a - mm; c = c - mm;
            a[0] = EXP2(a[0]); a[1] = EXP2(a[1]);
            c[0] = EXP2(c[0]); c[1] = EXP2(c[1]);
            st0[2 * k] = a[0]; st0[2 * k + 1] = a[1];
            st1[2 * k] = c[0]; st1[2 * k + 1] = c[1];
            sac = sac + a; sac = sac + c;
        }
        float sum = sac[0] + sac[1];
        sum += __shfl_xor(sum, 32);
        li += sum;

        // P^T -> PV B-frags: cvt_pk pairs + R18-VERIFIED shfl exchange.
        // hi=0 -> {own d0, own d1, partner d0, partner d1};
        // hi=1 -> {partner d2, partner d3, own d2, own d3}.
        u16x8 pb4[4];
        #define PACK(SRC, C, OUT) {                                           \
            u32 d0 = cvtpk(SRC[8*(C)+0], SRC[8*(C)+1]);                       \
            u32 d1 = cvtpk(SRC[8*(C)+2], SRC[8*(C)+3]);                       \
            u32 d2 = cvtpk(SRC[8*(C)+4], SRC[8*(C)+5]);                       \
            u32 d3 = cvtpk(SRC[8*(C)+6], SRC[8*(C)+7]);                       \
            u32 e0 = __shfl_xor(hi ? d0 : d2, 32);                            \
            u32 e1 = __shfl_xor(hi ? d1 : d3, 32);                            \
            u32x4 wds{ hi ? e0 : d0, hi ? e1 : d1,                            \
                       hi ? d2 : e0, hi ? d3 : e1 };                          \
            OUT = __builtin_bit_cast(u16x8, wds); }
        PACK(st0, 0, pb4[0]); PACK(st0, 1, pb4[1]);
        PACK(st1, 0, pb4[2]); PACK(st1, 1, pb4[3]);
        #undef PACK

        // O^T += V^T . P^T  (A rows = dv, k = s)
        __builtin_amdgcn_s_setprio(1);
        #pragma unroll
        for (int kc = 0; kc < 4; kc++) {
            const int co = (kc * 16 + hi * 8) * 2;
            u16x8 v0 = *(const u16x8*)(Vsb + ((l31 * 128 + co) ^ ax));
            u16x8 v1 = *(const u16x8*)(Vsb + (((32 + l31) * 128 + co) ^ ax));
            ot0 = mfma32(v0, pb4[kc], ot0);
            ot1 = mfma32(v1, pb4[kc], ot1);
        }
        __builtin_amdgcn_s_setprio(0);
    };

    STAGE(&Ks0[0][0], &Vs0[0][0], 0);
    STAGE(&Ks1[0][0], &Vs1[0][0], 1);         // 4 outstanding / lane

    const int np = nt >> 1;                   // nt is even (4g+4)
    for (int j = 0; j < np; j++) {
        const int i0 = 2 * j, i1 = 2 * j + 1;
        WAIT_BAR(2);
        if (i0 <= i_d) COMPUTE((const char*)Ks0, (const char*)Vs0, i0);
        BAR_ONLY();
        if (i0 + 2 < nt) STAGE(&Ks0[0][0], &Vs0[0][0], i0 + 2);
        if (j < np - 1) { WAIT_BAR(2); } else { WAIT_BAR(0); }
        if (i1 <= i_d) COMPUTE((const char*)Ks1, (const char*)Vs1, i1);
        BAR_ONLY();
        if (i1 + 2 < nt) STAGE(&Ks1[0][0], &Vs1[0][0], i1 + 2);
    }

    // output: O^T reg r -> dv = td*32 + 16c + 8hf + 4hi + j, q = qrow
    const float inv = 1.0f / li;
    float* orow = out + (size_t)(b * T_ + qrow) * DMO + h * D_;
    #pragma unroll
    for (int c = 0; c < 2; c++)
        #pragma unroll
        for (int hf = 0; hf < 2; hf++) {
            f32x4 v0, v1;
            #pragma unroll
            for (int j = 0; j < 4; j++) {
                v0[j] = ot0[c * 8 + hf * 4 + j] * inv;
                v1[j] = ot1[c * 8 + hf * 4 + j] * inv;
            }
            *(f32x4*)(orow + c * 16 + hf * 8 + hi * 4)      = v0;
            *(f32x4*)(orow + 32 + c * 16 + hf * 8 + hi * 4) = v1;
        }
}

// ---------------------------------------------------------------------------
extern "C" void kernel_launch(void* const* d_in, const int* in_sizes, int n_in,
                              void* d_out, int out_size, void* d_ws, size_t ws_size,
                              hipStream_t stream) {
    int xi = 0, wi[3] = {1, 2, 3};
    {
        int k = 0, found = 0;
        for (int i = 0; i < n_in && i < 8; i++) {
            if (in_sizes[i] == B_ * T_ * DM_) { xi = i; found = 1; }
            else if (in_sizes[i] == H_ * DM_ * D_ && k < 3) wi[k++] = i;
        }
        if (!found || k != 3) { xi = 0; wi[0] = 1; wi[1] = 2; wi[2] = 3; }
    }
    const float* x  = (const float*)d_in[xi];
    const float* Wq = (const float*)d_in[wi[0]];
    const float* Wk = (const float*)d_in[wi[1]];
    const float* Wv = (const float*)d_in[wi[2]];
    float* out = (float*)d_out;

    // bf16 staging scratch lives in d_out (dead before attn writes it):
    //   xb = 8.4M u16 (16.8 MB), Wt = 3.1M u16 (6.3 MB) -> 23.1 of 33.5 MB.
    u16* xb = (u16*)d_out;
    u16* Wt = xb + (size_t)B_ * T_ * DM_;
    // ws: Q + K + Vt bf16 = 50.3 MB (R8-verified to fit).
    const size_t per = (size_t)B_ * H_ * T_ * D_;
    u16* Qc  = (u16*)d_ws;
    u16* Kc  = Qc + per;
    u16* Vtc = Kc + per;

    cvt_all<<<1792, 256, 0, stream>>>(x, Wq, Wk, Wv, xb, Wt);
    proj_kernel<<<1536, 256, 0, stream>>>(xb, Wt, Qc, Kc, Vtc);
    attn_kernel<<<512, 512, 0, stream>>>(Qc, Kc, Vtc, out);
}